// Round 13
// baseline (359.336 us; speedup 1.0000x reference)
//
#include <hip/hip_runtime.h>
#include <cstdint>

// ---------------- problem constants ----------------
constexpr int B_ = 8, N_ = 2048, D_ = 128, NW = 64;   // NW = words per bitset row
constexpr int EMAX = 131072;                           // per-batch edge capacity
constexpr int RPS = 2064;                              // rowptr stride per batch
constexpr int TDIL = 10;

// ---------------- workspace layout (bytes) ----------------
constexpr size_t OFF_BITSET = 0;                  // 4MB (preproc), reused as agg (8MB)
constexpr size_t OFF_AGG    = 0;
constexpr size_t OFF_H1     = (size_t)8  << 20;
constexpr size_t OFF_H2     = (size_t)16 << 20;
constexpr size_t OFF_H3     = (size_t)24 << 20;   // h3 (8MB); earlier: xb/h1b/h2b bf16
constexpr size_t OFF_XB     = (size_t)24 << 20;   // bf16 x   (4MB), dead before k8-L2
constexpr size_t OFF_H1B    = (size_t)28 << 20;   // bf16 h1  (4MB), dead before k8-L3
constexpr size_t OFF_H2B    = (size_t)24 << 20;   // bf16 h2  (4MB, reuses XB), dead before k8-L3
constexpr size_t OFF_COLS   = (size_t)32 << 20;   // u16 [B][EMAX]  (2MB)
constexpr size_t OFF_PACKED = (size_t)34 << 20;   // u32 [B][EMAX]  (4MB)
constexpr size_t OFF_RP     = (size_t)38 << 20;   // u32 [B][RPS]
constexpr size_t OFF_DEG0   = OFF_RP   + ((size_t)128 << 10);
constexpr size_t OFF_DEGF   = OFF_DEG0 + ((size_t)64  << 10);
constexpr size_t OFF_RMASK  = OFF_DEGF + ((size_t)64  << 10);  // u32 [B][N][4] (256KB)
constexpr size_t OFF_BN     = OFF_RMASK + ((size_t)256 << 10); // 3*256 floats
constexpr size_t OFF_WHI    = OFF_BN  + ((size_t)4 << 10);     // 147456 u16
constexpr size_t OFF_WLO    = OFF_WHI + ((size_t)304 << 10);   // 147456 u16

typedef __attribute__((ext_vector_type(8))) short short8v;
typedef __attribute__((ext_vector_type(4))) float f32x4;

__device__ __forceinline__ uint16_t bf16rne(float f) {
    uint32_t u = __float_as_uint(f);
    return (uint16_t)((u + 0x7FFFu + ((u >> 16) & 1u)) >> 16);
}

// ---------------- KW: weight split to bf16 hi/lo frags + x->bf16 copy -------
__global__ __launch_bounds__(256) void kW_prep(
        const float* __restrict__ Wr1, const float* __restrict__ Wx1,
        const float* __restrict__ Wr2, const float* __restrict__ Wx2,
        const float* __restrict__ Wr3, const float* __restrict__ Wx3,
        const float* __restrict__ Wl,
        uint16_t* __restrict__ whi, uint16_t* __restrict__ wlo,
        float* __restrict__ bn,
        const float* __restrict__ x, uint16_t* __restrict__ xb) {
    if (blockIdx.x >= 128) {
        size_t i = ((size_t)(blockIdx.x - 128) * 256 + threadIdx.x) * 4;
        float4 v = *(const float4*)&x[i];
        ushort4 o;
        o.x = bf16rne(v.x); o.y = bf16rne(v.y);
        o.z = bf16rne(v.z); o.w = bf16rne(v.w);
        *(ushort4*)&xb[i] = o;
        return;
    }
    if (blockIdx.x == 0) {
        for (int i = threadIdx.x; i < 768; i += 256) bn[i] = 0.f;
    }
    int g  = blockIdx.x >> 5;          // 0..3: L1,L2,L3,Wl
    int lb = blockIdx.x & 31;
    int K = (g == 3) ? 384 : 256;
    const float* A  = (g == 0) ? Wr1 : (g == 1) ? Wr2 : (g == 2) ? Wr3 : Wl;
    const float* Bw = (g == 0) ? Wx1 : (g == 1) ? Wx2 : (g == 2) ? Wx3 : nullptr;
    size_t base = (g == 3) ? (size_t)98304 : (size_t)g * 32768;
    int total = K * 128;
    for (int f = lb * 256 + threadIdx.x; f < total; f += 32 * 256) {
        int e = f & 7, lane = (f >> 3) & 63, ct = (f >> 9) & 7, ks = f >> 12;
        int k = ks * 32 + ((lane >> 4) << 3) + e;
        int col = (ct << 4) + (lane & 15);
        float v = (g == 3 || k < 128) ? A[(size_t)k * 128 + col]
                                      : Bw[(size_t)(k - 128) * 128 + col];
        uint32_t hi = bf16rne(v);
        float hf = __uint_as_float(hi << 16);
        whi[base + f] = (uint16_t)hi;
        wlo[base + f] = bf16rne(v - hf);
    }
}

// ---------------- K1: adj (fp32 0/1) -> bitset + degrees ----------------
__global__ __launch_bounds__(256) void k1_bitset(const float* __restrict__ adj,
        uint32_t* __restrict__ bitset, uint32_t* __restrict__ deg0) {
    int row  = blockIdx.x * 4 + (threadIdx.x >> 6);
    int lane = threadIdx.x & 63;
    const float* ar = adj + (size_t)row * N_;
    uint32_t myw = 0;
    #pragma unroll 4
    for (int it = 0; it < 32; ++it) {
        float v = ar[it * 64 + lane];
        unsigned long long m = __ballot(v != 0.0f);
        if (lane == 2 * it)          myw = (uint32_t)m;
        else if (lane == 2 * it + 1) myw = (uint32_t)(m >> 32);
    }
    bitset[(size_t)row * NW + lane] = myw;
    int pc = __popc(myw);
    #pragma unroll
    for (int off = 32; off >= 1; off >>= 1) pc += __shfl_xor(pc, off);
    if (lane == 0) deg0[row] = (uint32_t)pc;
}

// ---------------- K2: per-batch prefix sum of degrees -> rowptr ----------------
__global__ __launch_bounds__(256) void k2_rowptr(const uint32_t* __restrict__ deg0,
        uint32_t* __restrict__ rowptr) {
    int b = blockIdx.x, t = threadIdx.x;
    __shared__ uint32_t tsum[256];
    uint32_t v[8]; uint32_t s = 0;
    #pragma unroll
    for (int j = 0; j < 8; ++j) { v[j] = deg0[b * N_ + t * 8 + j]; s += v[j]; v[j] = s; }
    tsum[t] = s;
    __syncthreads();
    for (int off = 1; off < 256; off <<= 1) {
        uint32_t xv = (t >= off) ? tsum[t - off] : 0u;
        __syncthreads();
        tsum[t] += xv;
        __syncthreads();
    }
    uint32_t excl = tsum[t] - s;
    uint32_t* rp = rowptr + (size_t)b * RPS;
    if (t == 0) rp[0] = 0;
    #pragma unroll
    for (int j = 0; j < 8; ++j) {
        uint32_t val = excl + v[j];
        if (val > (uint32_t)EMAX) val = EMAX;
        rp[t * 8 + j + 1] = val;
    }
}

// ---------------- K3: fill sorted column lists ----------------
__global__ __launch_bounds__(256) void k3_cols(const uint32_t* __restrict__ bitset,
        const uint32_t* __restrict__ rowptr, uint16_t* __restrict__ cols) {
    int row  = blockIdx.x * 4 + (threadIdx.x >> 6);
    int lane = threadIdx.x & 63;
    int b = row >> 11, n = row & (N_ - 1);
    uint32_t w = bitset[(size_t)row * NW + lane];
    uint32_t pc = __popc(w);
    uint32_t inc = pc;
    #pragma unroll
    for (int off = 1; off < 64; off <<= 1) {
        uint32_t t = __shfl_up(inc, off);
        if (lane >= off) inc += t;
    }
    uint32_t base = rowptr[(size_t)b * RPS + n] + (inc - pc);
    uint16_t* cb = cols + (size_t)b * EMAX;
    while (w) {
        int bit = __builtin_ctz(w); w &= w - 1;
        if (base < (uint32_t)EMAX) cb[base] = (uint16_t)(lane * 32 + bit);
        ++base;
    }
}

// ---------------- K4: packed (col | mate_local<<16) via binary search ----------------
__global__ __launch_bounds__(256) void k4_packed(const uint16_t* __restrict__ cols,
        const uint32_t* __restrict__ rowptr, uint32_t* __restrict__ packed) {
    int row  = blockIdx.x * 4 + (threadIdx.x >> 6);
    int lane = threadIdx.x & 63;
    int b = row >> 11, n = row & (N_ - 1);
    const uint32_t* rpb = rowptr + (size_t)b * RPS;
    const uint16_t* cb  = cols + (size_t)b * EMAX;
    uint32_t start = rpb[n], end = rpb[n + 1];
    for (uint32_t e = start + lane; e < end; e += 64) {
        uint32_t j = cb[e];
        uint32_t lo = rpb[j], hi = rpb[j + 1];
        uint32_t rj = lo;
        while (lo < hi) {
            uint32_t mid = (lo + hi) >> 1;
            if ((int)cb[mid] < n) lo = mid + 1; else hi = mid;
        }
        packed[(size_t)b * EMAX + e] = j | ((lo - rj) << 16);
    }
}

// ---------------- K5: DAG-parallel dilation (16 waves per batch) ----------------
// R11/R12 async-spin core with wave-uniform cnt<=64 fast path. done-bit
// publish: relaxed ds_or + compiler fence (per-wave in-order DS completion
// orders the rm4 writes first). Tail: write rank masks + degf (NO compaction
// — k7 skips dead edges via the rank mask; the serial compaction tail was
// R12's 45us regression).
#define K5_ISSUE(PK0, PK1, CNT, ROW)                                        \
    do {                                                                    \
        int rr_ = (ROW);                                                    \
        if (rr_ < N_) {                                                     \
            uint32_t ldI_ = rps[rr_], enI_ = rps[rr_ + 1];                  \
            CNT = (int)(enI_ - ldI_);                                       \
            PK0 = (lane < CNT) ? pkg[ldI_ + lane] : 0xFFFFFFFFu;            \
            if (CNT > 64)                                                   \
                PK1 = (lane + 64 < CNT) ? pkg[ldI_ + 64 + lane] : 0xFFFFFFFFu; \
            else PK1 = 0xFFFFFFFFu;                                         \
        } else { CNT = 0; PK0 = 0xFFFFFFFFu; PK1 = 0xFFFFFFFFu; }           \
    } while (0)

#define K5_PROC(PK0, PK1, CNT, NROW)                                        \
    do {                                                                    \
        int nr_ = (NROW);                                                   \
        if (CNT <= 64) {                                                    \
            /* ---------- fast path: deg <= 64 ---------- */                \
            uint32_t c0_ = PK0 & 0xFFFFu;                                   \
            bool e0_ = (lane < CNT) && (c0_ < (uint32_t)nr_);               \
            while (true) {                                                  \
                uint32_t d0_ = e0_ ? __hip_atomic_load(&done[c0_ >> 5],     \
                        __ATOMIC_ACQUIRE, __HIP_MEMORY_SCOPE_WORKGROUP) : 0u; \
                bool ok0_ = !e0_ || ((d0_ >> (c0_ & 31)) & 1u);             \
                if (__all((int)ok0_)) break;                                \
            }                                                               \
            __builtin_amdgcn_s_setprio(1);                                  \
            uint2 mc_ = *(const uint2*)&rm4[(size_t)nr_ * 4];               \
            uint32_t w01_ = (lane < 32) ? mc_.x : mc_.y;                    \
            uint32_t a0_ = (w01_ >> (lane & 31)) & 1u;                      \
            unsigned long long bl0_ = __ballot(a0_ != 0);                   \
            uint32_t num_ = (uint32_t)__popcll(bl0_);                       \
            if (mk[nr_] && num_ > 1u) {                                     \
                bool allrm_ = num_ <= (uint32_t)TDIL;                       \
                uint32_t sf_ = (num_ + 1u) >> 1;                            \
                uint32_t r2_ = (num_ & 1u) ? 0xFFFFFFFFu : num_;            \
                uint32_t rank0_ = (uint32_t)__popcll(bl0_ & below) + 1u;    \
                bool rm0_ = a0_ && (allrm_ || rank0_ == sf_ || rank0_ == r2_); \
                unsigned long long rb0_ = __ballot(rm0_);                   \
                if (rm0_) {                                                 \
                    uint32_t ml_ = PK0 >> 16;                               \
                    if (ml_ < 128u) atomicAnd(&rm4[c0_ * 4 + (ml_ >> 5)], ~(1u << (ml_ & 31))); \
                }                                                           \
                if (lane == 0) {                                            \
                    uint2 nm_;                                              \
                    nm_.x = mc_.x & ~(uint32_t)rb0_;                        \
                    nm_.y = mc_.y & ~(uint32_t)(rb0_ >> 32);                \
                    *(uint2*)&rm4[(size_t)nr_ * 4] = nm_;                   \
                }                                                           \
            }                                                               \
            __asm__ __volatile__("" ::: "memory");                          \
            if (lane == 0)                                                  \
                __hip_atomic_fetch_or(&done[nr_ >> 5], 1u << (nr_ & 31),    \
                        __ATOMIC_RELAXED, __HIP_MEMORY_SCOPE_WORKGROUP);    \
            __builtin_amdgcn_s_setprio(0);                                  \
        } else {                                                            \
            /* ---------- slow path: deg > 64 (rare) ---------- */          \
            uint32_t c0_ = PK0 & 0xFFFFu, c1_ = PK1 & 0xFFFFu;              \
            bool e0_ = (lane < CNT)      && (c0_ < (uint32_t)nr_);          \
            bool e1_ = (lane + 64 < CNT) && (c1_ < (uint32_t)nr_);          \
            while (true) {                                                  \
                uint32_t d0_ = e0_ ? __hip_atomic_load(&done[c0_ >> 5],     \
                        __ATOMIC_ACQUIRE, __HIP_MEMORY_SCOPE_WORKGROUP) : 0u; \
                uint32_t d1_ = e1_ ? __hip_atomic_load(&done[c1_ >> 5],     \
                        __ATOMIC_ACQUIRE, __HIP_MEMORY_SCOPE_WORKGROUP) : 0u; \
                bool ok0_ = !e0_ || ((d0_ >> (c0_ & 31)) & 1u);             \
                bool ok1_ = !e1_ || ((d1_ >> (c1_ & 31)) & 1u);             \
                if (__all((int)(ok0_ && ok1_))) break;                      \
            }                                                               \
            __builtin_amdgcn_s_setprio(1);                                  \
            uint4 mcur_ = *(const uint4*)&rm4[(size_t)nr_ * 4];             \
            uint32_t w01_ = (lane < 32) ? mcur_.x : mcur_.y;                \
            uint32_t w23_ = (lane < 32) ? mcur_.z : mcur_.w;                \
            uint32_t a0_ = (w01_ >> (lane & 31)) & 1u;                      \
            uint32_t a1_ = (w23_ >> (lane & 31)) & 1u;                      \
            unsigned long long bl0_ = __ballot(a0_ != 0), bl1_ = __ballot(a1_ != 0); \
            uint32_t num_ = (uint32_t)__popcll(bl0_) + (uint32_t)__popcll(bl1_); \
            if (mk[nr_] && num_ > 1u) {                                     \
                bool allrm_ = num_ <= (uint32_t)TDIL;                       \
                uint32_t sf_ = (num_ + 1u) >> 1;                            \
                uint32_t r2_ = (num_ & 1u) ? 0xFFFFFFFFu : num_;            \
                uint32_t rank0_ = (uint32_t)__popcll(bl0_ & below) + 1u;    \
                uint32_t rank1_ = (uint32_t)__popcll(bl0_) +                \
                                  (uint32_t)__popcll(bl1_ & below) + 1u;    \
                bool rm0_ = a0_ && (allrm_ || rank0_ == sf_ || rank0_ == r2_); \
                bool rm1_ = a1_ && (allrm_ || rank1_ == sf_ || rank1_ == r2_); \
                unsigned long long rb0_ = __ballot(rm0_), rb1_ = __ballot(rm1_); \
                if (rm0_) {                                                 \
                    uint32_t ml_ = PK0 >> 16;                               \
                    if (ml_ < 128u) atomicAnd(&rm4[c0_ * 4 + (ml_ >> 5)], ~(1u << (ml_ & 31))); \
                }                                                           \
                if (rm1_) {                                                 \
                    uint32_t ml_ = PK1 >> 16;                               \
                    if (ml_ < 128u) atomicAnd(&rm4[c1_ * 4 + (ml_ >> 5)], ~(1u << (ml_ & 31))); \
                }                                                           \
                if (lane == 0) {                                            \
                    uint4 nm_;                                              \
                    nm_.x = mcur_.x & ~(uint32_t)rb0_;                      \
                    nm_.y = mcur_.y & ~(uint32_t)(rb0_ >> 32);              \
                    nm_.z = mcur_.z & ~(uint32_t)rb1_;                      \
                    nm_.w = mcur_.w & ~(uint32_t)(rb1_ >> 32);              \
                    *(uint4*)&rm4[(size_t)nr_ * 4] = nm_;                   \
                }                                                           \
            }                                                               \
            __asm__ __volatile__("" ::: "memory");                          \
            if (lane == 0)                                                  \
                __hip_atomic_fetch_or(&done[nr_ >> 5], 1u << (nr_ & 31),    \
                        __ATOMIC_RELAXED, __HIP_MEMORY_SCOPE_WORKGROUP);    \
            __builtin_amdgcn_s_setprio(0);                                  \
        }                                                                   \
    } while (0)

__global__ __launch_bounds__(1024) void k5_dilate(
        const uint32_t* __restrict__ packed, const uint32_t* __restrict__ rowptr,
        const uint32_t* __restrict__ deg0, const int* __restrict__ mask,
        uint32_t* __restrict__ rmaskg, uint32_t* __restrict__ degf) {
    int b = blockIdx.x;
    int tid = threadIdx.x;
    int lane = tid & 63;
    int wv = tid >> 6;                                // 0..15
    __shared__ __align__(16) uint32_t rm4[N_ * 4];    // 32KB
    __shared__ uint32_t rps[N_ + 1];                  // 8.2KB
    __shared__ uint8_t  mk[N_];                       // 2KB
    __shared__ uint32_t done[64];                     // 2048 done-bits
    const uint32_t* pkg = packed + (size_t)b * EMAX;
    const uint32_t* rpg = rowptr + (size_t)b * RPS;

    for (int i = tid; i <= N_; i += 1024) rps[i] = rpg[i];
    if (tid < 64) done[tid] = 0u;
    for (int i = tid; i < N_; i += 1024) {
        int d = (int)deg0[b * N_ + i]; if (d > 128) d = 128;
        uint4 mm;
        mm.x = (d >= 32) ? ~0u : ((d > 0)  ? ((1u << d)        - 1u) : 0u);
        mm.y = (d >= 64) ? ~0u : ((d > 32) ? ((1u << (d - 32)) - 1u) : 0u);
        mm.z = (d >= 96) ? ~0u : ((d > 64) ? ((1u << (d - 64)) - 1u) : 0u);
        mm.w = (d >= 128)? ~0u : ((d > 96) ? ((1u << (d - 96)) - 1u) : 0u);
        *(uint4*)&rm4[(size_t)i * 4] = mm;
        mk[i] = (uint8_t)(mask[b * N_ + i] != 0);
    }
    __syncthreads();

    unsigned long long below = (1ULL << lane) - 1ULL;
    int cntA, cntB, cntC;
    uint32_t pkA0, pkA1, pkB0, pkB1, pkC0, pkC1;
    K5_ISSUE(pkA0, pkA1, cntA, wv);
    K5_ISSUE(pkB0, pkB1, cntB, wv + 16);
    K5_ISSUE(pkC0, pkC1, cntC, wv + 32);

    int n = wv;
    while (n < N_) {
        K5_PROC(pkA0, pkA1, cntA, n);
        K5_ISSUE(pkA0, pkA1, cntA, n + 48);
        n += 16; if (n >= N_) break;
        K5_PROC(pkB0, pkB1, cntB, n);
        K5_ISSUE(pkB0, pkB1, cntB, n + 48);
        n += 16; if (n >= N_) break;
        K5_PROC(pkC0, pkC1, cntC, n);
        K5_ISSUE(pkC0, pkC1, cntC, n + 48);
        n += 16;
    }
    __syncthreads();
    for (int i = tid; i < N_; i += 1024) {
        uint4 mm = *(const uint4*)&rm4[(size_t)i * 4];
        *(uint4*)&rmaskg[((size_t)b * N_ + i) * 4] = mm;
        degf[b * N_ + i] = (uint32_t)(__popc(mm.x) + __popc(mm.y) + __popc(mm.z) + __popc(mm.w));
    }
}

// ---------------- K7: SpMM mean-aggregate over bf16 features, skip-dead -----
// Gathers over the ORIGINAL (uncompacted) cols list; dead edges are skipped
// via the rank-indexed alive bitmap (held in SGPRs; test is wave-uniform).
__global__ __launch_bounds__(256) void k7_spmm(const uint16_t* __restrict__ Xb16,
        const uint16_t* __restrict__ cols, const uint32_t* __restrict__ rowptr,
        const uint32_t* __restrict__ rmaskg, const uint32_t* __restrict__ degf,
        float* __restrict__ agg) {
    int wid  = blockIdx.x * 4 + (threadIdx.x >> 6);
    int lane = threadIdx.x & 63;
    int b = wid >> 11, n = wid & (N_ - 1);
    const uint16_t* cb = cols + (size_t)b * EMAX;
    uint32_t start = rowptr[(size_t)b * RPS + n];
    uint32_t end   = rowptr[(size_t)b * RPS + n + 1];
    int cnt0 = (int)(end - start);
    uint4 mm = *(const uint4*)&rmaskg[(size_t)wid * 4];
    unsigned long long am0 = (unsigned long long)mm.x | ((unsigned long long)mm.y << 32);
    unsigned long long am1 = (unsigned long long)mm.z | ((unsigned long long)mm.w << 32);
    const uint16_t* Xb = Xb16 + ((size_t)b * N_) * D_;
    float ax = 0.f, ay = 0.f;
    for (int base = 0; base < cnt0; base += 64) {
        int idx = base + lane;
        int cl = (idx < cnt0) ? (int)cb[start + idx] : 0;
        unsigned long long am = base ? am1 : am0;
        int kmax = cnt0 - base; if (kmax > 64) kmax = 64;
        for (int k = 0; k < kmax; ++k) {
            if ((am >> k) & 1ULL) {
                int c = __shfl(cl, k);
                uint32_t u = ((const uint32_t*)(Xb + (size_t)c * D_))[lane];
                ax += __uint_as_float(u << 16);
                ay += __uint_as_float(u & 0xFFFF0000u);
            }
        }
    }
    uint32_t cnt = degf[wid];
    float inv = 1.0f / (float)(cnt ? cnt : 1u);
    ((float2*)(agg + (size_t)wid * D_))[lane] = make_float2(ax * inv, ay * inv);
}

// ---------------- bf16 split helper ----------------
__device__ __forceinline__ void cvt_store4(uint16_t* hiA, uint16_t* loA,
                                           int idx, float4 v) {
    float vv[4] = {v.x, v.y, v.z, v.w};
    ushort4 hs, ls;
    uint16_t* hp = (uint16_t*)&hs; uint16_t* lp = (uint16_t*)&ls;
    #pragma unroll
    for (int i = 0; i < 4; ++i) {
        uint32_t hi = bf16rne(vv[i]);
        float hf = __uint_as_float(hi << 16);
        hp[i] = (uint16_t)hi;
        lp[i] = bf16rne(vv[i] - hf);
    }
    *(ushort4*)&hiA[idx] = hs;
    *(ushort4*)&loA[idx] = ls;
}

// ---------------- K8: fused SAGE via bf16x3 MFMA ----------------
constexpr int ASTR = 264;   // shorts per row (256 + 8 pad)
__global__ __launch_bounds__(256) void k8_mfma(const float* __restrict__ agg,
        const float* __restrict__ Hin,
        const uint16_t* __restrict__ whi, const uint16_t* __restrict__ wlo,
        const float* __restrict__ bias, const int* __restrict__ mask,
        const float* __restrict__ bnp, const float* __restrict__ gp,
        const float* __restrict__ bep, int use_bn,
        float* __restrict__ P, uint16_t* __restrict__ Pb,
        float* __restrict__ bnstat) {
    __shared__ __align__(16) char buf[2 * 32 * ASTR * 2];   // 33792B
    __shared__ float scL[128], shL[128];
    uint16_t* aHi = (uint16_t*)buf;
    uint16_t* aLo = (uint16_t*)(buf + 32 * ASTR * 2);
    float* outP = (float*)buf;                              // overlay after MFMA
    int tid = threadIdx.x, lane = tid & 63, h = tid >> 6;
    size_t row0 = (size_t)blockIdx.x * 32;

    if (tid < 128) {
        float sc = 1.f, sh = 0.f;
        if (use_bn) {
            float mean = bnp[tid] * (1.f / 16384.f);
            float var  = bnp[128 + tid] * (1.f / 16384.f) - mean * mean;
            sc = gp[tid] * rsqrtf(var + 1e-5f);
            sh = bep[tid] - mean * sc;
        }
        scL[tid] = sc; shL[tid] = sh;
    }
    __syncthreads();

    for (int f = tid * 4; f < 4096; f += 1024) {
        int r = f >> 7, c = f & 127;
        float4 va = *(const float4*)&agg[(row0 + r) * 128 + c];
        float4 vx = *(const float4*)&Hin[(row0 + r) * 128 + c];
        float4 s4 = *(const float4*)&scL[c];
        float4 h4 = *(const float4*)&shL[c];
        va.x = va.x * s4.x + h4.x; va.y = va.y * s4.y + h4.y;
        va.z = va.z * s4.z + h4.z; va.w = va.w * s4.w + h4.w;
        vx.x = vx.x * s4.x + h4.x; vx.y = vx.y * s4.y + h4.y;
        vx.z = vx.z * s4.z + h4.z; vx.w = vx.w * s4.w + h4.w;
        cvt_store4(aHi, aLo, r * ASTR + c, va);
        cvt_store4(aHi, aLo, r * ASTR + 128 + c, vx);
    }
    __syncthreads();

    f32x4 acc00 = {0.f,0.f,0.f,0.f}, acc01 = acc00, acc10 = acc00, acc11 = acc00;
    int ct0 = h * 2, ct1 = h * 2 + 1;
    int arow = (lane & 15);
    int koff = (lane >> 4) * 8;
    #pragma unroll
    for (int ks = 0; ks < 8; ++ks) {
        int k0 = ks * 32 + koff;
        short8v a0h = *(short8v*)&aHi[arow * ASTR + k0];
        short8v a0l = *(short8v*)&aLo[arow * ASTR + k0];
        short8v a1h = *(short8v*)&aHi[(arow + 16) * ASTR + k0];
        short8v a1l = *(short8v*)&aLo[(arow + 16) * ASTR + k0];
        short8v b0h = *(const short8v*)&whi[(size_t)(((ks * 8 + ct0) << 6) + lane) * 8];
        short8v b0l = *(const short8v*)&wlo[(size_t)(((ks * 8 + ct0) << 6) + lane) * 8];
        short8v b1h = *(const short8v*)&whi[(size_t)(((ks * 8 + ct1) << 6) + lane) * 8];
        short8v b1l = *(const short8v*)&wlo[(size_t)(((ks * 8 + ct1) << 6) + lane) * 8];
        acc00 = __builtin_amdgcn_mfma_f32_16x16x32_bf16(a0h, b0h, acc00, 0, 0, 0);
        acc00 = __builtin_amdgcn_mfma_f32_16x16x32_bf16(a0h, b0l, acc00, 0, 0, 0);
        acc00 = __builtin_amdgcn_mfma_f32_16x16x32_bf16(a0l, b0h, acc00, 0, 0, 0);
        acc01 = __builtin_amdgcn_mfma_f32_16x16x32_bf16(a0h, b1h, acc01, 0, 0, 0);
        acc01 = __builtin_amdgcn_mfma_f32_16x16x32_bf16(a0h, b1l, acc01, 0, 0, 0);
        acc01 = __builtin_amdgcn_mfma_f32_16x16x32_bf16(a0l, b1h, acc01, 0, 0, 0);
        acc10 = __builtin_amdgcn_mfma_f32_16x16x32_bf16(a1h, b0h, acc10, 0, 0, 0);
        acc10 = __builtin_amdgcn_mfma_f32_16x16x32_bf16(a1h, b0l, acc10, 0, 0, 0);
        acc10 = __builtin_amdgcn_mfma_f32_16x16x32_bf16(a1l, b0h, acc10, 0, 0, 0);
        acc11 = __builtin_amdgcn_mfma_f32_16x16x32_bf16(a1h, b1h, acc11, 0, 0, 0);
        acc11 = __builtin_amdgcn_mfma_f32_16x16x32_bf16(a1h, b1l, acc11, 0, 0, 0);
        acc11 = __builtin_amdgcn_mfma_f32_16x16x32_bf16(a1l, b1h, acc11, 0, 0, 0);
    }
    __syncthreads();

    int orow = (lane >> 4) * 4;
    int oc0 = ct0 * 16 + (lane & 15);
    int oc1 = ct1 * 16 + (lane & 15);
    #pragma unroll
    for (int j = 0; j < 4; ++j) {
        outP[(orow + j) * 128 + oc0]      = acc00[j];
        outP[(orow + j) * 128 + oc1]      = acc01[j];
        outP[(16 + orow + j) * 128 + oc0] = acc10[j];
        outP[(16 + orow + j) * 128 + oc1] = acc11[j];
    }
    __syncthreads();

    float bs0 = bias[lane], bs1 = bias[lane + 64];
    #pragma unroll
    for (int i = 0; i < 8; ++i) {
        int r = h * 8 + i;
        float v0 = outP[r * 128 + lane] + bs0;
        float v1 = outP[r * 128 + lane + 64] + bs1;
        float s = v0 * v0 + v1 * v1;
        #pragma unroll
        for (int off = 32; off >= 1; off >>= 1) s += __shfl_xor(s, off);
        float nrm = fmaxf(sqrtf(s), 1e-12f);
        float mf = (mask[row0 + r] != 0) ? 1.f : 0.f;
        float inv = mf / nrm;
        float p0 = fmaxf(v0 * inv, 0.f), p1 = fmaxf(v1 * inv, 0.f);
        P[(row0 + r) * 128 + lane]      = p0;
        P[(row0 + r) * 128 + lane + 64] = p1;
        if (Pb) {
            Pb[(row0 + r) * 128 + lane]      = bf16rne(p0);
            Pb[(row0 + r) * 128 + lane + 64] = bf16rne(p1);
        }
        outP[r * 128 + lane] = p0; outP[r * 128 + lane + 64] = p1;
    }
    __syncthreads();
    if (tid < 128) {
        float s = 0.f, q = 0.f;
        #pragma unroll
        for (int r = 0; r < 32; ++r) { float v = outP[r * 128 + tid]; s += v; q += v * v; }
        atomicAdd(&bnstat[tid], s);
        atomicAdd(&bnstat[128 + tid], q);
    }
}

// ---------------- K11: final (concat BN(h_i) * mf) @ Wl + bl, * mf ----------
__global__ __launch_bounds__(256) void k11_final(const float* __restrict__ h1,
        const float* __restrict__ h2, const float* __restrict__ h3,
        const float* __restrict__ Wl, const float* __restrict__ bl,
        const int* __restrict__ mask, const float* __restrict__ bn,
        const float* __restrict__ g1, const float* __restrict__ be1,
        const float* __restrict__ g2, const float* __restrict__ be2,
        const float* __restrict__ g3, const float* __restrict__ be3,
        float* __restrict__ out) {
    __shared__ float s1[32 * 128], s2[32 * 128], s3[32 * 128];
    __shared__ float scA[128], shA[128], scB[128], shB[128], scC[128], shC[128];
    int tid = threadIdx.x;
    size_t row0 = (size_t)blockIdx.x * 32;
    if (tid < 128) {
        float m1 = bn[tid] * (1.f / 16384.f);
        float v1 = bn[128 + tid] * (1.f / 16384.f) - m1 * m1;
        scA[tid] = g1[tid] * rsqrtf(v1 + 1e-5f);
        shA[tid] = be1[tid] - m1 * scA[tid];
        float m2 = bn[256 + tid] * (1.f / 16384.f);
        float v2 = bn[384 + tid] * (1.f / 16384.f) - m2 * m2;
        scB[tid] = g2[tid] * rsqrtf(v2 + 1e-5f);
        shB[tid] = be2[tid] - m2 * scB[tid];
        float m3 = bn[512 + tid] * (1.f / 16384.f);
        float v3 = bn[640 + tid] * (1.f / 16384.f) - m3 * m3;
        scC[tid] = g3[tid] * rsqrtf(v3 + 1e-5f);
        shC[tid] = be3[tid] - m3 * scC[tid];
    }
    __syncthreads();
    for (int t = tid * 4; t < 32 * 128; t += 1024) {
        int r = t >> 7;
        float mf = (mask[row0 + r] != 0) ? 1.f : 0.f;
        int c = t & 127;
        float4 a = *(const float4*)&h1[row0 * 128 + t];
        float4 b = *(const float4*)&h2[row0 * 128 + t];
        float4 cc = *(const float4*)&h3[row0 * 128 + t];
        float4 sa = *(const float4*)&scA[c], ha = *(const float4*)&shA[c];
        float4 sb = *(const float4*)&scB[c], hb = *(const float4*)&shB[c];
        float4 sc = *(const float4*)&scC[c], hc = *(const float4*)&shC[c];
        a.x = (a.x * sa.x + ha.x) * mf; a.y = (a.y * sa.y + ha.y) * mf;
        a.z = (a.z * sa.z + ha.z) * mf; a.w = (a.w * sa.w + ha.w) * mf;
        b.x = (b.x * sb.x + hb.x) * mf; b.y = (b.y * sb.y + hb.y) * mf;
        b.z = (b.z * sb.z + hb.z) * mf; b.w = (b.w * sb.w + hb.w) * mf;
        cc.x = (cc.x * sc.x + hc.x) * mf; cc.y = (cc.y * sc.y + hc.y) * mf;
        cc.z = (cc.z * sc.z + hc.z) * mf; cc.w = (cc.w * sc.w + hc.w) * mf;
        *(float4*)&s1[t] = a; *(float4*)&s2[t] = b; *(float4*)&s3[t] = cc;
    }
    __syncthreads();
    int h = tid >> 6, c0 = (tid & 63) * 2;
    float2 acc[8];
    #pragma unroll
    for (int i = 0; i < 8; ++i) acc[i] = make_float2(0.f, 0.f);
    for (int k4 = 0; k4 < 128; k4 += 4) {
        float2 w1[4], w2[4], w3[4];
        #pragma unroll
        for (int kk = 0; kk < 4; ++kk) {
            w1[kk] = *(const float2*)&Wl[(k4 + kk) * 128 + c0];
            w2[kk] = *(const float2*)&Wl[(128 + k4 + kk) * 128 + c0];
            w3[kk] = *(const float2*)&Wl[(256 + k4 + kk) * 128 + c0];
        }
        #pragma unroll
        for (int i = 0; i < 8; ++i) {
            int r = h * 8 + i;
            float4 a = *(const float4*)&s1[r * 128 + k4];
            float4 b = *(const float4*)&s2[r * 128 + k4];
            float4 c = *(const float4*)&s3[r * 128 + k4];
            acc[i].x += a.x * w1[0].x + a.y * w1[1].x + a.z * w1[2].x + a.w * w1[3].x
                      + b.x * w2[0].x + b.y * w2[1].x + b.z * w2[2].x + b.w * w2[3].x
                      + c.x * w3[0].x + c.y * w3[1].x + c.z * w3[2].x + c.w * w3[3].x;
            acc[i].y += a.x * w1[0].y + a.y * w1[1].y + a.z * w1[2].y + a.w * w1[3].y
                      + b.x * w2[0].y + b.y * w2[1].y + b.z * w2[2].y + b.w * w2[3].y
                      + c.x * w3[0].y + c.y * w3[1].y + c.z * w3[2].y + c.w * w3[3].y;
        }
    }
    float bx = bl[c0], by = bl[c0 + 1];
    #pragma unroll
    for (int i = 0; i < 8; ++i) {
        int r = h * 8 + i;
        float mf = (mask[row0 + r] != 0) ? 1.f : 0.f;
        *(float2*)&out[(row0 + r) * 128 + c0] =
            make_float2((acc[i].x + bx) * mf, (acc[i].y + by) * mf);
    }
}

// ---------------- launch ----------------
extern "C" void kernel_launch(void* const* d_in, const int* in_sizes, int n_in,
                              void* d_out, int out_size, void* d_ws, size_t ws_size,
                              hipStream_t stream) {
    (void)in_sizes; (void)n_in; (void)out_size; (void)ws_size;
    const float* x    = (const float*)d_in[0];
    const float* adj  = (const float*)d_in[1];
    const int*   mask = (const int*)d_in[2];
    const float* Wr1 = (const float*)d_in[3],  *Wx1 = (const float*)d_in[4];
    const float* b1  = (const float*)d_in[5],  *g1  = (const float*)d_in[6],  *be1 = (const float*)d_in[7];
    const float* Wr2 = (const float*)d_in[8],  *Wx2 = (const float*)d_in[9];
    const float* b2  = (const float*)d_in[10], *g2  = (const float*)d_in[11], *be2 = (const float*)d_in[12];
    const float* Wr3 = (const float*)d_in[13], *Wx3 = (const float*)d_in[14];
    const float* b3  = (const float*)d_in[15], *g3  = (const float*)d_in[16], *be3 = (const float*)d_in[17];
    const float* Wl  = (const float*)d_in[18], *bl  = (const float*)d_in[19];

    char* ws = (char*)d_ws;
    uint32_t* bitset = (uint32_t*)(ws + OFF_BITSET);
    float*    agg    = (float*)(ws + OFF_AGG);
    float*    h1     = (float*)(ws + OFF_H1);
    float*    h2     = (float*)(ws + OFF_H2);
    float*    h3     = (float*)(ws + OFF_H3);
    uint16_t* xb     = (uint16_t*)(ws + OFF_XB);
    uint16_t* h1b    = (uint16_t*)(ws + OFF_H1B);
    uint16_t* h2b    = (uint16_t*)(ws + OFF_H2B);
    uint16_t* cols   = (uint16_t*)(ws + OFF_COLS);
    uint32_t* packed = (uint32_t*)(ws + OFF_PACKED);
    uint32_t* rp     = (uint32_t*)(ws + OFF_RP);
    uint32_t* deg0   = (uint32_t*)(ws + OFF_DEG0);
    uint32_t* degf   = (uint32_t*)(ws + OFF_DEGF);
    uint32_t* rmaskg = (uint32_t*)(ws + OFF_RMASK);
    float*    bn     = (float*)(ws + OFF_BN);
    uint16_t* whi    = (uint16_t*)(ws + OFF_WHI);
    uint16_t* wlo    = (uint16_t*)(ws + OFF_WLO);
    float*    out    = (float*)d_out;

    kW_prep   <<<2176, 256, 0, stream>>>(Wr1, Wx1, Wr2, Wx2, Wr3, Wx3, Wl,
                                         whi, wlo, bn, x, xb);
    k1_bitset <<<4096, 256, 0, stream>>>(adj, bitset, deg0);
    k2_rowptr <<<8,    256, 0, stream>>>(deg0, rp);
    k3_cols   <<<4096, 256, 0, stream>>>(bitset, rp, cols);
    k4_packed <<<4096, 256, 0, stream>>>(cols, rp, packed);
    k5_dilate <<<8,    1024, 0, stream>>>(packed, rp, deg0, mask, rmaskg, degf);
    // layer 1 (gather bf16 x; identity affine)
    k7_spmm   <<<4096, 256, 0, stream>>>(xb,  cols, rp, rmaskg, degf, agg);
    k8_mfma   <<<512,  256, 0, stream>>>(agg, x,  whi,         wlo,         b1, mask,
                                         bn, g1, be1, 0, h1, h1b, bn + 0);
    // layer 2 (gather bf16 h1; BN1 affine on the fly)
    k7_spmm   <<<4096, 256, 0, stream>>>(h1b, cols, rp, rmaskg, degf, agg);
    k8_mfma   <<<512,  256, 0, stream>>>(agg, h1, whi + 32768, wlo + 32768, b2, mask,
                                         bn + 0, g1, be1, 1, h2, h2b, bn + 256);
    // layer 3 (gather bf16 h2; BN2 affine on the fly)
    k7_spmm   <<<4096, 256, 0, stream>>>(h2b, cols, rp, rmaskg, degf, agg);
    k8_mfma   <<<512,  256, 0, stream>>>(agg, h2, whi + 65536, wlo + 65536, b3, mask,
                                         bn + 256, g2, be2, 1, h3, nullptr, bn + 512);
    // final
    k11_final <<<512,  256, 0, stream>>>(h1, h2, h3, Wl, bl, mask, bn,
                                         g1, be1, g2, be2, g3, be3, out);
}

// Round 14
// 292.653 us; speedup vs baseline: 1.2279x; 1.2279x over previous
//
#include <hip/hip_runtime.h>
#include <cstdint>

// ---------------- problem constants ----------------
constexpr int B_ = 8, N_ = 2048, D_ = 128, NW = 64;   // NW = words per bitset row
constexpr int EMAX = 131072;                           // per-batch edge capacity
constexpr int RPS = 2064;                              // rowptr stride per batch
constexpr int TDIL = 10;

// ---------------- workspace layout (bytes) ----------------
constexpr size_t OFF_BITSET = 0;                  // 4MB (preproc), reused as agg (8MB)
constexpr size_t OFF_AGG    = 0;
constexpr size_t OFF_H1     = (size_t)8  << 20;
constexpr size_t OFF_H2     = (size_t)16 << 20;
constexpr size_t OFF_H3     = (size_t)24 << 20;   // h3 (8MB); earlier: xb/h1b/h2b bf16
constexpr size_t OFF_XB     = (size_t)24 << 20;   // bf16 x   (4MB), dead before k8-L2
constexpr size_t OFF_H1B    = (size_t)28 << 20;   // bf16 h1  (4MB), dead before k8-L3
constexpr size_t OFF_H2B    = (size_t)24 << 20;   // bf16 h2  (4MB, reuses XB), dead before k8-L3
constexpr size_t OFF_COLS   = (size_t)32 << 20;   // u16 [B][EMAX]  (2MB)
constexpr size_t OFF_PACKED = (size_t)34 << 20;   // u32 [B][EMAX]  (4MB)
constexpr size_t OFF_RP     = (size_t)38 << 20;   // u32 [B][RPS]
constexpr size_t OFF_DEG0   = OFF_RP   + ((size_t)128 << 10);
constexpr size_t OFF_DEGF   = OFF_DEG0 + ((size_t)64  << 10);
constexpr size_t OFF_RMASK  = OFF_DEGF + ((size_t)64  << 10);  // u32 [B][N][4] (256KB)
constexpr size_t OFF_BN     = OFF_RMASK + ((size_t)256 << 10); // 3*256 floats
constexpr size_t OFF_WHI    = OFF_BN  + ((size_t)4 << 10);     // 147456 u16
constexpr size_t OFF_WLO    = OFF_WHI + ((size_t)304 << 10);   // 147456 u16

typedef __attribute__((ext_vector_type(8))) short short8v;
typedef __attribute__((ext_vector_type(4))) float f32x4;

__device__ __forceinline__ uint16_t bf16rne(float f) {
    uint32_t u = __float_as_uint(f);
    return (uint16_t)((u + 0x7FFFu + ((u >> 16) & 1u)) >> 16);
}

// ---------------- KW: weight split to bf16 hi/lo frags + x->bf16 copy -------
__global__ __launch_bounds__(256) void kW_prep(
        const float* __restrict__ Wr1, const float* __restrict__ Wx1,
        const float* __restrict__ Wr2, const float* __restrict__ Wx2,
        const float* __restrict__ Wr3, const float* __restrict__ Wx3,
        const float* __restrict__ Wl,
        uint16_t* __restrict__ whi, uint16_t* __restrict__ wlo,
        float* __restrict__ bn,
        const float* __restrict__ x, uint16_t* __restrict__ xb) {
    if (blockIdx.x >= 128) {
        size_t i = ((size_t)(blockIdx.x - 128) * 256 + threadIdx.x) * 4;
        float4 v = *(const float4*)&x[i];
        ushort4 o;
        o.x = bf16rne(v.x); o.y = bf16rne(v.y);
        o.z = bf16rne(v.z); o.w = bf16rne(v.w);
        *(ushort4*)&xb[i] = o;
        return;
    }
    if (blockIdx.x == 0) {
        for (int i = threadIdx.x; i < 768; i += 256) bn[i] = 0.f;
    }
    int g  = blockIdx.x >> 5;          // 0..3: L1,L2,L3,Wl
    int lb = blockIdx.x & 31;
    int K = (g == 3) ? 384 : 256;
    const float* A  = (g == 0) ? Wr1 : (g == 1) ? Wr2 : (g == 2) ? Wr3 : Wl;
    const float* Bw = (g == 0) ? Wx1 : (g == 1) ? Wx2 : (g == 2) ? Wx3 : nullptr;
    size_t base = (g == 3) ? (size_t)98304 : (size_t)g * 32768;
    int total = K * 128;
    for (int f = lb * 256 + threadIdx.x; f < total; f += 32 * 256) {
        int e = f & 7, lane = (f >> 3) & 63, ct = (f >> 9) & 7, ks = f >> 12;
        int k = ks * 32 + ((lane >> 4) << 3) + e;
        int col = (ct << 4) + (lane & 15);
        float v = (g == 3 || k < 128) ? A[(size_t)k * 128 + col]
                                      : Bw[(size_t)(k - 128) * 128 + col];
        uint32_t hi = bf16rne(v);
        float hf = __uint_as_float(hi << 16);
        whi[base + f] = (uint16_t)hi;
        wlo[base + f] = bf16rne(v - hf);
    }
}

// ---------------- K1: adj (fp32 0/1) -> bitset + degrees ----------------
__global__ __launch_bounds__(256) void k1_bitset(const float* __restrict__ adj,
        uint32_t* __restrict__ bitset, uint32_t* __restrict__ deg0) {
    int row  = blockIdx.x * 4 + (threadIdx.x >> 6);
    int lane = threadIdx.x & 63;
    const float* ar = adj + (size_t)row * N_;
    uint32_t myw = 0;
    #pragma unroll 4
    for (int it = 0; it < 32; ++it) {
        float v = ar[it * 64 + lane];
        unsigned long long m = __ballot(v != 0.0f);
        if (lane == 2 * it)          myw = (uint32_t)m;
        else if (lane == 2 * it + 1) myw = (uint32_t)(m >> 32);
    }
    bitset[(size_t)row * NW + lane] = myw;
    int pc = __popc(myw);
    #pragma unroll
    for (int off = 32; off >= 1; off >>= 1) pc += __shfl_xor(pc, off);
    if (lane == 0) deg0[row] = (uint32_t)pc;
}

// ---------------- K2: per-batch prefix sum of degrees -> rowptr ----------------
__global__ __launch_bounds__(256) void k2_rowptr(const uint32_t* __restrict__ deg0,
        uint32_t* __restrict__ rowptr) {
    int b = blockIdx.x, t = threadIdx.x;
    __shared__ uint32_t tsum[256];
    uint32_t v[8]; uint32_t s = 0;
    #pragma unroll
    for (int j = 0; j < 8; ++j) { v[j] = deg0[b * N_ + t * 8 + j]; s += v[j]; v[j] = s; }
    tsum[t] = s;
    __syncthreads();
    for (int off = 1; off < 256; off <<= 1) {
        uint32_t xv = (t >= off) ? tsum[t - off] : 0u;
        __syncthreads();
        tsum[t] += xv;
        __syncthreads();
    }
    uint32_t excl = tsum[t] - s;
    uint32_t* rp = rowptr + (size_t)b * RPS;
    if (t == 0) rp[0] = 0;
    #pragma unroll
    for (int j = 0; j < 8; ++j) {
        uint32_t val = excl + v[j];
        if (val > (uint32_t)EMAX) val = EMAX;
        rp[t * 8 + j + 1] = val;
    }
}

// ---------------- K3: fill sorted column lists ----------------
__global__ __launch_bounds__(256) void k3_cols(const uint32_t* __restrict__ bitset,
        const uint32_t* __restrict__ rowptr, uint16_t* __restrict__ cols) {
    int row  = blockIdx.x * 4 + (threadIdx.x >> 6);
    int lane = threadIdx.x & 63;
    int b = row >> 11, n = row & (N_ - 1);
    uint32_t w = bitset[(size_t)row * NW + lane];
    uint32_t pc = __popc(w);
    uint32_t inc = pc;
    #pragma unroll
    for (int off = 1; off < 64; off <<= 1) {
        uint32_t t = __shfl_up(inc, off);
        if (lane >= off) inc += t;
    }
    uint32_t base = rowptr[(size_t)b * RPS + n] + (inc - pc);
    uint16_t* cb = cols + (size_t)b * EMAX;
    while (w) {
        int bit = __builtin_ctz(w); w &= w - 1;
        if (base < (uint32_t)EMAX) cb[base] = (uint16_t)(lane * 32 + bit);
        ++base;
    }
}

// ---------------- K4: packed (col | mate_local<<16) via binary search ----------------
__global__ __launch_bounds__(256) void k4_packed(const uint16_t* __restrict__ cols,
        const uint32_t* __restrict__ rowptr, uint32_t* __restrict__ packed) {
    int row  = blockIdx.x * 4 + (threadIdx.x >> 6);
    int lane = threadIdx.x & 63;
    int b = row >> 11, n = row & (N_ - 1);
    const uint32_t* rpb = rowptr + (size_t)b * RPS;
    const uint16_t* cb  = cols + (size_t)b * EMAX;
    uint32_t start = rpb[n], end = rpb[n + 1];
    for (uint32_t e = start + lane; e < end; e += 64) {
        uint32_t j = cb[e];
        uint32_t lo = rpb[j], hi = rpb[j + 1];
        uint32_t rj = lo;
        while (lo < hi) {
            uint32_t mid = (lo + hi) >> 1;
            if ((int)cb[mid] < n) lo = mid + 1; else hi = mid;
        }
        packed[(size_t)b * EMAX + e] = j | ((lo - rj) << 16);
    }
}

// ---------------- K5: DAG-parallel dilation (16 waves per batch) ----------------
// Async-spin core with wave-uniform cnt<=64 fast path (R13: 87us). Tail writes
// rank masks + degf; compaction is the separate parallel k6 (serial-tail
// fusion was R12's regression; skip-dead gather was R13's).
#define K5_ISSUE(PK0, PK1, CNT, ROW)                                        \
    do {                                                                    \
        int rr_ = (ROW);                                                    \
        if (rr_ < N_) {                                                     \
            uint32_t ldI_ = rps[rr_], enI_ = rps[rr_ + 1];                  \
            CNT = (int)(enI_ - ldI_);                                       \
            PK0 = (lane < CNT) ? pkg[ldI_ + lane] : 0xFFFFFFFFu;            \
            if (CNT > 64)                                                   \
                PK1 = (lane + 64 < CNT) ? pkg[ldI_ + 64 + lane] : 0xFFFFFFFFu; \
            else PK1 = 0xFFFFFFFFu;                                         \
        } else { CNT = 0; PK0 = 0xFFFFFFFFu; PK1 = 0xFFFFFFFFu; }           \
    } while (0)

#define K5_PROC(PK0, PK1, CNT, NROW)                                        \
    do {                                                                    \
        int nr_ = (NROW);                                                   \
        if (CNT <= 64) {                                                    \
            /* ---------- fast path: deg <= 64 ---------- */                \
            uint32_t c0_ = PK0 & 0xFFFFu;                                   \
            bool e0_ = (lane < CNT) && (c0_ < (uint32_t)nr_);               \
            while (true) {                                                  \
                uint32_t d0_ = e0_ ? __hip_atomic_load(&done[c0_ >> 5],     \
                        __ATOMIC_ACQUIRE, __HIP_MEMORY_SCOPE_WORKGROUP) : 0u; \
                bool ok0_ = !e0_ || ((d0_ >> (c0_ & 31)) & 1u);             \
                if (__all((int)ok0_)) break;                                \
            }                                                               \
            __builtin_amdgcn_s_setprio(1);                                  \
            uint2 mc_ = *(const uint2*)&rm4[(size_t)nr_ * 4];               \
            uint32_t w01_ = (lane < 32) ? mc_.x : mc_.y;                    \
            uint32_t a0_ = (w01_ >> (lane & 31)) & 1u;                      \
            unsigned long long bl0_ = __ballot(a0_ != 0);                   \
            uint32_t num_ = (uint32_t)__popcll(bl0_);                       \
            if (mk[nr_] && num_ > 1u) {                                     \
                bool allrm_ = num_ <= (uint32_t)TDIL;                       \
                uint32_t sf_ = (num_ + 1u) >> 1;                            \
                uint32_t r2_ = (num_ & 1u) ? 0xFFFFFFFFu : num_;            \
                uint32_t rank0_ = (uint32_t)__popcll(bl0_ & below) + 1u;    \
                bool rm0_ = a0_ && (allrm_ || rank0_ == sf_ || rank0_ == r2_); \
                unsigned long long rb0_ = __ballot(rm0_);                   \
                if (rm0_) {                                                 \
                    uint32_t ml_ = PK0 >> 16;                               \
                    if (ml_ < 128u) atomicAnd(&rm4[c0_ * 4 + (ml_ >> 5)], ~(1u << (ml_ & 31))); \
                }                                                           \
                if (lane == 0) {                                            \
                    uint2 nm_;                                              \
                    nm_.x = mc_.x & ~(uint32_t)rb0_;                        \
                    nm_.y = mc_.y & ~(uint32_t)(rb0_ >> 32);                \
                    *(uint2*)&rm4[(size_t)nr_ * 4] = nm_;                   \
                }                                                           \
            }                                                               \
            __asm__ __volatile__("" ::: "memory");                          \
            if (lane == 0)                                                  \
                __hip_atomic_fetch_or(&done[nr_ >> 5], 1u << (nr_ & 31),    \
                        __ATOMIC_RELAXED, __HIP_MEMORY_SCOPE_WORKGROUP);    \
            __builtin_amdgcn_s_setprio(0);                                  \
        } else {                                                            \
            /* ---------- slow path: deg > 64 (rare) ---------- */          \
            uint32_t c0_ = PK0 & 0xFFFFu, c1_ = PK1 & 0xFFFFu;              \
            bool e0_ = (lane < CNT)      && (c0_ < (uint32_t)nr_);          \
            bool e1_ = (lane + 64 < CNT) && (c1_ < (uint32_t)nr_);          \
            while (true) {                                                  \
                uint32_t d0_ = e0_ ? __hip_atomic_load(&done[c0_ >> 5],     \
                        __ATOMIC_ACQUIRE, __HIP_MEMORY_SCOPE_WORKGROUP) : 0u; \
                uint32_t d1_ = e1_ ? __hip_atomic_load(&done[c1_ >> 5],     \
                        __ATOMIC_ACQUIRE, __HIP_MEMORY_SCOPE_WORKGROUP) : 0u; \
                bool ok0_ = !e0_ || ((d0_ >> (c0_ & 31)) & 1u);             \
                bool ok1_ = !e1_ || ((d1_ >> (c1_ & 31)) & 1u);             \
                if (__all((int)(ok0_ && ok1_))) break;                      \
            }                                                               \
            __builtin_amdgcn_s_setprio(1);                                  \
            uint4 mcur_ = *(const uint4*)&rm4[(size_t)nr_ * 4];             \
            uint32_t w01_ = (lane < 32) ? mcur_.x : mcur_.y;                \
            uint32_t w23_ = (lane < 32) ? mcur_.z : mcur_.w;                \
            uint32_t a0_ = (w01_ >> (lane & 31)) & 1u;                      \
            uint32_t a1_ = (w23_ >> (lane & 31)) & 1u;                      \
            unsigned long long bl0_ = __ballot(a0_ != 0), bl1_ = __ballot(a1_ != 0); \
            uint32_t num_ = (uint32_t)__popcll(bl0_) + (uint32_t)__popcll(bl1_); \
            if (mk[nr_] && num_ > 1u) {                                     \
                bool allrm_ = num_ <= (uint32_t)TDIL;                       \
                uint32_t sf_ = (num_ + 1u) >> 1;                            \
                uint32_t r2_ = (num_ & 1u) ? 0xFFFFFFFFu : num_;            \
                uint32_t rank0_ = (uint32_t)__popcll(bl0_ & below) + 1u;    \
                uint32_t rank1_ = (uint32_t)__popcll(bl0_) +                \
                                  (uint32_t)__popcll(bl1_ & below) + 1u;    \
                bool rm0_ = a0_ && (allrm_ || rank0_ == sf_ || rank0_ == r2_); \
                bool rm1_ = a1_ && (allrm_ || rank1_ == sf_ || rank1_ == r2_); \
                unsigned long long rb0_ = __ballot(rm0_), rb1_ = __ballot(rm1_); \
                if (rm0_) {                                                 \
                    uint32_t ml_ = PK0 >> 16;                               \
                    if (ml_ < 128u) atomicAnd(&rm4[c0_ * 4 + (ml_ >> 5)], ~(1u << (ml_ & 31))); \
                }                                                           \
                if (rm1_) {                                                 \
                    uint32_t ml_ = PK1 >> 16;                               \
                    if (ml_ < 128u) atomicAnd(&rm4[c1_ * 4 + (ml_ >> 5)], ~(1u << (ml_ & 31))); \
                }                                                           \
                if (lane == 0) {                                            \
                    uint4 nm_;                                              \
                    nm_.x = mcur_.x & ~(uint32_t)rb0_;                      \
                    nm_.y = mcur_.y & ~(uint32_t)(rb0_ >> 32);              \
                    nm_.z = mcur_.z & ~(uint32_t)rb1_;                      \
                    nm_.w = mcur_.w & ~(uint32_t)(rb1_ >> 32);              \
                    *(uint4*)&rm4[(size_t)nr_ * 4] = nm_;                   \
                }                                                           \
            }                                                               \
            __asm__ __volatile__("" ::: "memory");                          \
            if (lane == 0)                                                  \
                __hip_atomic_fetch_or(&done[nr_ >> 5], 1u << (nr_ & 31),    \
                        __ATOMIC_RELAXED, __HIP_MEMORY_SCOPE_WORKGROUP);    \
            __builtin_amdgcn_s_setprio(0);                                  \
        }                                                                   \
    } while (0)

__global__ __launch_bounds__(1024) void k5_dilate(
        const uint32_t* __restrict__ packed, const uint32_t* __restrict__ rowptr,
        const uint32_t* __restrict__ deg0, const int* __restrict__ mask,
        uint32_t* __restrict__ rmaskg, uint32_t* __restrict__ degf) {
    int b = blockIdx.x;
    int tid = threadIdx.x;
    int lane = tid & 63;
    int wv = tid >> 6;                                // 0..15
    __shared__ __align__(16) uint32_t rm4[N_ * 4];    // 32KB
    __shared__ uint32_t rps[N_ + 1];                  // 8.2KB
    __shared__ uint8_t  mk[N_];                       // 2KB
    __shared__ uint32_t done[64];                     // 2048 done-bits
    const uint32_t* pkg = packed + (size_t)b * EMAX;
    const uint32_t* rpg = rowptr + (size_t)b * RPS;

    for (int i = tid; i <= N_; i += 1024) rps[i] = rpg[i];
    if (tid < 64) done[tid] = 0u;
    for (int i = tid; i < N_; i += 1024) {
        int d = (int)deg0[b * N_ + i]; if (d > 128) d = 128;
        uint4 mm;
        mm.x = (d >= 32) ? ~0u : ((d > 0)  ? ((1u << d)        - 1u) : 0u);
        mm.y = (d >= 64) ? ~0u : ((d > 32) ? ((1u << (d - 32)) - 1u) : 0u);
        mm.z = (d >= 96) ? ~0u : ((d > 64) ? ((1u << (d - 64)) - 1u) : 0u);
        mm.w = (d >= 128)? ~0u : ((d > 96) ? ((1u << (d - 96)) - 1u) : 0u);
        *(uint4*)&rm4[(size_t)i * 4] = mm;
        mk[i] = (uint8_t)(mask[b * N_ + i] != 0);
    }
    __syncthreads();

    unsigned long long below = (1ULL << lane) - 1ULL;
    int cntA, cntB, cntC;
    uint32_t pkA0, pkA1, pkB0, pkB1, pkC0, pkC1;
    K5_ISSUE(pkA0, pkA1, cntA, wv);
    K5_ISSUE(pkB0, pkB1, cntB, wv + 16);
    K5_ISSUE(pkC0, pkC1, cntC, wv + 32);

    int n = wv;
    while (n < N_) {
        K5_PROC(pkA0, pkA1, cntA, n);
        K5_ISSUE(pkA0, pkA1, cntA, n + 48);
        n += 16; if (n >= N_) break;
        K5_PROC(pkB0, pkB1, cntB, n);
        K5_ISSUE(pkB0, pkB1, cntB, n + 48);
        n += 16; if (n >= N_) break;
        K5_PROC(pkC0, pkC1, cntC, n);
        K5_ISSUE(pkC0, pkC1, cntC, n + 48);
        n += 16;
    }
    __syncthreads();
    for (int i = tid; i < N_; i += 1024) {
        uint4 mm = *(const uint4*)&rm4[(size_t)i * 4];
        *(uint4*)&rmaskg[((size_t)b * N_ + i) * 4] = mm;
        degf[b * N_ + i] = (uint32_t)(__popc(mm.x) + __popc(mm.y) + __popc(mm.z) + __popc(mm.w));
    }
}

// ---------------- K6: compact surviving cols in place (parallel, R11) --------
__global__ __launch_bounds__(256) void k6_compact(uint16_t* __restrict__ cols,
        const uint32_t* __restrict__ rowptr, const uint32_t* __restrict__ rmaskg) {
    int row  = blockIdx.x * 4 + (threadIdx.x >> 6);
    int lane = threadIdx.x & 63;
    int b = row >> 11, n = row & (N_ - 1);
    uint16_t* cb = cols + (size_t)b * EMAX;
    uint4 mm = *(const uint4*)&rmaskg[(size_t)row * 4];
    uint32_t st = rowptr[(size_t)b * RPS + n];
    uint32_t w01 = (lane < 32) ? mm.x : mm.y;
    uint32_t w23 = (lane < 32) ? mm.z : mm.w;
    uint32_t a0 = (w01 >> (lane & 31)) & 1u;
    uint32_t a1 = (w23 >> (lane & 31)) & 1u;
    unsigned long long b0 = __ballot(a0 != 0), b1 = __ballot(a1 != 0);
    unsigned long long below = (1ULL << lane) - 1ULL;
    uint16_t c0v = 0, c1v = 0;
    if (a0) c0v = cb[st + lane];
    if (a1) c1v = cb[st + 64 + lane];
    uint32_t i0 = st + (uint32_t)__popcll(b0 & below);
    uint32_t i1 = st + (uint32_t)__popcll(b0) + (uint32_t)__popcll(b1 & below);
    if (a0) cb[i0] = c0v;
    if (a1) cb[i1] = c1v;
}

// ---------------- K7: SpMM mean-aggregate over bf16 features (R11) ----------
__global__ __launch_bounds__(256) void k7_spmm(const uint16_t* __restrict__ Xb16,
        const uint16_t* __restrict__ cols, const uint32_t* __restrict__ rowptr,
        const uint32_t* __restrict__ degf, float* __restrict__ agg) {
    int wid  = blockIdx.x * 4 + (threadIdx.x >> 6);
    int lane = threadIdx.x & 63;
    int b = wid >> 11, n = wid & (N_ - 1);
    const uint16_t* cb = cols + (size_t)b * EMAX;
    uint32_t start = rowptr[(size_t)b * RPS + n];
    uint32_t cnt = degf[wid];
    const uint16_t* Xb = Xb16 + ((size_t)b * N_) * D_;
    float ax = 0.f, ay = 0.f;
    for (uint32_t base = 0; base < cnt; base += 64) {
        int idx = (int)base + lane;
        int cl = (idx < (int)cnt) ? (int)cb[start + idx] : 0;
        int kmax = (int)cnt - (int)base; if (kmax > 64) kmax = 64;
        int k = 0;
        for (; k + 4 <= kmax; k += 4) {
            int cA = __shfl(cl, k),     cB = __shfl(cl, k + 1);
            int cC = __shfl(cl, k + 2), cD = __shfl(cl, k + 3);
            uint32_t uA = ((const uint32_t*)(Xb + (size_t)cA * D_))[lane];
            uint32_t uB = ((const uint32_t*)(Xb + (size_t)cB * D_))[lane];
            uint32_t uC = ((const uint32_t*)(Xb + (size_t)cC * D_))[lane];
            uint32_t uD = ((const uint32_t*)(Xb + (size_t)cD * D_))[lane];
            ax += __uint_as_float(uA << 16) + __uint_as_float(uB << 16)
                + __uint_as_float(uC << 16) + __uint_as_float(uD << 16);
            ay += __uint_as_float(uA & 0xFFFF0000u) + __uint_as_float(uB & 0xFFFF0000u)
                + __uint_as_float(uC & 0xFFFF0000u) + __uint_as_float(uD & 0xFFFF0000u);
        }
        for (; k < kmax; ++k) {
            int c = __shfl(cl, k);
            uint32_t u = ((const uint32_t*)(Xb + (size_t)c * D_))[lane];
            ax += __uint_as_float(u << 16);
            ay += __uint_as_float(u & 0xFFFF0000u);
        }
    }
    float inv = 1.0f / (float)(cnt ? cnt : 1u);
    ((float2*)(agg + (size_t)wid * D_))[lane] = make_float2(ax * inv, ay * inv);
}

// ---------------- bf16 split helper ----------------
__device__ __forceinline__ void cvt_store4(uint16_t* hiA, uint16_t* loA,
                                           int idx, float4 v) {
    float vv[4] = {v.x, v.y, v.z, v.w};
    ushort4 hs, ls;
    uint16_t* hp = (uint16_t*)&hs; uint16_t* lp = (uint16_t*)&ls;
    #pragma unroll
    for (int i = 0; i < 4; ++i) {
        uint32_t hi = bf16rne(vv[i]);
        float hf = __uint_as_float(hi << 16);
        hp[i] = (uint16_t)hi;
        lp[i] = bf16rne(vv[i] - hf);
    }
    *(ushort4*)&hiA[idx] = hs;
    *(ushort4*)&loA[idx] = ls;
}

// ---------------- K8: fused SAGE via bf16x3 MFMA ----------------
constexpr int ASTR = 264;   // shorts per row (256 + 8 pad)
__global__ __launch_bounds__(256) void k8_mfma(const float* __restrict__ agg,
        const float* __restrict__ Hin,
        const uint16_t* __restrict__ whi, const uint16_t* __restrict__ wlo,
        const float* __restrict__ bias, const int* __restrict__ mask,
        const float* __restrict__ bnp, const float* __restrict__ gp,
        const float* __restrict__ bep, int use_bn,
        float* __restrict__ P, uint16_t* __restrict__ Pb,
        float* __restrict__ bnstat) {
    __shared__ __align__(16) char buf[2 * 32 * ASTR * 2];   // 33792B
    __shared__ float scL[128], shL[128];
    uint16_t* aHi = (uint16_t*)buf;
    uint16_t* aLo = (uint16_t*)(buf + 32 * ASTR * 2);
    float* outP = (float*)buf;                              // overlay after MFMA
    int tid = threadIdx.x, lane = tid & 63, h = tid >> 6;
    size_t row0 = (size_t)blockIdx.x * 32;

    if (tid < 128) {
        float sc = 1.f, sh = 0.f;
        if (use_bn) {
            float mean = bnp[tid] * (1.f / 16384.f);
            float var  = bnp[128 + tid] * (1.f / 16384.f) - mean * mean;
            sc = gp[tid] * rsqrtf(var + 1e-5f);
            sh = bep[tid] - mean * sc;
        }
        scL[tid] = sc; shL[tid] = sh;
    }
    __syncthreads();

    for (int f = tid * 4; f < 4096; f += 1024) {
        int r = f >> 7, c = f & 127;
        float4 va = *(const float4*)&agg[(row0 + r) * 128 + c];
        float4 vx = *(const float4*)&Hin[(row0 + r) * 128 + c];
        float4 s4 = *(const float4*)&scL[c];
        float4 h4 = *(const float4*)&shL[c];
        va.x = va.x * s4.x + h4.x; va.y = va.y * s4.y + h4.y;
        va.z = va.z * s4.z + h4.z; va.w = va.w * s4.w + h4.w;
        vx.x = vx.x * s4.x + h4.x; vx.y = vx.y * s4.y + h4.y;
        vx.z = vx.z * s4.z + h4.z; vx.w = vx.w * s4.w + h4.w;
        cvt_store4(aHi, aLo, r * ASTR + c, va);
        cvt_store4(aHi, aLo, r * ASTR + 128 + c, vx);
    }
    __syncthreads();

    f32x4 acc00 = {0.f,0.f,0.f,0.f}, acc01 = acc00, acc10 = acc00, acc11 = acc00;
    int ct0 = h * 2, ct1 = h * 2 + 1;
    int arow = (lane & 15);
    int koff = (lane >> 4) * 8;
    #pragma unroll
    for (int ks = 0; ks < 8; ++ks) {
        int k0 = ks * 32 + koff;
        short8v a0h = *(short8v*)&aHi[arow * ASTR + k0];
        short8v a0l = *(short8v*)&aLo[arow * ASTR + k0];
        short8v a1h = *(short8v*)&aHi[(arow + 16) * ASTR + k0];
        short8v a1l = *(short8v*)&aLo[(arow + 16) * ASTR + k0];
        short8v b0h = *(const short8v*)&whi[(size_t)(((ks * 8 + ct0) << 6) + lane) * 8];
        short8v b0l = *(const short8v*)&wlo[(size_t)(((ks * 8 + ct0) << 6) + lane) * 8];
        short8v b1h = *(const short8v*)&whi[(size_t)(((ks * 8 + ct1) << 6) + lane) * 8];
        short8v b1l = *(const short8v*)&wlo[(size_t)(((ks * 8 + ct1) << 6) + lane) * 8];
        acc00 = __builtin_amdgcn_mfma_f32_16x16x32_bf16(a0h, b0h, acc00, 0, 0, 0);
        acc00 = __builtin_amdgcn_mfma_f32_16x16x32_bf16(a0h, b0l, acc00, 0, 0, 0);
        acc00 = __builtin_amdgcn_mfma_f32_16x16x32_bf16(a0l, b0h, acc00, 0, 0, 0);
        acc01 = __builtin_amdgcn_mfma_f32_16x16x32_bf16(a0h, b1h, acc01, 0, 0, 0);
        acc01 = __builtin_amdgcn_mfma_f32_16x16x32_bf16(a0h, b1l, acc01, 0, 0, 0);
        acc01 = __builtin_amdgcn_mfma_f32_16x16x32_bf16(a0l, b1h, acc01, 0, 0, 0);
        acc10 = __builtin_amdgcn_mfma_f32_16x16x32_bf16(a1h, b0h, acc10, 0, 0, 0);
        acc10 = __builtin_amdgcn_mfma_f32_16x16x32_bf16(a1h, b0l, acc10, 0, 0, 0);
        acc10 = __builtin_amdgcn_mfma_f32_16x16x32_bf16(a1l, b0h, acc10, 0, 0, 0);
        acc11 = __builtin_amdgcn_mfma_f32_16x16x32_bf16(a1h, b1h, acc11, 0, 0, 0);
        acc11 = __builtin_amdgcn_mfma_f32_16x16x32_bf16(a1h, b1l, acc11, 0, 0, 0);
        acc11 = __builtin_amdgcn_mfma_f32_16x16x32_bf16(a1l, b1h, acc11, 0, 0, 0);
    }
    __syncthreads();

    int orow = (lane >> 4) * 4;
    int oc0 = ct0 * 16 + (lane & 15);
    int oc1 = ct1 * 16 + (lane & 15);
    #pragma unroll
    for (int j = 0; j < 4; ++j) {
        outP[(orow + j) * 128 + oc0]      = acc00[j];
        outP[(orow + j) * 128 + oc1]      = acc01[j];
        outP[(16 + orow + j) * 128 + oc0] = acc10[j];
        outP[(16 + orow + j) * 128 + oc1] = acc11[j];
    }
    __syncthreads();

    float bs0 = bias[lane], bs1 = bias[lane + 64];
    #pragma unroll
    for (int i = 0; i < 8; ++i) {
        int r = h * 8 + i;
        float v0 = outP[r * 128 + lane] + bs0;
        float v1 = outP[r * 128 + lane + 64] + bs1;
        float s = v0 * v0 + v1 * v1;
        #pragma unroll
        for (int off = 32; off >= 1; off >>= 1) s += __shfl_xor(s, off);
        float nrm = fmaxf(sqrtf(s), 1e-12f);
        float mf = (mask[row0 + r] != 0) ? 1.f : 0.f;
        float inv = mf / nrm;
        float p0 = fmaxf(v0 * inv, 0.f), p1 = fmaxf(v1 * inv, 0.f);
        P[(row0 + r) * 128 + lane]      = p0;
        P[(row0 + r) * 128 + lane + 64] = p1;
        if (Pb) {
            Pb[(row0 + r) * 128 + lane]      = bf16rne(p0);
            Pb[(row0 + r) * 128 + lane + 64] = bf16rne(p1);
        }
        outP[r * 128 + lane] = p0; outP[r * 128 + lane + 64] = p1;
    }
    __syncthreads();
    if (tid < 128) {
        float s = 0.f, q = 0.f;
        #pragma unroll
        for (int r = 0; r < 32; ++r) { float v = outP[r * 128 + tid]; s += v; q += v * v; }
        atomicAdd(&bnstat[tid], s);
        atomicAdd(&bnstat[128 + tid], q);
    }
}

// ---------------- K11: final (concat BN(h_i) * mf) @ Wl + bl, * mf ----------
__global__ __launch_bounds__(256) void k11_final(const float* __restrict__ h1,
        const float* __restrict__ h2, const float* __restrict__ h3,
        const float* __restrict__ Wl, const float* __restrict__ bl,
        const int* __restrict__ mask, const float* __restrict__ bn,
        const float* __restrict__ g1, const float* __restrict__ be1,
        const float* __restrict__ g2, const float* __restrict__ be2,
        const float* __restrict__ g3, const float* __restrict__ be3,
        float* __restrict__ out) {
    __shared__ float s1[32 * 128], s2[32 * 128], s3[32 * 128];
    __shared__ float scA[128], shA[128], scB[128], shB[128], scC[128], shC[128];
    int tid = threadIdx.x;
    size_t row0 = (size_t)blockIdx.x * 32;
    if (tid < 128) {
        float m1 = bn[tid] * (1.f / 16384.f);
        float v1 = bn[128 + tid] * (1.f / 16384.f) - m1 * m1;
        scA[tid] = g1[tid] * rsqrtf(v1 + 1e-5f);
        shA[tid] = be1[tid] - m1 * scA[tid];
        float m2 = bn[256 + tid] * (1.f / 16384.f);
        float v2 = bn[384 + tid] * (1.f / 16384.f) - m2 * m2;
        scB[tid] = g2[tid] * rsqrtf(v2 + 1e-5f);
        shB[tid] = be2[tid] - m2 * scB[tid];
        float m3 = bn[512 + tid] * (1.f / 16384.f);
        float v3 = bn[640 + tid] * (1.f / 16384.f) - m3 * m3;
        scC[tid] = g3[tid] * rsqrtf(v3 + 1e-5f);
        shC[tid] = be3[tid] - m3 * scC[tid];
    }
    __syncthreads();
    for (int t = tid * 4; t < 32 * 128; t += 1024) {
        int r = t >> 7;
        float mf = (mask[row0 + r] != 0) ? 1.f : 0.f;
        int c = t & 127;
        float4 a = *(const float4*)&h1[row0 * 128 + t];
        float4 b = *(const float4*)&h2[row0 * 128 + t];
        float4 cc = *(const float4*)&h3[row0 * 128 + t];
        float4 sa = *(const float4*)&scA[c], ha = *(const float4*)&shA[c];
        float4 sb = *(const float4*)&scB[c], hb = *(const float4*)&shB[c];
        float4 sc = *(const float4*)&scC[c], hc = *(const float4*)&shC[c];
        a.x = (a.x * sa.x + ha.x) * mf; a.y = (a.y * sa.y + ha.y) * mf;
        a.z = (a.z * sa.z + ha.z) * mf; a.w = (a.w * sa.w + ha.w) * mf;
        b.x = (b.x * sb.x + hb.x) * mf; b.y = (b.y * sb.y + hb.y) * mf;
        b.z = (b.z * sb.z + hb.z) * mf; b.w = (b.w * sb.w + hb.w) * mf;
        cc.x = (cc.x * sc.x + hc.x) * mf; cc.y = (cc.y * sc.y + hc.y) * mf;
        cc.z = (cc.z * sc.z + hc.z) * mf; cc.w = (cc.w * sc.w + hc.w) * mf;
        *(float4*)&s1[t] = a; *(float4*)&s2[t] = b; *(float4*)&s3[t] = cc;
    }
    __syncthreads();
    int h = tid >> 6, c0 = (tid & 63) * 2;
    float2 acc[8];
    #pragma unroll
    for (int i = 0; i < 8; ++i) acc[i] = make_float2(0.f, 0.f);
    for (int k4 = 0; k4 < 128; k4 += 4) {
        float2 w1[4], w2[4], w3[4];
        #pragma unroll
        for (int kk = 0; kk < 4; ++kk) {
            w1[kk] = *(const float2*)&Wl[(k4 + kk) * 128 + c0];
            w2[kk] = *(const float2*)&Wl[(128 + k4 + kk) * 128 + c0];
            w3[kk] = *(const float2*)&Wl[(256 + k4 + kk) * 128 + c0];
        }
        #pragma unroll
        for (int i = 0; i < 8; ++i) {
            int r = h * 8 + i;
            float4 a = *(const float4*)&s1[r * 128 + k4];
            float4 b = *(const float4*)&s2[r * 128 + k4];
            float4 c = *(const float4*)&s3[r * 128 + k4];
            acc[i].x += a.x * w1[0].x + a.y * w1[1].x + a.z * w1[2].x + a.w * w1[3].x
                      + b.x * w2[0].x + b.y * w2[1].x + b.z * w2[2].x + b.w * w2[3].x
                      + c.x * w3[0].x + c.y * w3[1].x + c.z * w3[2].x + c.w * w3[3].x;
            acc[i].y += a.x * w1[0].y + a.y * w1[1].y + a.z * w1[2].y + a.w * w1[3].y
                      + b.x * w2[0].y + b.y * w2[1].y + b.z * w2[2].y + b.w * w2[3].y
                      + c.x * w3[0].y + c.y * w3[1].y + c.z * w3[2].y + c.w * w3[3].y;
        }
    }
    float bx = bl[c0], by = bl[c0 + 1];
    #pragma unroll
    for (int i = 0; i < 8; ++i) {
        int r = h * 8 + i;
        float mf = (mask[row0 + r] != 0) ? 1.f : 0.f;
        *(float2*)&out[(row0 + r) * 128 + c0] =
            make_float2((acc[i].x + bx) * mf, (acc[i].y + by) * mf);
    }
}

// ---------------- launch ----------------
extern "C" void kernel_launch(void* const* d_in, const int* in_sizes, int n_in,
                              void* d_out, int out_size, void* d_ws, size_t ws_size,
                              hipStream_t stream) {
    (void)in_sizes; (void)n_in; (void)out_size; (void)ws_size;
    const float* x    = (const float*)d_in[0];
    const float* adj  = (const float*)d_in[1];
    const int*   mask = (const int*)d_in[2];
    const float* Wr1 = (const float*)d_in[3],  *Wx1 = (const float*)d_in[4];
    const float* b1  = (const float*)d_in[5],  *g1  = (const float*)d_in[6],  *be1 = (const float*)d_in[7];
    const float* Wr2 = (const float*)d_in[8],  *Wx2 = (const float*)d_in[9];
    const float* b2  = (const float*)d_in[10], *g2  = (const float*)d_in[11], *be2 = (const float*)d_in[12];
    const float* Wr3 = (const float*)d_in[13], *Wx3 = (const float*)d_in[14];
    const float* b3  = (const float*)d_in[15], *g3  = (const float*)d_in[16], *be3 = (const float*)d_in[17];
    const float* Wl  = (const float*)d_in[18], *bl  = (const float*)d_in[19];

    char* ws = (char*)d_ws;
    uint32_t* bitset = (uint32_t*)(ws + OFF_BITSET);
    float*    agg    = (float*)(ws + OFF_AGG);
    float*    h1     = (float*)(ws + OFF_H1);
    float*    h2     = (float*)(ws + OFF_H2);
    float*    h3     = (float*)(ws + OFF_H3);
    uint16_t* xb     = (uint16_t*)(ws + OFF_XB);
    uint16_t* h1b    = (uint16_t*)(ws + OFF_H1B);
    uint16_t* h2b    = (uint16_t*)(ws + OFF_H2B);
    uint16_t* cols   = (uint16_t*)(ws + OFF_COLS);
    uint32_t* packed = (uint32_t*)(ws + OFF_PACKED);
    uint32_t* rp     = (uint32_t*)(ws + OFF_RP);
    uint32_t* deg0   = (uint32_t*)(ws + OFF_DEG0);
    uint32_t* degf   = (uint32_t*)(ws + OFF_DEGF);
    uint32_t* rmaskg = (uint32_t*)(ws + OFF_RMASK);
    float*    bn     = (float*)(ws + OFF_BN);
    uint16_t* whi    = (uint16_t*)(ws + OFF_WHI);
    uint16_t* wlo    = (uint16_t*)(ws + OFF_WLO);
    float*    out    = (float*)d_out;

    kW_prep   <<<2176, 256, 0, stream>>>(Wr1, Wx1, Wr2, Wx2, Wr3, Wx3, Wl,
                                         whi, wlo, bn, x, xb);
    k1_bitset <<<4096, 256, 0, stream>>>(adj, bitset, deg0);
    k2_rowptr <<<8,    256, 0, stream>>>(deg0, rp);
    k3_cols   <<<4096, 256, 0, stream>>>(bitset, rp, cols);
    k4_packed <<<4096, 256, 0, stream>>>(cols, rp, packed);
    k5_dilate <<<8,    1024, 0, stream>>>(packed, rp, deg0, mask, rmaskg, degf);
    k6_compact<<<4096, 256, 0, stream>>>(cols, rp, rmaskg);
    // layer 1 (gather bf16 x; identity affine)
    k7_spmm   <<<4096, 256, 0, stream>>>(xb,  cols, rp, degf, agg);
    k8_mfma   <<<512,  256, 0, stream>>>(agg, x,  whi,         wlo,         b1, mask,
                                         bn, g1, be1, 0, h1, h1b, bn + 0);
    // layer 2 (gather bf16 h1; BN1 affine on the fly)
    k7_spmm   <<<4096, 256, 0, stream>>>(h1b, cols, rp, degf, agg);
    k8_mfma   <<<512,  256, 0, stream>>>(agg, h1, whi + 32768, wlo + 32768, b2, mask,
                                         bn + 0, g1, be1, 1, h2, h2b, bn + 256);
    // layer 3 (gather bf16 h2; BN2 affine on the fly)
    k7_spmm   <<<4096, 256, 0, stream>>>(h2b, cols, rp, degf, agg);
    k8_mfma   <<<512,  256, 0, stream>>>(agg, h2, whi + 65536, wlo + 65536, b3, mask,
                                         bn + 256, g2, be2, 1, h3, nullptr, bn + 512);
    // final
    k11_final <<<512,  256, 0, stream>>>(h1, h2, h3, Wl, bl, mask, bn,
                                         g1, be1, g2, be2, g3, be3, out);
}

// Round 15
// 285.990 us; speedup vs baseline: 1.2565x; 1.0233x over previous
//
#include <hip/hip_runtime.h>
#include <cstdint>

// ---------------- problem constants ----------------
constexpr int B_ = 8, N_ = 2048, D_ = 128, NW = 64;   // NW = words per bitset row
constexpr int EMAX = 131072;                           // per-batch edge capacity
constexpr int RPS = 2064;                              // rowptr stride per batch
constexpr int TDIL = 10;

// ---------------- workspace layout (bytes) ----------------
constexpr size_t OFF_BITSET = 0;                  // 4MB (preproc), reused as agg (8MB)
constexpr size_t OFF_AGG    = 0;
constexpr size_t OFF_H1     = (size_t)8  << 20;
constexpr size_t OFF_H2     = (size_t)16 << 20;
constexpr size_t OFF_H3     = (size_t)24 << 20;   // h3 (8MB); earlier: xb/h1b/h2b bf16
constexpr size_t OFF_XB     = (size_t)24 << 20;   // bf16 x   (4MB), dead before k8-L2
constexpr size_t OFF_H1B    = (size_t)28 << 20;   // bf16 h1  (4MB), dead before k8-L3
constexpr size_t OFF_H2B    = (size_t)24 << 20;   // bf16 h2  (4MB, reuses XB), dead before k8-L3
constexpr size_t OFF_COLS   = (size_t)32 << 20;   // u16 [B][EMAX]  (2MB)
constexpr size_t OFF_PACKED = (size_t)34 << 20;   // u32 [B][EMAX]  (4MB)
constexpr size_t OFF_RP     = (size_t)38 << 20;   // u32 [B][RPS]
constexpr size_t OFF_DEG0   = OFF_RP   + ((size_t)128 << 10);
constexpr size_t OFF_DEGF   = OFF_DEG0 + ((size_t)64  << 10);
constexpr size_t OFF_RMASK  = OFF_DEGF + ((size_t)64  << 10);  // u32 [B][N][4] (256KB)
constexpr size_t OFF_BN     = OFF_RMASK + ((size_t)256 << 10); // 3*256 floats
constexpr size_t OFF_WHI    = OFF_BN  + ((size_t)4 << 10);     // 147456 u16
constexpr size_t OFF_WLO    = OFF_WHI + ((size_t)304 << 10);   // 147456 u16

typedef __attribute__((ext_vector_type(8))) short short8v;
typedef __attribute__((ext_vector_type(4))) float f32x4;

__device__ __forceinline__ uint16_t bf16rne(float f) {
    uint32_t u = __float_as_uint(f);
    return (uint16_t)((u + 0x7FFFu + ((u >> 16) & 1u)) >> 16);
}

// ---------------- KP: fused prep — weights split + x->bf16 + adj->bitset ----
// blocks 0..127: weight prep. blocks 128..2175: xb conversion.
// blocks 2176..6271: k1 (adj -> bitset + deg0).
__global__ __launch_bounds__(256) void kP_prep(
        const float* __restrict__ Wr1, const float* __restrict__ Wx1,
        const float* __restrict__ Wr2, const float* __restrict__ Wx2,
        const float* __restrict__ Wr3, const float* __restrict__ Wx3,
        const float* __restrict__ Wl,
        uint16_t* __restrict__ whi, uint16_t* __restrict__ wlo,
        float* __restrict__ bn,
        const float* __restrict__ x, uint16_t* __restrict__ xb,
        const float* __restrict__ adj, uint32_t* __restrict__ bitset,
        uint32_t* __restrict__ deg0) {
    if (blockIdx.x >= 2176) {
        // ---- k1: adj (fp32 0/1) -> bitset + degrees ----
        int row  = (blockIdx.x - 2176) * 4 + (threadIdx.x >> 6);
        int lane = threadIdx.x & 63;
        const float* ar = adj + (size_t)row * N_;
        uint32_t myw = 0;
        #pragma unroll 4
        for (int it = 0; it < 32; ++it) {
            float v = ar[it * 64 + lane];
            unsigned long long m = __ballot(v != 0.0f);
            if (lane == 2 * it)          myw = (uint32_t)m;
            else if (lane == 2 * it + 1) myw = (uint32_t)(m >> 32);
        }
        bitset[(size_t)row * NW + lane] = myw;
        int pc = __popc(myw);
        #pragma unroll
        for (int off = 32; off >= 1; off >>= 1) pc += __shfl_xor(pc, off);
        if (lane == 0) deg0[row] = (uint32_t)pc;
        return;
    }
    if (blockIdx.x >= 128) {
        size_t i = ((size_t)(blockIdx.x - 128) * 256 + threadIdx.x) * 4;
        float4 v = *(const float4*)&x[i];
        ushort4 o;
        o.x = bf16rne(v.x); o.y = bf16rne(v.y);
        o.z = bf16rne(v.z); o.w = bf16rne(v.w);
        *(ushort4*)&xb[i] = o;
        return;
    }
    if (blockIdx.x == 0) {
        for (int i = threadIdx.x; i < 768; i += 256) bn[i] = 0.f;
    }
    int g  = blockIdx.x >> 5;          // 0..3: L1,L2,L3,Wl
    int lb = blockIdx.x & 31;
    int K = (g == 3) ? 384 : 256;
    const float* A  = (g == 0) ? Wr1 : (g == 1) ? Wr2 : (g == 2) ? Wr3 : Wl;
    const float* Bw = (g == 0) ? Wx1 : (g == 1) ? Wx2 : (g == 2) ? Wx3 : nullptr;
    size_t base = (g == 3) ? (size_t)98304 : (size_t)g * 32768;
    int total = K * 128;
    for (int f = lb * 256 + threadIdx.x; f < total; f += 32 * 256) {
        int e = f & 7, lane = (f >> 3) & 63, ct = (f >> 9) & 7, ks = f >> 12;
        int k = ks * 32 + ((lane >> 4) << 3) + e;
        int col = (ct << 4) + (lane & 15);
        float v = (g == 3 || k < 128) ? A[(size_t)k * 128 + col]
                                      : Bw[(size_t)(k - 128) * 128 + col];
        uint32_t hi = bf16rne(v);
        float hf = __uint_as_float(hi << 16);
        whi[base + f] = (uint16_t)hi;
        wlo[base + f] = bf16rne(v - hf);
    }
}

// ---------------- K2: per-batch prefix sum of degrees -> rowptr ----------------
__global__ __launch_bounds__(256) void k2_rowptr(const uint32_t* __restrict__ deg0,
        uint32_t* __restrict__ rowptr) {
    int b = blockIdx.x, t = threadIdx.x;
    __shared__ uint32_t tsum[256];
    uint32_t v[8]; uint32_t s = 0;
    #pragma unroll
    for (int j = 0; j < 8; ++j) { v[j] = deg0[b * N_ + t * 8 + j]; s += v[j]; v[j] = s; }
    tsum[t] = s;
    __syncthreads();
    for (int off = 1; off < 256; off <<= 1) {
        uint32_t xv = (t >= off) ? tsum[t - off] : 0u;
        __syncthreads();
        tsum[t] += xv;
        __syncthreads();
    }
    uint32_t excl = tsum[t] - s;
    uint32_t* rp = rowptr + (size_t)b * RPS;
    if (t == 0) rp[0] = 0;
    #pragma unroll
    for (int j = 0; j < 8; ++j) {
        uint32_t val = excl + v[j];
        if (val > (uint32_t)EMAX) val = EMAX;
        rp[t * 8 + j + 1] = val;
    }
}

// ---------------- K3: fill sorted column lists ----------------
__global__ __launch_bounds__(256) void k3_cols(const uint32_t* __restrict__ bitset,
        const uint32_t* __restrict__ rowptr, uint16_t* __restrict__ cols) {
    int row  = blockIdx.x * 4 + (threadIdx.x >> 6);
    int lane = threadIdx.x & 63;
    int b = row >> 11, n = row & (N_ - 1);
    uint32_t w = bitset[(size_t)row * NW + lane];
    uint32_t pc = __popc(w);
    uint32_t inc = pc;
    #pragma unroll
    for (int off = 1; off < 64; off <<= 1) {
        uint32_t t = __shfl_up(inc, off);
        if (lane >= off) inc += t;
    }
    uint32_t base = rowptr[(size_t)b * RPS + n] + (inc - pc);
    uint16_t* cb = cols + (size_t)b * EMAX;
    while (w) {
        int bit = __builtin_ctz(w); w &= w - 1;
        if (base < (uint32_t)EMAX) cb[base] = (uint16_t)(lane * 32 + bit);
        ++base;
    }
}

// ---------------- K4: packed (col | mate_local<<16) via binary search ----------------
__global__ __launch_bounds__(256) void k4_packed(const uint16_t* __restrict__ cols,
        const uint32_t* __restrict__ rowptr, uint32_t* __restrict__ packed) {
    int row  = blockIdx.x * 4 + (threadIdx.x >> 6);
    int lane = threadIdx.x & 63;
    int b = row >> 11, n = row & (N_ - 1);
    const uint32_t* rpb = rowptr + (size_t)b * RPS;
    const uint16_t* cb  = cols + (size_t)b * EMAX;
    uint32_t start = rpb[n], end = rpb[n + 1];
    for (uint32_t e = start + lane; e < end; e += 64) {
        uint32_t j = cb[e];
        uint32_t lo = rpb[j], hi = rpb[j + 1];
        uint32_t rj = lo;
        while (lo < hi) {
            uint32_t mid = (lo + hi) >> 1;
            if ((int)cb[mid] < n) lo = mid + 1; else hi = mid;
        }
        packed[(size_t)b * EMAX + e] = j | ((lo - rj) << 16);
    }
}

// ---------------- K5: DAG-parallel dilation (16 waves per batch) ----------------
// Async-spin core with wave-uniform cnt<=64 fast path (R13/R14: ~86us).
#define K5_ISSUE(PK0, PK1, CNT, ROW)                                        \
    do {                                                                    \
        int rr_ = (ROW);                                                    \
        if (rr_ < N_) {                                                     \
            uint32_t ldI_ = rps[rr_], enI_ = rps[rr_ + 1];                  \
            CNT = (int)(enI_ - ldI_);                                       \
            PK0 = (lane < CNT) ? pkg[ldI_ + lane] : 0xFFFFFFFFu;            \
            if (CNT > 64)                                                   \
                PK1 = (lane + 64 < CNT) ? pkg[ldI_ + 64 + lane] : 0xFFFFFFFFu; \
            else PK1 = 0xFFFFFFFFu;                                         \
        } else { CNT = 0; PK0 = 0xFFFFFFFFu; PK1 = 0xFFFFFFFFu; }           \
    } while (0)

#define K5_PROC(PK0, PK1, CNT, NROW)                                        \
    do {                                                                    \
        int nr_ = (NROW);                                                   \
        if (CNT <= 64) {                                                    \
            uint32_t c0_ = PK0 & 0xFFFFu;                                   \
            bool e0_ = (lane < CNT) && (c0_ < (uint32_t)nr_);               \
            while (true) {                                                  \
                uint32_t d0_ = e0_ ? __hip_atomic_load(&done[c0_ >> 5],     \
                        __ATOMIC_ACQUIRE, __HIP_MEMORY_SCOPE_WORKGROUP) : 0u; \
                bool ok0_ = !e0_ || ((d0_ >> (c0_ & 31)) & 1u);             \
                if (__all((int)ok0_)) break;                                \
            }                                                               \
            __builtin_amdgcn_s_setprio(1);                                  \
            uint2 mc_ = *(const uint2*)&rm4[(size_t)nr_ * 4];               \
            uint32_t w01_ = (lane < 32) ? mc_.x : mc_.y;                    \
            uint32_t a0_ = (w01_ >> (lane & 31)) & 1u;                      \
            unsigned long long bl0_ = __ballot(a0_ != 0);                   \
            uint32_t num_ = (uint32_t)__popcll(bl0_);                       \
            if (mk[nr_] && num_ > 1u) {                                     \
                bool allrm_ = num_ <= (uint32_t)TDIL;                       \
                uint32_t sf_ = (num_ + 1u) >> 1;                            \
                uint32_t r2_ = (num_ & 1u) ? 0xFFFFFFFFu : num_;            \
                uint32_t rank0_ = (uint32_t)__popcll(bl0_ & below) + 1u;    \
                bool rm0_ = a0_ && (allrm_ || rank0_ == sf_ || rank0_ == r2_); \
                unsigned long long rb0_ = __ballot(rm0_);                   \
                if (rm0_) {                                                 \
                    uint32_t ml_ = PK0 >> 16;                               \
                    if (ml_ < 128u) atomicAnd(&rm4[c0_ * 4 + (ml_ >> 5)], ~(1u << (ml_ & 31))); \
                }                                                           \
                if (lane == 0) {                                            \
                    uint2 nm_;                                              \
                    nm_.x = mc_.x & ~(uint32_t)rb0_;                        \
                    nm_.y = mc_.y & ~(uint32_t)(rb0_ >> 32);                \
                    *(uint2*)&rm4[(size_t)nr_ * 4] = nm_;                   \
                }                                                           \
            }                                                               \
            __asm__ __volatile__("" ::: "memory");                          \
            if (lane == 0)                                                  \
                __hip_atomic_fetch_or(&done[nr_ >> 5], 1u << (nr_ & 31),    \
                        __ATOMIC_RELAXED, __HIP_MEMORY_SCOPE_WORKGROUP);    \
            __builtin_amdgcn_s_setprio(0);                                  \
        } else {                                                            \
            uint32_t c0_ = PK0 & 0xFFFFu, c1_ = PK1 & 0xFFFFu;              \
            bool e0_ = (lane < CNT)      && (c0_ < (uint32_t)nr_);          \
            bool e1_ = (lane + 64 < CNT) && (c1_ < (uint32_t)nr_);          \
            while (true) {                                                  \
                uint32_t d0_ = e0_ ? __hip_atomic_load(&done[c0_ >> 5],     \
                        __ATOMIC_ACQUIRE, __HIP_MEMORY_SCOPE_WORKGROUP) : 0u; \
                uint32_t d1_ = e1_ ? __hip_atomic_load(&done[c1_ >> 5],     \
                        __ATOMIC_ACQUIRE, __HIP_MEMORY_SCOPE_WORKGROUP) : 0u; \
                bool ok0_ = !e0_ || ((d0_ >> (c0_ & 31)) & 1u);             \
                bool ok1_ = !e1_ || ((d1_ >> (c1_ & 31)) & 1u);             \
                if (__all((int)(ok0_ && ok1_))) break;                      \
            }                                                               \
            __builtin_amdgcn_s_setprio(1);                                  \
            uint4 mcur_ = *(const uint4*)&rm4[(size_t)nr_ * 4];             \
            uint32_t w01_ = (lane < 32) ? mcur_.x : mcur_.y;                \
            uint32_t w23_ = (lane < 32) ? mcur_.z : mcur_.w;                \
            uint32_t a0_ = (w01_ >> (lane & 31)) & 1u;                      \
            uint32_t a1_ = (w23_ >> (lane & 31)) & 1u;                      \
            unsigned long long bl0_ = __ballot(a0_ != 0), bl1_ = __ballot(a1_ != 0); \
            uint32_t num_ = (uint32_t)__popcll(bl0_) + (uint32_t)__popcll(bl1_); \
            if (mk[nr_] && num_ > 1u) {                                     \
                bool allrm_ = num_ <= (uint32_t)TDIL;                       \
                uint32_t sf_ = (num_ + 1u) >> 1;                            \
                uint32_t r2_ = (num_ & 1u) ? 0xFFFFFFFFu : num_;            \
                uint32_t rank0_ = (uint32_t)__popcll(bl0_ & below) + 1u;    \
                uint32_t rank1_ = (uint32_t)__popcll(bl0_) +                \
                                  (uint32_t)__popcll(bl1_ & below) + 1u;    \
                bool rm0_ = a0_ && (allrm_ || rank0_ == sf_ || rank0_ == r2_); \
                bool rm1_ = a1_ && (allrm_ || rank1_ == sf_ || rank1_ == r2_); \
                unsigned long long rb0_ = __ballot(rm0_), rb1_ = __ballot(rm1_); \
                if (rm0_) {                                                 \
                    uint32_t ml_ = PK0 >> 16;                               \
                    if (ml_ < 128u) atomicAnd(&rm4[c0_ * 4 + (ml_ >> 5)], ~(1u << (ml_ & 31))); \
                }                                                           \
                if (rm1_) {                                                 \
                    uint32_t ml_ = PK1 >> 16;                               \
                    if (ml_ < 128u) atomicAnd(&rm4[c1_ * 4 + (ml_ >> 5)], ~(1u << (ml_ & 31))); \
                }                                                           \
                if (lane == 0) {                                            \
                    uint4 nm_;                                              \
                    nm_.x = mcur_.x & ~(uint32_t)rb0_;                      \
                    nm_.y = mcur_.y & ~(uint32_t)(rb0_ >> 32);              \
                    nm_.z = mcur_.z & ~(uint32_t)rb1_;                      \
                    nm_.w = mcur_.w & ~(uint32_t)(rb1_ >> 32);              \
                    *(uint4*)&rm4[(size_t)nr_ * 4] = nm_;                   \
                }                                                           \
            }                                                               \
            __asm__ __volatile__("" ::: "memory");                          \
            if (lane == 0)                                                  \
                __hip_atomic_fetch_or(&done[nr_ >> 5], 1u << (nr_ & 31),    \
                        __ATOMIC_RELAXED, __HIP_MEMORY_SCOPE_WORKGROUP);    \
            __builtin_amdgcn_s_setprio(0);                                  \
        }                                                                   \
    } while (0)

__global__ __launch_bounds__(1024) void k5_dilate(
        const uint32_t* __restrict__ packed, const uint32_t* __restrict__ rowptr,
        const uint32_t* __restrict__ deg0, const int* __restrict__ mask,
        uint32_t* __restrict__ rmaskg, uint32_t* __restrict__ degf) {
    int b = blockIdx.x;
    int tid = threadIdx.x;
    int lane = tid & 63;
    int wv = tid >> 6;                                // 0..15
    __shared__ __align__(16) uint32_t rm4[N_ * 4];    // 32KB
    __shared__ uint32_t rps[N_ + 1];                  // 8.2KB
    __shared__ uint8_t  mk[N_];                       // 2KB
    __shared__ uint32_t done[64];                     // 2048 done-bits
    const uint32_t* pkg = packed + (size_t)b * EMAX;
    const uint32_t* rpg = rowptr + (size_t)b * RPS;

    for (int i = tid; i <= N_; i += 1024) rps[i] = rpg[i];
    if (tid < 64) done[tid] = 0u;
    for (int i = tid; i < N_; i += 1024) {
        int d = (int)deg0[b * N_ + i]; if (d > 128) d = 128;
        uint4 mm;
        mm.x = (d >= 32) ? ~0u : ((d > 0)  ? ((1u << d)        - 1u) : 0u);
        mm.y = (d >= 64) ? ~0u : ((d > 32) ? ((1u << (d - 32)) - 1u) : 0u);
        mm.z = (d >= 96) ? ~0u : ((d > 64) ? ((1u << (d - 64)) - 1u) : 0u);
        mm.w = (d >= 128)? ~0u : ((d > 96) ? ((1u << (d - 96)) - 1u) : 0u);
        *(uint4*)&rm4[(size_t)i * 4] = mm;
        mk[i] = (uint8_t)(mask[b * N_ + i] != 0);
    }
    __syncthreads();

    unsigned long long below = (1ULL << lane) - 1ULL;
    int cntA, cntB, cntC;
    uint32_t pkA0, pkA1, pkB0, pkB1, pkC0, pkC1;
    K5_ISSUE(pkA0, pkA1, cntA, wv);
    K5_ISSUE(pkB0, pkB1, cntB, wv + 16);
    K5_ISSUE(pkC0, pkC1, cntC, wv + 32);

    int n = wv;
    while (n < N_) {
        K5_PROC(pkA0, pkA1, cntA, n);
        K5_ISSUE(pkA0, pkA1, cntA, n + 48);
        n += 16; if (n >= N_) break;
        K5_PROC(pkB0, pkB1, cntB, n);
        K5_ISSUE(pkB0, pkB1, cntB, n + 48);
        n += 16; if (n >= N_) break;
        K5_PROC(pkC0, pkC1, cntC, n);
        K5_ISSUE(pkC0, pkC1, cntC, n + 48);
        n += 16;
    }
    __syncthreads();
    for (int i = tid; i < N_; i += 1024) {
        uint4 mm = *(const uint4*)&rm4[(size_t)i * 4];
        *(uint4*)&rmaskg[((size_t)b * N_ + i) * 4] = mm;
        degf[b * N_ + i] = (uint32_t)(__popc(mm.x) + __popc(mm.y) + __popc(mm.z) + __popc(mm.w));
    }
}

// ---------------- K7L1: fused per-row compaction + bf16 gather (layer 1) ----
// Wave compacts its OWN row's cols via ballot (registers -> LDS wave buffer +
// global write-back for layers 2/3), then gathers via LDS broadcast reads.
// Per-row fusion is safe: gather of row n reads only row n's cols range.
__global__ __launch_bounds__(256) void k7_l1(const uint16_t* __restrict__ Xb16,
        uint16_t* __restrict__ cols, const uint32_t* __restrict__ rowptr,
        const uint32_t* __restrict__ rmaskg, float* __restrict__ agg) {
    __shared__ uint16_t wbuf[4][128];
    int wid  = blockIdx.x * 4 + (threadIdx.x >> 6);
    int wv   = (threadIdx.x >> 6) & 3;
    int lane = threadIdx.x & 63;
    int b = wid >> 11, n = wid & (N_ - 1);
    uint16_t* cb = cols + (size_t)b * EMAX;
    uint32_t st = rowptr[(size_t)b * RPS + n];
    uint32_t en = rowptr[(size_t)b * RPS + n + 1];
    int cnt0 = (int)(en - st);
    uint4 mm = *(const uint4*)&rmaskg[(size_t)wid * 4];
    uint32_t w01 = (lane < 32) ? mm.x : mm.y;
    uint32_t w23 = (lane < 32) ? mm.z : mm.w;
    uint32_t a0 = (lane < cnt0)      ? ((w01 >> (lane & 31)) & 1u) : 0u;
    uint32_t a1 = (lane + 64 < cnt0) ? ((w23 >> (lane & 31)) & 1u) : 0u;
    uint16_t c0v = 0, c1v = 0;
    if (a0) c0v = cb[st + lane];
    if (a1) c1v = cb[st + 64 + lane];
    unsigned long long b0 = __ballot(a0 != 0), b1 = __ballot(a1 != 0);
    unsigned long long below = (1ULL << lane) - 1ULL;
    uint32_t i0 = (uint32_t)__popcll(b0 & below);
    uint32_t i1 = (uint32_t)__popcll(b0) + (uint32_t)__popcll(b1 & below);
    if (a0) { wbuf[wv][i0] = c0v; cb[st + i0] = c0v; }
    if (a1) { wbuf[wv][i1] = c1v; cb[st + i1] = c1v; }
    int dcnt = (int)((uint32_t)__popcll(b0) + (uint32_t)__popcll(b1));

    const uint16_t* Xb = Xb16 + ((size_t)b * N_) * D_;
    float ax = 0.f, ay = 0.f;
    int k = 0;
    for (; k + 4 <= dcnt; k += 4) {
        int cA = wbuf[wv][k],     cB = wbuf[wv][k + 1];
        int cC = wbuf[wv][k + 2], cD = wbuf[wv][k + 3];
        uint32_t uA = ((const uint32_t*)(Xb + (size_t)cA * D_))[lane];
        uint32_t uB = ((const uint32_t*)(Xb + (size_t)cB * D_))[lane];
        uint32_t uC = ((const uint32_t*)(Xb + (size_t)cC * D_))[lane];
        uint32_t uD = ((const uint32_t*)(Xb + (size_t)cD * D_))[lane];
        ax += __uint_as_float(uA << 16) + __uint_as_float(uB << 16)
            + __uint_as_float(uC << 16) + __uint_as_float(uD << 16);
        ay += __uint_as_float(uA & 0xFFFF0000u) + __uint_as_float(uB & 0xFFFF0000u)
            + __uint_as_float(uC & 0xFFFF0000u) + __uint_as_float(uD & 0xFFFF0000u);
    }
    for (; k < dcnt; ++k) {
        int c = wbuf[wv][k];
        uint32_t u = ((const uint32_t*)(Xb + (size_t)c * D_))[lane];
        ax += __uint_as_float(u << 16);
        ay += __uint_as_float(u & 0xFFFF0000u);
    }
    float inv = 1.0f / (float)(dcnt ? dcnt : 1);
    ((float2*)(agg + (size_t)wid * D_))[lane] = make_float2(ax * inv, ay * inv);
}

// ---------------- K7: SpMM mean-aggregate over bf16 features (layers 2/3) ---
__global__ __launch_bounds__(256) void k7_spmm(const uint16_t* __restrict__ Xb16,
        const uint16_t* __restrict__ cols, const uint32_t* __restrict__ rowptr,
        const uint32_t* __restrict__ degf, float* __restrict__ agg) {
    int wid  = blockIdx.x * 4 + (threadIdx.x >> 6);
    int lane = threadIdx.x & 63;
    int b = wid >> 11, n = wid & (N_ - 1);
    const uint16_t* cb = cols + (size_t)b * EMAX;
    uint32_t start = rowptr[(size_t)b * RPS + n];
    uint32_t cnt = degf[wid];
    const uint16_t* Xb = Xb16 + ((size_t)b * N_) * D_;
    float ax = 0.f, ay = 0.f;
    for (uint32_t base = 0; base < cnt; base += 64) {
        int idx = (int)base + lane;
        int cl = (idx < (int)cnt) ? (int)cb[start + idx] : 0;
        int kmax = (int)cnt - (int)base; if (kmax > 64) kmax = 64;
        int k = 0;
        for (; k + 4 <= kmax; k += 4) {
            int cA = __shfl(cl, k),     cB = __shfl(cl, k + 1);
            int cC = __shfl(cl, k + 2), cD = __shfl(cl, k + 3);
            uint32_t uA = ((const uint32_t*)(Xb + (size_t)cA * D_))[lane];
            uint32_t uB = ((const uint32_t*)(Xb + (size_t)cB * D_))[lane];
            uint32_t uC = ((const uint32_t*)(Xb + (size_t)cC * D_))[lane];
            uint32_t uD = ((const uint32_t*)(Xb + (size_t)cD * D_))[lane];
            ax += __uint_as_float(uA << 16) + __uint_as_float(uB << 16)
                + __uint_as_float(uC << 16) + __uint_as_float(uD << 16);
            ay += __uint_as_float(uA & 0xFFFF0000u) + __uint_as_float(uB & 0xFFFF0000u)
                + __uint_as_float(uC & 0xFFFF0000u) + __uint_as_float(uD & 0xFFFF0000u);
        }
        for (; k < kmax; ++k) {
            int c = __shfl(cl, k);
            uint32_t u = ((const uint32_t*)(Xb + (size_t)c * D_))[lane];
            ax += __uint_as_float(u << 16);
            ay += __uint_as_float(u & 0xFFFF0000u);
        }
    }
    float inv = 1.0f / (float)(cnt ? cnt : 1u);
    ((float2*)(agg + (size_t)wid * D_))[lane] = make_float2(ax * inv, ay * inv);
}

// ---------------- bf16 split helper ----------------
__device__ __forceinline__ void cvt_store4(uint16_t* hiA, uint16_t* loA,
                                           int idx, float4 v) {
    float vv[4] = {v.x, v.y, v.z, v.w};
    ushort4 hs, ls;
    uint16_t* hp = (uint16_t*)&hs; uint16_t* lp = (uint16_t*)&ls;
    #pragma unroll
    for (int i = 0; i < 4; ++i) {
        uint32_t hi = bf16rne(vv[i]);
        float hf = __uint_as_float(hi << 16);
        hp[i] = (uint16_t)hi;
        lp[i] = bf16rne(vv[i] - hf);
    }
    *(ushort4*)&hiA[idx] = hs;
    *(ushort4*)&loA[idx] = ls;
}

// ---------------- K8: fused SAGE via bf16x3 MFMA ----------------
constexpr int ASTR = 264;   // shorts per row (256 + 8 pad)
__global__ __launch_bounds__(256) void k8_mfma(const float* __restrict__ agg,
        const float* __restrict__ Hin,
        const uint16_t* __restrict__ whi, const uint16_t* __restrict__ wlo,
        const float* __restrict__ bias, const int* __restrict__ mask,
        const float* __restrict__ bnp, const float* __restrict__ gp,
        const float* __restrict__ bep, int use_bn,
        float* __restrict__ P, uint16_t* __restrict__ Pb,
        float* __restrict__ bnstat) {
    __shared__ __align__(16) char buf[2 * 32 * ASTR * 2];   // 33792B
    __shared__ float scL[128], shL[128];
    uint16_t* aHi = (uint16_t*)buf;
    uint16_t* aLo = (uint16_t*)(buf + 32 * ASTR * 2);
    float* outP = (float*)buf;                              // overlay after MFMA
    int tid = threadIdx.x, lane = tid & 63, h = tid >> 6;
    size_t row0 = (size_t)blockIdx.x * 32;

    if (tid < 128) {
        float sc = 1.f, sh = 0.f;
        if (use_bn) {
            float mean = bnp[tid] * (1.f / 16384.f);
            float var  = bnp[128 + tid] * (1.f / 16384.f) - mean * mean;
            sc = gp[tid] * rsqrtf(var + 1e-5f);
            sh = bep[tid] - mean * sc;
        }
        scL[tid] = sc; shL[tid] = sh;
    }
    __syncthreads();

    for (int f = tid * 4; f < 4096; f += 1024) {
        int r = f >> 7, c = f & 127;
        float4 va = *(const float4*)&agg[(row0 + r) * 128 + c];
        float4 vx = *(const float4*)&Hin[(row0 + r) * 128 + c];
        float4 s4 = *(const float4*)&scL[c];
        float4 h4 = *(const float4*)&shL[c];
        va.x = va.x * s4.x + h4.x; va.y = va.y * s4.y + h4.y;
        va.z = va.z * s4.z + h4.z; va.w = va.w * s4.w + h4.w;
        vx.x = vx.x * s4.x + h4.x; vx.y = vx.y * s4.y + h4.y;
        vx.z = vx.z * s4.z + h4.z; vx.w = vx.w * s4.w + h4.w;
        cvt_store4(aHi, aLo, r * ASTR + c, va);
        cvt_store4(aHi, aLo, r * ASTR + 128 + c, vx);
    }
    __syncthreads();

    f32x4 acc00 = {0.f,0.f,0.f,0.f}, acc01 = acc00, acc10 = acc00, acc11 = acc00;
    int ct0 = h * 2, ct1 = h * 2 + 1;
    int arow = (lane & 15);
    int koff = (lane >> 4) * 8;
    #pragma unroll
    for (int ks = 0; ks < 8; ++ks) {
        int k0 = ks * 32 + koff;
        short8v a0h = *(short8v*)&aHi[arow * ASTR + k0];
        short8v a0l = *(short8v*)&aLo[arow * ASTR + k0];
        short8v a1h = *(short8v*)&aHi[(arow + 16) * ASTR + k0];
        short8v a1l = *(short8v*)&aLo[(arow + 16) * ASTR + k0];
        short8v b0h = *(const short8v*)&whi[(size_t)(((ks * 8 + ct0) << 6) + lane) * 8];
        short8v b0l = *(const short8v*)&wlo[(size_t)(((ks * 8 + ct0) << 6) + lane) * 8];
        short8v b1h = *(const short8v*)&whi[(size_t)(((ks * 8 + ct1) << 6) + lane) * 8];
        short8v b1l = *(const short8v*)&wlo[(size_t)(((ks * 8 + ct1) << 6) + lane) * 8];
        acc00 = __builtin_amdgcn_mfma_f32_16x16x32_bf16(a0h, b0h, acc00, 0, 0, 0);
        acc00 = __builtin_amdgcn_mfma_f32_16x16x32_bf16(a0h, b0l, acc00, 0, 0, 0);
        acc00 = __builtin_amdgcn_mfma_f32_16x16x32_bf16(a0l, b0h, acc00, 0, 0, 0);
        acc01 = __builtin_amdgcn_mfma_f32_16x16x32_bf16(a0h, b1h, acc01, 0, 0, 0);
        acc01 = __builtin_amdgcn_mfma_f32_16x16x32_bf16(a0h, b1l, acc01, 0, 0, 0);
        acc01 = __builtin_amdgcn_mfma_f32_16x16x32_bf16(a0l, b1h, acc01, 0, 0, 0);
        acc10 = __builtin_amdgcn_mfma_f32_16x16x32_bf16(a1h, b0h, acc10, 0, 0, 0);
        acc10 = __builtin_amdgcn_mfma_f32_16x16x32_bf16(a1h, b0l, acc10, 0, 0, 0);
        acc10 = __builtin_amdgcn_mfma_f32_16x16x32_bf16(a1l, b0h, acc10, 0, 0, 0);
        acc11 = __builtin_amdgcn_mfma_f32_16x16x32_bf16(a1h, b1h, acc11, 0, 0, 0);
        acc11 = __builtin_amdgcn_mfma_f32_16x16x32_bf16(a1h, b1l, acc11, 0, 0, 0);
        acc11 = __builtin_amdgcn_mfma_f32_16x16x32_bf16(a1l, b1h, acc11, 0, 0, 0);
    }
    __syncthreads();

    int orow = (lane >> 4) * 4;
    int oc0 = ct0 * 16 + (lane & 15);
    int oc1 = ct1 * 16 + (lane & 15);
    #pragma unroll
    for (int j = 0; j < 4; ++j) {
        outP[(orow + j) * 128 + oc0]      = acc00[j];
        outP[(orow + j) * 128 + oc1]      = acc01[j];
        outP[(16 + orow + j) * 128 + oc0] = acc10[j];
        outP[(16 + orow + j) * 128 + oc1] = acc11[j];
    }
    __syncthreads();

    float bs0 = bias[lane], bs1 = bias[lane + 64];
    #pragma unroll
    for (int i = 0; i < 8; ++i) {
        int r = h * 8 + i;
        float v0 = outP[r * 128 + lane] + bs0;
        float v1 = outP[r * 128 + lane + 64] + bs1;
        float s = v0 * v0 + v1 * v1;
        #pragma unroll
        for (int off = 32; off >= 1; off >>= 1) s += __shfl_xor(s, off);
        float nrm = fmaxf(sqrtf(s), 1e-12f);
        float mf = (mask[row0 + r] != 0) ? 1.f : 0.f;
        float inv = mf / nrm;
        float p0 = fmaxf(v0 * inv, 0.f), p1 = fmaxf(v1 * inv, 0.f);
        P[(row0 + r) * 128 + lane]      = p0;
        P[(row0 + r) * 128 + lane + 64] = p1;
        if (Pb) {
            Pb[(row0 + r) * 128 + lane]      = bf16rne(p0);
            Pb[(row0 + r) * 128 + lane + 64] = bf16rne(p1);
        }
        outP[r * 128 + lane] = p0; outP[r * 128 + lane + 64] = p1;
    }
    __syncthreads();
    if (tid < 128) {
        float s = 0.f, q = 0.f;
        #pragma unroll
        for (int r = 0; r < 32; ++r) { float v = outP[r * 128 + tid]; s += v; q += v * v; }
        atomicAdd(&bnstat[tid], s);
        atomicAdd(&bnstat[128 + tid], q);
    }
}

// ---------------- K11: final (concat BN(h_i) * mf) @ Wl + bl, * mf ----------
__global__ __launch_bounds__(256) void k11_final(const float* __restrict__ h1,
        const float* __restrict__ h2, const float* __restrict__ h3,
        const float* __restrict__ Wl, const float* __restrict__ bl,
        const int* __restrict__ mask, const float* __restrict__ bn,
        const float* __restrict__ g1, const float* __restrict__ be1,
        const float* __restrict__ g2, const float* __restrict__ be2,
        const float* __restrict__ g3, const float* __restrict__ be3,
        float* __restrict__ out) {
    __shared__ float s1[32 * 128], s2[32 * 128], s3[32 * 128];
    __shared__ float scA[128], shA[128], scB[128], shB[128], scC[128], shC[128];
    int tid = threadIdx.x;
    size_t row0 = (size_t)blockIdx.x * 32;
    if (tid < 128) {
        float m1 = bn[tid] * (1.f / 16384.f);
        float v1 = bn[128 + tid] * (1.f / 16384.f) - m1 * m1;
        scA[tid] = g1[tid] * rsqrtf(v1 + 1e-5f);
        shA[tid] = be1[tid] - m1 * scA[tid];
        float m2 = bn[256 + tid] * (1.f / 16384.f);
        float v2 = bn[384 + tid] * (1.f / 16384.f) - m2 * m2;
        scB[tid] = g2[tid] * rsqrtf(v2 + 1e-5f);
        shB[tid] = be2[tid] - m2 * scB[tid];
        float m3 = bn[512 + tid] * (1.f / 16384.f);
        float v3 = bn[640 + tid] * (1.f / 16384.f) - m3 * m3;
        scC[tid] = g3[tid] * rsqrtf(v3 + 1e-5f);
        shC[tid] = be3[tid] - m3 * scC[tid];
    }
    __syncthreads();
    for (int t = tid * 4; t < 32 * 128; t += 1024) {
        int r = t >> 7;
        float mf = (mask[row0 + r] != 0) ? 1.f : 0.f;
        int c = t & 127;
        float4 a = *(const float4*)&h1[row0 * 128 + t];
        float4 b = *(const float4*)&h2[row0 * 128 + t];
        float4 cc = *(const float4*)&h3[row0 * 128 + t];
        float4 sa = *(const float4*)&scA[c], ha = *(const float4*)&shA[c];
        float4 sb = *(const float4*)&scB[c], hb = *(const float4*)&shB[c];
        float4 sc = *(const float4*)&scC[c], hc = *(const float4*)&shC[c];
        a.x = (a.x * sa.x + ha.x) * mf; a.y = (a.y * sa.y + ha.y) * mf;
        a.z = (a.z * sa.z + ha.z) * mf; a.w = (a.w * sa.w + ha.w) * mf;
        b.x = (b.x * sb.x + hb.x) * mf; b.y = (b.y * sb.y + hb.y) * mf;
        b.z = (b.z * sb.z + hb.z) * mf; b.w = (b.w * sb.w + hb.w) * mf;
        cc.x = (cc.x * sc.x + hc.x) * mf; cc.y = (cc.y * sc.y + hc.y) * mf;
        cc.z = (cc.z * sc.z + hc.z) * mf; cc.w = (cc.w * sc.w + hc.w) * mf;
        *(float4*)&s1[t] = a; *(float4*)&s2[t] = b; *(float4*)&s3[t] = cc;
    }
    __syncthreads();
    int h = tid >> 6, c0 = (tid & 63) * 2;
    float2 acc[8];
    #pragma unroll
    for (int i = 0; i < 8; ++i) acc[i] = make_float2(0.f, 0.f);
    for (int k4 = 0; k4 < 128; k4 += 4) {
        float2 w1[4], w2[4], w3[4];
        #pragma unroll
        for (int kk = 0; kk < 4; ++kk) {
            w1[kk] = *(const float2*)&Wl[(k4 + kk) * 128 + c0];
            w2[kk] = *(const float2*)&Wl[(128 + k4 + kk) * 128 + c0];
            w3[kk] = *(const float2*)&Wl[(256 + k4 + kk) * 128 + c0];
        }
        #pragma unroll
        for (int i = 0; i < 8; ++i) {
            int r = h * 8 + i;
            float4 a = *(const float4*)&s1[r * 128 + k4];
            float4 b = *(const float4*)&s2[r * 128 + k4];
            float4 c = *(const float4*)&s3[r * 128 + k4];
            acc[i].x += a.x * w1[0].x + a.y * w1[1].x + a.z * w1[2].x + a.w * w1[3].x
                      + b.x * w2[0].x + b.y * w2[1].x + b.z * w2[2].x + b.w * w2[3].x
                      + c.x * w3[0].x + c.y * w3[1].x + c.z * w3[2].x + c.w * w3[3].x;
            acc[i].y += a.x * w1[0].y + a.y * w1[1].y + a.z * w1[2].y + a.w * w1[3].y
                      + b.x * w2[0].y + b.y * w2[1].y + b.z * w2[2].y + b.w * w2[3].y
                      + c.x * w3[0].y + c.y * w3[1].y + c.z * w3[2].y + c.w * w3[3].y;
        }
    }
    float bx = bl[c0], by = bl[c0 + 1];
    #pragma unroll
    for (int i = 0; i < 8; ++i) {
        int r = h * 8 + i;
        float mf = (mask[row0 + r] != 0) ? 1.f : 0.f;
        *(float2*)&out[(row0 + r) * 128 + c0] =
            make_float2((acc[i].x + bx) * mf, (acc[i].y + by) * mf);
    }
}

// ---------------- launch ----------------
extern "C" void kernel_launch(void* const* d_in, const int* in_sizes, int n_in,
                              void* d_out, int out_size, void* d_ws, size_t ws_size,
                              hipStream_t stream) {
    (void)in_sizes; (void)n_in; (void)out_size; (void)ws_size;
    const float* x    = (const float*)d_in[0];
    const float* adj  = (const float*)d_in[1];
    const int*   mask = (const int*)d_in[2];
    const float* Wr1 = (const float*)d_in[3],  *Wx1 = (const float*)d_in[4];
    const float* b1  = (const float*)d_in[5],  *g1  = (const float*)d_in[6],  *be1 = (const float*)d_in[7];
    const float* Wr2 = (const float*)d_in[8],  *Wx2 = (const float*)d_in[9];
    const float* b2  = (const float*)d_in[10], *g2  = (const float*)d_in[11], *be2 = (const float*)d_in[12];
    const float* Wr3 = (const float*)d_in[13], *Wx3 = (const float*)d_in[14];
    const float* b3  = (const float*)d_in[15], *g3  = (const float*)d_in[16], *be3 = (const float*)d_in[17];
    const float* Wl  = (const float*)d_in[18], *bl  = (const float*)d_in[19];

    char* ws = (char*)d_ws;
    uint32_t* bitset = (uint32_t*)(ws + OFF_BITSET);
    float*    agg    = (float*)(ws + OFF_AGG);
    float*    h1     = (float*)(ws + OFF_H1);
    float*    h2     = (float*)(ws + OFF_H2);
    float*    h3     = (float*)(ws + OFF_H3);
    uint16_t* xb     = (uint16_t*)(ws + OFF_XB);
    uint16_t* h1b    = (uint16_t*)(ws + OFF_H1B);
    uint16_t* h2b    = (uint16_t*)(ws + OFF_H2B);
    uint16_t* cols   = (uint16_t*)(ws + OFF_COLS);
    uint32_t* packed = (uint32_t*)(ws + OFF_PACKED);
    uint32_t* rp     = (uint32_t*)(ws + OFF_RP);
    uint32_t* deg0   = (uint32_t*)(ws + OFF_DEG0);
    uint32_t* degf   = (uint32_t*)(ws + OFF_DEGF);
    uint32_t* rmaskg = (uint32_t*)(ws + OFF_RMASK);
    float*    bn     = (float*)(ws + OFF_BN);
    uint16_t* whi    = (uint16_t*)(ws + OFF_WHI);
    uint16_t* wlo    = (uint16_t*)(ws + OFF_WLO);
    float*    out    = (float*)d_out;

    kP_prep   <<<6272, 256, 0, stream>>>(Wr1, Wx1, Wr2, Wx2, Wr3, Wx3, Wl,
                                         whi, wlo, bn, x, xb, adj, bitset, deg0);
    k2_rowptr <<<8,    256, 0, stream>>>(deg0, rp);
    k3_cols   <<<4096, 256, 0, stream>>>(bitset, rp, cols);
    k4_packed <<<4096, 256, 0, stream>>>(cols, rp, packed);
    k5_dilate <<<8,    1024, 0, stream>>>(packed, rp, deg0, mask, rmaskg, degf);
    // layer 1 (fused compaction + gather bf16 x; identity affine)
    k7_l1     <<<4096, 256, 0, stream>>>(xb,  cols, rp, rmaskg, agg);
    k8_mfma   <<<512,  256, 0, stream>>>(agg, x,  whi,         wlo,         b1, mask,
                                         bn, g1, be1, 0, h1, h1b, bn + 0);
    // layer 2 (gather bf16 h1; BN1 affine on the fly)
    k7_spmm   <<<4096, 256, 0, stream>>>(h1b, cols, rp, degf, agg);
    k8_mfma   <<<512,  256, 0, stream>>>(agg, h1, whi + 32768, wlo + 32768, b2, mask,
                                         bn + 0, g1, be1, 1, h2, h2b, bn + 256);
    // layer 3 (gather bf16 h2; BN2 affine on the fly)
    k7_spmm   <<<4096, 256, 0, stream>>>(h2b, cols, rp, degf, agg);
    k8_mfma   <<<512,  256, 0, stream>>>(agg, h2, whi + 65536, wlo + 65536, b3, mask,
                                         bn + 256, g2, be2, 1, h3, nullptr, bn + 512);
    // final
    k11_final <<<512,  256, 0, stream>>>(h1, h2, h3, Wl, bl, mask, bn,
                                         g1, be1, g2, be2, g3, be3, out);
}

// Round 16
// 277.170 us; speedup vs baseline: 1.2964x; 1.0318x over previous
//
#include <hip/hip_runtime.h>
#include <cstdint>

// ---------------- problem constants ----------------
constexpr int B_ = 8, N_ = 2048, D_ = 128, NW = 64;   // NW = words per bitset row
constexpr int EMAX = 131072;                           // per-batch edge capacity
constexpr int RPS = 2064;                              // rowptr stride per batch
constexpr int TDIL = 10;

// ---------------- workspace layout (bytes) ----------------
constexpr size_t OFF_BITSET = 0;                  // 4MB (preproc), reused as agg (8MB)
constexpr size_t OFF_AGG    = 0;
constexpr size_t OFF_H1     = (size_t)8  << 20;
constexpr size_t OFF_H2     = (size_t)16 << 20;
constexpr size_t OFF_H3     = (size_t)24 << 20;   // h3 (8MB); earlier: xb/h1b/h2b bf16
constexpr size_t OFF_XB     = (size_t)24 << 20;   // bf16 x   (4MB), dead before k8-L2
constexpr size_t OFF_H1B    = (size_t)28 << 20;   // bf16 h1  (4MB), dead before k8-L3
constexpr size_t OFF_H2B    = (size_t)24 << 20;   // bf16 h2  (4MB, reuses XB), dead before k8-L3
constexpr size_t OFF_COLS   = (size_t)32 << 20;   // u16 [B][EMAX]  (2MB)
constexpr size_t OFF_PACKED = (size_t)34 << 20;   // u32 [B][EMAX]  (4MB)
constexpr size_t OFF_RP     = (size_t)38 << 20;   // u32 [B][RPS]
constexpr size_t OFF_DEG0   = OFF_RP   + ((size_t)128 << 10);
constexpr size_t OFF_DEGF   = OFF_DEG0 + ((size_t)64  << 10);
constexpr size_t OFF_RMASK  = OFF_DEGF + ((size_t)64  << 10);  // u32 [B][N][4] (256KB)
constexpr size_t OFF_BN     = OFF_RMASK + ((size_t)256 << 10); // 3*256 floats
constexpr size_t OFF_WHI    = OFF_BN  + ((size_t)4 << 10);     // 147456 u16
constexpr size_t OFF_WLO    = OFF_WHI + ((size_t)304 << 10);   // 147456 u16
constexpr size_t OFF_PREF   = OFF_WLO + ((size_t)304 << 10);   // u16 [B*N][64] (2MB)

typedef __attribute__((ext_vector_type(8))) short short8v;
typedef __attribute__((ext_vector_type(4))) float f32x4;

__device__ __forceinline__ uint16_t bf16rne(float f) {
    uint32_t u = __float_as_uint(f);
    return (uint16_t)((u + 0x7FFFu + ((u >> 16) & 1u)) >> 16);
}

// ---------------- KP: fused prep — weights split + x->bf16 + adj->bitset ----
__global__ __launch_bounds__(256) void kP_prep(
        const float* __restrict__ Wr1, const float* __restrict__ Wx1,
        const float* __restrict__ Wr2, const float* __restrict__ Wx2,
        const float* __restrict__ Wr3, const float* __restrict__ Wx3,
        const float* __restrict__ Wl,
        uint16_t* __restrict__ whi, uint16_t* __restrict__ wlo,
        float* __restrict__ bn,
        const float* __restrict__ x, uint16_t* __restrict__ xb,
        const float* __restrict__ adj, uint32_t* __restrict__ bitset,
        uint32_t* __restrict__ deg0) {
    if (blockIdx.x >= 2176) {
        int row  = (blockIdx.x - 2176) * 4 + (threadIdx.x >> 6);
        int lane = threadIdx.x & 63;
        const float* ar = adj + (size_t)row * N_;
        uint32_t myw = 0;
        #pragma unroll 4
        for (int it = 0; it < 32; ++it) {
            float v = ar[it * 64 + lane];
            unsigned long long m = __ballot(v != 0.0f);
            if (lane == 2 * it)          myw = (uint32_t)m;
            else if (lane == 2 * it + 1) myw = (uint32_t)(m >> 32);
        }
        bitset[(size_t)row * NW + lane] = myw;
        int pc = __popc(myw);
        #pragma unroll
        for (int off = 32; off >= 1; off >>= 1) pc += __shfl_xor(pc, off);
        if (lane == 0) deg0[row] = (uint32_t)pc;
        return;
    }
    if (blockIdx.x >= 128) {
        size_t i = ((size_t)(blockIdx.x - 128) * 256 + threadIdx.x) * 4;
        float4 v = *(const float4*)&x[i];
        ushort4 o;
        o.x = bf16rne(v.x); o.y = bf16rne(v.y);
        o.z = bf16rne(v.z); o.w = bf16rne(v.w);
        *(ushort4*)&xb[i] = o;
        return;
    }
    if (blockIdx.x == 0) {
        for (int i = threadIdx.x; i < 768; i += 256) bn[i] = 0.f;
    }
    int g  = blockIdx.x >> 5;          // 0..3: L1,L2,L3,Wl
    int lb = blockIdx.x & 31;
    int K = (g == 3) ? 384 : 256;
    const float* A  = (g == 0) ? Wr1 : (g == 1) ? Wr2 : (g == 2) ? Wr3 : Wl;
    const float* Bw = (g == 0) ? Wx1 : (g == 1) ? Wx2 : (g == 2) ? Wx3 : nullptr;
    size_t base = (g == 3) ? (size_t)98304 : (size_t)g * 32768;
    int total = K * 128;
    for (int f = lb * 256 + threadIdx.x; f < total; f += 32 * 256) {
        int e = f & 7, lane = (f >> 3) & 63, ct = (f >> 9) & 7, ks = f >> 12;
        int k = ks * 32 + ((lane >> 4) << 3) + e;
        int col = (ct << 4) + (lane & 15);
        float v = (g == 3 || k < 128) ? A[(size_t)k * 128 + col]
                                      : Bw[(size_t)(k - 128) * 128 + col];
        uint32_t hi = bf16rne(v);
        float hf = __uint_as_float(hi << 16);
        whi[base + f] = (uint16_t)hi;
        wlo[base + f] = bf16rne(v - hf);
    }
}

// ---------------- K2: per-batch prefix sum of degrees -> rowptr ----------------
__global__ __launch_bounds__(256) void k2_rowptr(const uint32_t* __restrict__ deg0,
        uint32_t* __restrict__ rowptr) {
    int b = blockIdx.x, t = threadIdx.x;
    __shared__ uint32_t tsum[256];
    uint32_t v[8]; uint32_t s = 0;
    #pragma unroll
    for (int j = 0; j < 8; ++j) { v[j] = deg0[b * N_ + t * 8 + j]; s += v[j]; v[j] = s; }
    tsum[t] = s;
    __syncthreads();
    for (int off = 1; off < 256; off <<= 1) {
        uint32_t xv = (t >= off) ? tsum[t - off] : 0u;
        __syncthreads();
        tsum[t] += xv;
        __syncthreads();
    }
    uint32_t excl = tsum[t] - s;
    uint32_t* rp = rowptr + (size_t)b * RPS;
    if (t == 0) rp[0] = 0;
    #pragma unroll
    for (int j = 0; j < 8; ++j) {
        uint32_t val = excl + v[j];
        if (val > (uint32_t)EMAX) val = EMAX;
        rp[t * 8 + j + 1] = val;
    }
}

// ---------------- K3: fill sorted column lists + per-word bit-prefix --------
__global__ __launch_bounds__(256) void k3_cols(const uint32_t* __restrict__ bitset,
        const uint32_t* __restrict__ rowptr, uint16_t* __restrict__ cols,
        uint16_t* __restrict__ pref) {
    int row  = blockIdx.x * 4 + (threadIdx.x >> 6);
    int lane = threadIdx.x & 63;
    int b = row >> 11, n = row & (N_ - 1);
    uint32_t w = bitset[(size_t)row * NW + lane];
    uint32_t pc = __popc(w);
    uint32_t inc = pc;
    #pragma unroll
    for (int off = 1; off < 64; off <<= 1) {
        uint32_t t = __shfl_up(inc, off);
        if (lane >= off) inc += t;
    }
    pref[(size_t)row * 64 + lane] = (uint16_t)(inc - pc);   // exclusive word prefix
    uint32_t base = rowptr[(size_t)b * RPS + n] + (inc - pc);
    uint16_t* cb = cols + (size_t)b * EMAX;
    while (w) {
        int bit = __builtin_ctz(w); w &= w - 1;
        if (base < (uint32_t)EMAX) cb[base] = (uint16_t)(lane * 32 + bit);
        ++base;
    }
}

// ---------------- K4: packed (col | mate_local<<16) via bitset-rank ---------
// mate_local = #set bits below bit n in bitset row j  (O(1): pref + popc).
__global__ __launch_bounds__(256) void k4_packed(const uint32_t* __restrict__ bitset,
        const uint16_t* __restrict__ cols, const uint32_t* __restrict__ rowptr,
        const uint16_t* __restrict__ pref, uint32_t* __restrict__ packed) {
    int row  = blockIdx.x * 4 + (threadIdx.x >> 6);
    int lane = threadIdx.x & 63;
    int b = row >> 11, n = row & (N_ - 1);
    const uint32_t* rpb = rowptr + (size_t)b * RPS;
    const uint16_t* cb  = cols + (size_t)b * EMAX;
    uint32_t start = rpb[n], end = rpb[n + 1];
    uint32_t wi = (uint32_t)(n >> 5);
    uint32_t bmask = (n & 31) ? ((1u << (n & 31)) - 1u) : 0u;
    for (uint32_t e = start + lane; e < end; e += 64) {
        uint32_t j = cb[e];
        size_t grow = (size_t)b * N_ + j;
        uint32_t ml = (uint32_t)pref[grow * 64 + wi]
                    + (uint32_t)__popc(bitset[grow * NW + wi] & bmask);
        packed[(size_t)b * EMAX + e] = j | (ml << 16);
    }
}

// ---------------- K5: DAG-parallel dilation (16 waves per batch) ----------------
#define K5_ISSUE(PK0, PK1, CNT, ROW)                                        \
    do {                                                                    \
        int rr_ = (ROW);                                                    \
        if (rr_ < N_) {                                                     \
            uint32_t ldI_ = rps[rr_], enI_ = rps[rr_ + 1];                  \
            CNT = (int)(enI_ - ldI_);                                       \
            PK0 = (lane < CNT) ? pkg[ldI_ + lane] : 0xFFFFFFFFu;            \
            if (CNT > 64)                                                   \
                PK1 = (lane + 64 < CNT) ? pkg[ldI_ + 64 + lane] : 0xFFFFFFFFu; \
            else PK1 = 0xFFFFFFFFu;                                         \
        } else { CNT = 0; PK0 = 0xFFFFFFFFu; PK1 = 0xFFFFFFFFu; }           \
    } while (0)

#define K5_PROC(PK0, PK1, CNT, NROW)                                        \
    do {                                                                    \
        int nr_ = (NROW);                                                   \
        if (CNT <= 64) {                                                    \
            uint32_t c0_ = PK0 & 0xFFFFu;                                   \
            bool e0_ = (lane < CNT) && (c0_ < (uint32_t)nr_);               \
            while (true) {                                                  \
                uint32_t d0_ = e0_ ? __hip_atomic_load(&done[c0_ >> 5],     \
                        __ATOMIC_ACQUIRE, __HIP_MEMORY_SCOPE_WORKGROUP) : 0u; \
                bool ok0_ = !e0_ || ((d0_ >> (c0_ & 31)) & 1u);             \
                if (__all((int)ok0_)) break;                                \
            }                                                               \
            __builtin_amdgcn_s_setprio(1);                                  \
            uint2 mc_ = *(const uint2*)&rm4[(size_t)nr_ * 4];               \
            uint32_t w01_ = (lane < 32) ? mc_.x : mc_.y;                    \
            uint32_t a0_ = (w01_ >> (lane & 31)) & 1u;                      \
            unsigned long long bl0_ = __ballot(a0_ != 0);                   \
            uint32_t num_ = (uint32_t)__popcll(bl0_);                       \
            if (mk[nr_] && num_ > 1u) {                                     \
                bool allrm_ = num_ <= (uint32_t)TDIL;                       \
                uint32_t sf_ = (num_ + 1u) >> 1;                            \
                uint32_t r2_ = (num_ & 1u) ? 0xFFFFFFFFu : num_;            \
                uint32_t rank0_ = (uint32_t)__popcll(bl0_ & below) + 1u;    \
                bool rm0_ = a0_ && (allrm_ || rank0_ == sf_ || rank0_ == r2_); \
                unsigned long long rb0_ = __ballot(rm0_);                   \
                if (rm0_) {                                                 \
                    uint32_t ml_ = PK0 >> 16;                               \
                    if (ml_ < 128u) atomicAnd(&rm4[c0_ * 4 + (ml_ >> 5)], ~(1u << (ml_ & 31))); \
                }                                                           \
                if (lane == 0) {                                            \
                    uint2 nm_;                                              \
                    nm_.x = mc_.x & ~(uint32_t)rb0_;                        \
                    nm_.y = mc_.y & ~(uint32_t)(rb0_ >> 32);                \
                    *(uint2*)&rm4[(size_t)nr_ * 4] = nm_;                   \
                }                                                           \
            }                                                               \
            __asm__ __volatile__("" ::: "memory");                          \
            if (lane == 0)                                                  \
                __hip_atomic_fetch_or(&done[nr_ >> 5], 1u << (nr_ & 31),    \
                        __ATOMIC_RELAXED, __HIP_MEMORY_SCOPE_WORKGROUP);    \
            __builtin_amdgcn_s_setprio(0);                                  \
        } else {                                                            \
            uint32_t c0_ = PK0 & 0xFFFFu, c1_ = PK1 & 0xFFFFu;              \
            bool e0_ = (lane < CNT)      && (c0_ < (uint32_t)nr_);          \
            bool e1_ = (lane + 64 < CNT) && (c1_ < (uint32_t)nr_);          \
            while (true) {                                                  \
                uint32_t d0_ = e0_ ? __hip_atomic_load(&done[c0_ >> 5],     \
                        __ATOMIC_ACQUIRE, __HIP_MEMORY_SCOPE_WORKGROUP) : 0u; \
                uint32_t d1_ = e1_ ? __hip_atomic_load(&done[c1_ >> 5],     \
                        __ATOMIC_ACQUIRE, __HIP_MEMORY_SCOPE_WORKGROUP) : 0u; \
                bool ok0_ = !e0_ || ((d0_ >> (c0_ & 31)) & 1u);             \
                bool ok1_ = !e1_ || ((d1_ >> (c1_ & 31)) & 1u);             \
                if (__all((int)(ok0_ && ok1_))) break;                      \
            }                                                               \
            __builtin_amdgcn_s_setprio(1);                                  \
            uint4 mcur_ = *(const uint4*)&rm4[(size_t)nr_ * 4];             \
            uint32_t w01_ = (lane < 32) ? mcur_.x : mcur_.y;                \
            uint32_t w23_ = (lane < 32) ? mcur_.z : mcur_.w;                \
            uint32_t a0_ = (w01_ >> (lane & 31)) & 1u;                      \
            uint32_t a1_ = (w23_ >> (lane & 31)) & 1u;                      \
            unsigned long long bl0_ = __ballot(a0_ != 0), bl1_ = __ballot(a1_ != 0); \
            uint32_t num_ = (uint32_t)__popcll(bl0_) + (uint32_t)__popcll(bl1_); \
            if (mk[nr_] && num_ > 1u) {                                     \
                bool allrm_ = num_ <= (uint32_t)TDIL;                       \
                uint32_t sf_ = (num_ + 1u) >> 1;                            \
                uint32_t r2_ = (num_ & 1u) ? 0xFFFFFFFFu : num_;            \
                uint32_t rank0_ = (uint32_t)__popcll(bl0_ & below) + 1u;    \
                uint32_t rank1_ = (uint32_t)__popcll(bl0_) +                \
                                  (uint32_t)__popcll(bl1_ & below) + 1u;    \
                bool rm0_ = a0_ && (allrm_ || rank0_ == sf_ || rank0_ == r2_); \
                bool rm1_ = a1_ && (allrm_ || rank1_ == sf_ || rank1_ == r2_); \
                unsigned long long rb0_ = __ballot(rm0_), rb1_ = __ballot(rm1_); \
                if (rm0_) {                                                 \
                    uint32_t ml_ = PK0 >> 16;                               \
                    if (ml_ < 128u) atomicAnd(&rm4[c0_ * 4 + (ml_ >> 5)], ~(1u << (ml_ & 31))); \
                }                                                           \
                if (rm1_) {                                                 \
                    uint32_t ml_ = PK1 >> 16;                               \
                    if (ml_ < 128u) atomicAnd(&rm4[c1_ * 4 + (ml_ >> 5)], ~(1u << (ml_ & 31))); \
                }                                                           \
                if (lane == 0) {                                            \
                    uint4 nm_;                                              \
                    nm_.x = mcur_.x & ~(uint32_t)rb0_;                      \
                    nm_.y = mcur_.y & ~(uint32_t)(rb0_ >> 32);              \
                    nm_.z = mcur_.z & ~(uint32_t)rb1_;                      \
                    nm_.w = mcur_.w & ~(uint32_t)(rb1_ >> 32);              \
                    *(uint4*)&rm4[(size_t)nr_ * 4] = nm_;                   \
                }                                                           \
            }                                                               \
            __asm__ __volatile__("" ::: "memory");                          \
            if (lane == 0)                                                  \
                __hip_atomic_fetch_or(&done[nr_ >> 5], 1u << (nr_ & 31),    \
                        __ATOMIC_RELAXED, __HIP_MEMORY_SCOPE_WORKGROUP);    \
            __builtin_amdgcn_s_setprio(0);                                  \
        }                                                                   \
    } while (0)

__global__ __launch_bounds__(1024) void k5_dilate(
        const uint32_t* __restrict__ packed, const uint32_t* __restrict__ rowptr,
        const uint32_t* __restrict__ deg0, const int* __restrict__ mask,
        uint32_t* __restrict__ rmaskg, uint32_t* __restrict__ degf) {
    int b = blockIdx.x;
    int tid = threadIdx.x;
    int lane = tid & 63;
    int wv = tid >> 6;                                // 0..15
    __shared__ __align__(16) uint32_t rm4[N_ * 4];    // 32KB
    __shared__ uint32_t rps[N_ + 1];                  // 8.2KB
    __shared__ uint8_t  mk[N_];                       // 2KB
    __shared__ uint32_t done[64];                     // 2048 done-bits
    const uint32_t* pkg = packed + (size_t)b * EMAX;
    const uint32_t* rpg = rowptr + (size_t)b * RPS;

    for (int i = tid; i <= N_; i += 1024) rps[i] = rpg[i];
    if (tid < 64) done[tid] = 0u;
    for (int i = tid; i < N_; i += 1024) {
        int d = (int)deg0[b * N_ + i]; if (d > 128) d = 128;
        uint4 mm;
        mm.x = (d >= 32) ? ~0u : ((d > 0)  ? ((1u << d)        - 1u) : 0u);
        mm.y = (d >= 64) ? ~0u : ((d > 32) ? ((1u << (d - 32)) - 1u) : 0u);
        mm.z = (d >= 96) ? ~0u : ((d > 64) ? ((1u << (d - 64)) - 1u) : 0u);
        mm.w = (d >= 128)? ~0u : ((d > 96) ? ((1u << (d - 96)) - 1u) : 0u);
        *(uint4*)&rm4[(size_t)i * 4] = mm;
        mk[i] = (uint8_t)(mask[b * N_ + i] != 0);
    }
    __syncthreads();

    unsigned long long below = (1ULL << lane) - 1ULL;
    int cntA, cntB, cntC;
    uint32_t pkA0, pkA1, pkB0, pkB1, pkC0, pkC1;
    K5_ISSUE(pkA0, pkA1, cntA, wv);
    K5_ISSUE(pkB0, pkB1, cntB, wv + 16);
    K5_ISSUE(pkC0, pkC1, cntC, wv + 32);

    int n = wv;
    while (n < N_) {
        K5_PROC(pkA0, pkA1, cntA, n);
        K5_ISSUE(pkA0, pkA1, cntA, n + 48);
        n += 16; if (n >= N_) break;
        K5_PROC(pkB0, pkB1, cntB, n);
        K5_ISSUE(pkB0, pkB1, cntB, n + 48);
        n += 16; if (n >= N_) break;
        K5_PROC(pkC0, pkC1, cntC, n);
        K5_ISSUE(pkC0, pkC1, cntC, n + 48);
        n += 16;
    }
    __syncthreads();
    for (int i = tid; i < N_; i += 1024) {
        uint4 mm = *(const uint4*)&rm4[(size_t)i * 4];
        *(uint4*)&rmaskg[((size_t)b * N_ + i) * 4] = mm;
        degf[b * N_ + i] = (uint32_t)(__popc(mm.x) + __popc(mm.y) + __popc(mm.z) + __popc(mm.w));
    }
}

// ---------------- K7L1: fused per-row compaction + bf16 gather (layer 1) ----
__global__ __launch_bounds__(256) void k7_l1(const uint16_t* __restrict__ Xb16,
        uint16_t* __restrict__ cols, const uint32_t* __restrict__ rowptr,
        const uint32_t* __restrict__ rmaskg, float* __restrict__ agg) {
    __shared__ uint16_t wbuf[4][128];
    int wid  = blockIdx.x * 4 + (threadIdx.x >> 6);
    int wv   = (threadIdx.x >> 6) & 3;
    int lane = threadIdx.x & 63;
    int b = wid >> 11, n = wid & (N_ - 1);
    uint16_t* cb = cols + (size_t)b * EMAX;
    uint32_t st = rowptr[(size_t)b * RPS + n];
    uint32_t en = rowptr[(size_t)b * RPS + n + 1];
    int cnt0 = (int)(en - st);
    uint4 mm = *(const uint4*)&rmaskg[(size_t)wid * 4];
    uint32_t w01 = (lane < 32) ? mm.x : mm.y;
    uint32_t w23 = (lane < 32) ? mm.z : mm.w;
    uint32_t a0 = (lane < cnt0)      ? ((w01 >> (lane & 31)) & 1u) : 0u;
    uint32_t a1 = (lane + 64 < cnt0) ? ((w23 >> (lane & 31)) & 1u) : 0u;
    uint16_t c0v = 0, c1v = 0;
    if (a0) c0v = cb[st + lane];
    if (a1) c1v = cb[st + 64 + lane];
    unsigned long long b0 = __ballot(a0 != 0), b1 = __ballot(a1 != 0);
    unsigned long long below = (1ULL << lane) - 1ULL;
    uint32_t i0 = (uint32_t)__popcll(b0 & below);
    uint32_t i1 = (uint32_t)__popcll(b0) + (uint32_t)__popcll(b1 & below);
    if (a0) { wbuf[wv][i0] = c0v; cb[st + i0] = c0v; }
    if (a1) { wbuf[wv][i1] = c1v; cb[st + i1] = c1v; }
    int dcnt = (int)((uint32_t)__popcll(b0) + (uint32_t)__popcll(b1));

    const uint16_t* Xb = Xb16 + ((size_t)b * N_) * D_;
    float ax = 0.f, ay = 0.f;
    int k = 0;
    for (; k + 8 <= dcnt; k += 8) {
        uint32_t u0 = ((const uint32_t*)(Xb + (size_t)wbuf[wv][k]     * D_))[lane];
        uint32_t u1 = ((const uint32_t*)(Xb + (size_t)wbuf[wv][k + 1] * D_))[lane];
        uint32_t u2 = ((const uint32_t*)(Xb + (size_t)wbuf[wv][k + 2] * D_))[lane];
        uint32_t u3 = ((const uint32_t*)(Xb + (size_t)wbuf[wv][k + 3] * D_))[lane];
        uint32_t u4 = ((const uint32_t*)(Xb + (size_t)wbuf[wv][k + 4] * D_))[lane];
        uint32_t u5 = ((const uint32_t*)(Xb + (size_t)wbuf[wv][k + 5] * D_))[lane];
        uint32_t u6 = ((const uint32_t*)(Xb + (size_t)wbuf[wv][k + 6] * D_))[lane];
        uint32_t u7 = ((const uint32_t*)(Xb + (size_t)wbuf[wv][k + 7] * D_))[lane];
        ax += __uint_as_float(u0 << 16) + __uint_as_float(u1 << 16)
            + __uint_as_float(u2 << 16) + __uint_as_float(u3 << 16)
            + __uint_as_float(u4 << 16) + __uint_as_float(u5 << 16)
            + __uint_as_float(u6 << 16) + __uint_as_float(u7 << 16);
        ay += __uint_as_float(u0 & 0xFFFF0000u) + __uint_as_float(u1 & 0xFFFF0000u)
            + __uint_as_float(u2 & 0xFFFF0000u) + __uint_as_float(u3 & 0xFFFF0000u)
            + __uint_as_float(u4 & 0xFFFF0000u) + __uint_as_float(u5 & 0xFFFF0000u)
            + __uint_as_float(u6 & 0xFFFF0000u) + __uint_as_float(u7 & 0xFFFF0000u);
    }
    for (; k < dcnt; ++k) {
        uint32_t u = ((const uint32_t*)(Xb + (size_t)wbuf[wv][k] * D_))[lane];
        ax += __uint_as_float(u << 16);
        ay += __uint_as_float(u & 0xFFFF0000u);
    }
    float inv = 1.0f / (float)(dcnt ? dcnt : 1);
    ((float2*)(agg + (size_t)wid * D_))[lane] = make_float2(ax * inv, ay * inv);
}

// ---------------- K7: SpMM mean-aggregate over bf16 features (layers 2/3) ---
__global__ __launch_bounds__(256) void k7_spmm(const uint16_t* __restrict__ Xb16,
        const uint16_t* __restrict__ cols, const uint32_t* __restrict__ rowptr,
        const uint32_t* __restrict__ degf, float* __restrict__ agg) {
    int wid  = blockIdx.x * 4 + (threadIdx.x >> 6);
    int lane = threadIdx.x & 63;
    int b = wid >> 11, n = wid & (N_ - 1);
    const uint16_t* cb = cols + (size_t)b * EMAX;
    uint32_t start = rowptr[(size_t)b * RPS + n];
    uint32_t cnt = degf[wid];
    const uint16_t* Xb = Xb16 + ((size_t)b * N_) * D_;
    float ax = 0.f, ay = 0.f;
    for (uint32_t base = 0; base < cnt; base += 64) {
        int idx = (int)base + lane;
        int cl = (idx < (int)cnt) ? (int)cb[start + idx] : 0;
        int kmax = (int)cnt - (int)base; if (kmax > 64) kmax = 64;
        int k = 0;
        for (; k + 8 <= kmax; k += 8) {
            int c0 = __shfl(cl, k),     c1 = __shfl(cl, k + 1);
            int c2 = __shfl(cl, k + 2), c3 = __shfl(cl, k + 3);
            int c4 = __shfl(cl, k + 4), c5 = __shfl(cl, k + 5);
            int c6 = __shfl(cl, k + 6), c7 = __shfl(cl, k + 7);
            uint32_t u0 = ((const uint32_t*)(Xb + (size_t)c0 * D_))[lane];
            uint32_t u1 = ((const uint32_t*)(Xb + (size_t)c1 * D_))[lane];
            uint32_t u2 = ((const uint32_t*)(Xb + (size_t)c2 * D_))[lane];
            uint32_t u3 = ((const uint32_t*)(Xb + (size_t)c3 * D_))[lane];
            uint32_t u4 = ((const uint32_t*)(Xb + (size_t)c4 * D_))[lane];
            uint32_t u5 = ((const uint32_t*)(Xb + (size_t)c5 * D_))[lane];
            uint32_t u6 = ((const uint32_t*)(Xb + (size_t)c6 * D_))[lane];
            uint32_t u7 = ((const uint32_t*)(Xb + (size_t)c7 * D_))[lane];
            ax += __uint_as_float(u0 << 16) + __uint_as_float(u1 << 16)
                + __uint_as_float(u2 << 16) + __uint_as_float(u3 << 16)
                + __uint_as_float(u4 << 16) + __uint_as_float(u5 << 16)
                + __uint_as_float(u6 << 16) + __uint_as_float(u7 << 16);
            ay += __uint_as_float(u0 & 0xFFFF0000u) + __uint_as_float(u1 & 0xFFFF0000u)
                + __uint_as_float(u2 & 0xFFFF0000u) + __uint_as_float(u3 & 0xFFFF0000u)
                + __uint_as_float(u4 & 0xFFFF0000u) + __uint_as_float(u5 & 0xFFFF0000u)
                + __uint_as_float(u6 & 0xFFFF0000u) + __uint_as_float(u7 & 0xFFFF0000u);
        }
        for (; k < kmax; ++k) {
            int c = __shfl(cl, k);
            uint32_t u = ((const uint32_t*)(Xb + (size_t)c * D_))[lane];
            ax += __uint_as_float(u << 16);
            ay += __uint_as_float(u & 0xFFFF0000u);
        }
    }
    float inv = 1.0f / (float)(cnt ? cnt : 1u);
    ((float2*)(agg + (size_t)wid * D_))[lane] = make_float2(ax * inv, ay * inv);
}

// ---------------- bf16 split helper ----------------
__device__ __forceinline__ void cvt_store4(uint16_t* hiA, uint16_t* loA,
                                           int idx, float4 v) {
    float vv[4] = {v.x, v.y, v.z, v.w};
    ushort4 hs, ls;
    uint16_t* hp = (uint16_t*)&hs; uint16_t* lp = (uint16_t*)&ls;
    #pragma unroll
    for (int i = 0; i < 4; ++i) {
        uint32_t hi = bf16rne(vv[i]);
        float hf = __uint_as_float(hi << 16);
        hp[i] = (uint16_t)hi;
        lp[i] = bf16rne(vv[i] - hf);
    }
    *(ushort4*)&hiA[idx] = hs;
    *(ushort4*)&loA[idx] = ls;
}

// ---------------- K8: fused SAGE via bf16x3 MFMA ----------------
constexpr int ASTR = 264;   // shorts per row (256 + 8 pad)
__global__ __launch_bounds__(256) void k8_mfma(const float* __restrict__ agg,
        const float* __restrict__ Hin,
        const uint16_t* __restrict__ whi, const uint16_t* __restrict__ wlo,
        const float* __restrict__ bias, const int* __restrict__ mask,
        const float* __restrict__ bnp, const float* __restrict__ gp,
        const float* __restrict__ bep, int use_bn,
        float* __restrict__ P, uint16_t* __restrict__ Pb,
        float* __restrict__ bnstat) {
    __shared__ __align__(16) char buf[2 * 32 * ASTR * 2];   // 33792B
    __shared__ float scL[128], shL[128];
    uint16_t* aHi = (uint16_t*)buf;
    uint16_t* aLo = (uint16_t*)(buf + 32 * ASTR * 2);
    float* outP = (float*)buf;                              // overlay after MFMA
    int tid = threadIdx.x, lane = tid & 63, h = tid >> 6;
    size_t row0 = (size_t)blockIdx.x * 32;

    if (tid < 128) {
        float sc = 1.f, sh = 0.f;
        if (use_bn) {
            float mean = bnp[tid] * (1.f / 16384.f);
            float var  = bnp[128 + tid] * (1.f / 16384.f) - mean * mean;
            sc = gp[tid] * rsqrtf(var + 1e-5f);
            sh = bep[tid] - mean * sc;
        }
        scL[tid] = sc; shL[tid] = sh;
    }
    __syncthreads();

    for (int f = tid * 4; f < 4096; f += 1024) {
        int r = f >> 7, c = f & 127;
        float4 va = *(const float4*)&agg[(row0 + r) * 128 + c];
        float4 vx = *(const float4*)&Hin[(row0 + r) * 128 + c];
        float4 s4 = *(const float4*)&scL[c];
        float4 h4 = *(const float4*)&shL[c];
        va.x = va.x * s4.x + h4.x; va.y = va.y * s4.y + h4.y;
        va.z = va.z * s4.z + h4.z; va.w = va.w * s4.w + h4.w;
        vx.x = vx.x * s4.x + h4.x; vx.y = vx.y * s4.y + h4.y;
        vx.z = vx.z * s4.z + h4.z; vx.w = vx.w * s4.w + h4.w;
        cvt_store4(aHi, aLo, r * ASTR + c, va);
        cvt_store4(aHi, aLo, r * ASTR + 128 + c, vx);
    }
    __syncthreads();

    f32x4 acc00 = {0.f,0.f,0.f,0.f}, acc01 = acc00, acc10 = acc00, acc11 = acc00;
    int ct0 = h * 2, ct1 = h * 2 + 1;
    int arow = (lane & 15);
    int koff = (lane >> 4) * 8;
    #pragma unroll
    for (int ks = 0; ks < 8; ++ks) {
        int k0 = ks * 32 + koff;
        short8v a0h = *(short8v*)&aHi[arow * ASTR + k0];
        short8v a0l = *(short8v*)&aLo[arow * ASTR + k0];
        short8v a1h = *(short8v*)&aHi[(arow + 16) * ASTR + k0];
        short8v a1l = *(short8v*)&aLo[(arow + 16) * ASTR + k0];
        short8v b0h = *(const short8v*)&whi[(size_t)(((ks * 8 + ct0) << 6) + lane) * 8];
        short8v b0l = *(const short8v*)&wlo[(size_t)(((ks * 8 + ct0) << 6) + lane) * 8];
        short8v b1h = *(const short8v*)&whi[(size_t)(((ks * 8 + ct1) << 6) + lane) * 8];
        short8v b1l = *(const short8v*)&wlo[(size_t)(((ks * 8 + ct1) << 6) + lane) * 8];
        acc00 = __builtin_amdgcn_mfma_f32_16x16x32_bf16(a0h, b0h, acc00, 0, 0, 0);
        acc00 = __builtin_amdgcn_mfma_f32_16x16x32_bf16(a0h, b0l, acc00, 0, 0, 0);
        acc00 = __builtin_amdgcn_mfma_f32_16x16x32_bf16(a0l, b0h, acc00, 0, 0, 0);
        acc01 = __builtin_amdgcn_mfma_f32_16x16x32_bf16(a0h, b1h, acc01, 0, 0, 0);
        acc01 = __builtin_amdgcn_mfma_f32_16x16x32_bf16(a0h, b1l, acc01, 0, 0, 0);
        acc01 = __builtin_amdgcn_mfma_f32_16x16x32_bf16(a0l, b1h, acc01, 0, 0, 0);
        acc10 = __builtin_amdgcn_mfma_f32_16x16x32_bf16(a1h, b0h, acc10, 0, 0, 0);
        acc10 = __builtin_amdgcn_mfma_f32_16x16x32_bf16(a1h, b0l, acc10, 0, 0, 0);
        acc10 = __builtin_amdgcn_mfma_f32_16x16x32_bf16(a1l, b0h, acc10, 0, 0, 0);
        acc11 = __builtin_amdgcn_mfma_f32_16x16x32_bf16(a1h, b1h, acc11, 0, 0, 0);
        acc11 = __builtin_amdgcn_mfma_f32_16x16x32_bf16(a1h, b1l, acc11, 0, 0, 0);
        acc11 = __builtin_amdgcn_mfma_f32_16x16x32_bf16(a1l, b1h, acc11, 0, 0, 0);
    }
    __syncthreads();

    int orow = (lane >> 4) * 4;
    int oc0 = ct0 * 16 + (lane & 15);
    int oc1 = ct1 * 16 + (lane & 15);
    #pragma unroll
    for (int j = 0; j < 4; ++j) {
        outP[(orow + j) * 128 + oc0]      = acc00[j];
        outP[(orow + j) * 128 + oc1]      = acc01[j];
        outP[(16 + orow + j) * 128 + oc0] = acc10[j];
        outP[(16 + orow + j) * 128 + oc1] = acc11[j];
    }
    __syncthreads();

    float bs0 = bias[lane], bs1 = bias[lane + 64];
    #pragma unroll
    for (int i = 0; i < 8; ++i) {
        int r = h * 8 + i;
        float v0 = outP[r * 128 + lane] + bs0;
        float v1 = outP[r * 128 + lane + 64] + bs1;
        float s = v0 * v0 + v1 * v1;
        #pragma unroll
        for (int off = 32; off >= 1; off >>= 1) s += __shfl_xor(s, off);
        float nrm = fmaxf(sqrtf(s), 1e-12f);
        float mf = (mask[row0 + r] != 0) ? 1.f : 0.f;
        float inv = mf / nrm;
        float p0 = fmaxf(v0 * inv, 0.f), p1 = fmaxf(v1 * inv, 0.f);
        P[(row0 + r) * 128 + lane]      = p0;
        P[(row0 + r) * 128 + lane + 64] = p1;
        if (Pb) {
            Pb[(row0 + r) * 128 + lane]      = bf16rne(p0);
            Pb[(row0 + r) * 128 + lane + 64] = bf16rne(p1);
        }
        outP[r * 128 + lane] = p0; outP[r * 128 + lane + 64] = p1;
    }
    __syncthreads();
    if (tid < 128) {
        float s = 0.f, q = 0.f;
        #pragma unroll
        for (int r = 0; r < 32; ++r) { float v = outP[r * 128 + tid]; s += v; q += v * v; }
        atomicAdd(&bnstat[tid], s);
        atomicAdd(&bnstat[128 + tid], q);
    }
}

// ---------------- K11: final (concat BN(h_i) * mf) @ Wl + bl, * mf ----------
__global__ __launch_bounds__(256) void k11_final(const float* __restrict__ h1,
        const float* __restrict__ h2, const float* __restrict__ h3,
        const float* __restrict__ Wl, const float* __restrict__ bl,
        const int* __restrict__ mask, const float* __restrict__ bn,
        const float* __restrict__ g1, const float* __restrict__ be1,
        const float* __restrict__ g2, const float* __restrict__ be2,
        const float* __restrict__ g3, const float* __restrict__ be3,
        float* __restrict__ out) {
    __shared__ float s1[32 * 128], s2[32 * 128], s3[32 * 128];
    __shared__ float scA[128], shA[128], scB[128], shB[128], scC[128], shC[128];
    int tid = threadIdx.x;
    size_t row0 = (size_t)blockIdx.x * 32;
    if (tid < 128) {
        float m1 = bn[tid] * (1.f / 16384.f);
        float v1 = bn[128 + tid] * (1.f / 16384.f) - m1 * m1;
        scA[tid] = g1[tid] * rsqrtf(v1 + 1e-5f);
        shA[tid] = be1[tid] - m1 * scA[tid];
        float m2 = bn[256 + tid] * (1.f / 16384.f);
        float v2 = bn[384 + tid] * (1.f / 16384.f) - m2 * m2;
        scB[tid] = g2[tid] * rsqrtf(v2 + 1e-5f);
        shB[tid] = be2[tid] - m2 * scB[tid];
        float m3 = bn[512 + tid] * (1.f / 16384.f);
        float v3 = bn[640 + tid] * (1.f / 16384.f) - m3 * m3;
        scC[tid] = g3[tid] * rsqrtf(v3 + 1e-5f);
        shC[tid] = be3[tid] - m3 * scC[tid];
    }
    __syncthreads();
    for (int t = tid * 4; t < 32 * 128; t += 1024) {
        int r = t >> 7;
        float mf = (mask[row0 + r] != 0) ? 1.f : 0.f;
        int c = t & 127;
        float4 a = *(const float4*)&h1[row0 * 128 + t];
        float4 b = *(const float4*)&h2[row0 * 128 + t];
        float4 cc = *(const float4*)&h3[row0 * 128 + t];
        float4 sa = *(const float4*)&scA[c], ha = *(const float4*)&shA[c];
        float4 sb = *(const float4*)&scB[c], hb = *(const float4*)&shB[c];
        float4 sc = *(const float4*)&scC[c], hc = *(const float4*)&shC[c];
        a.x = (a.x * sa.x + ha.x) * mf; a.y = (a.y * sa.y + ha.y) * mf;
        a.z = (a.z * sa.z + ha.z) * mf; a.w = (a.w * sa.w + ha.w) * mf;
        b.x = (b.x * sb.x + hb.x) * mf; b.y = (b.y * sb.y + hb.y) * mf;
        b.z = (b.z * sb.z + hb.z) * mf; b.w = (b.w * sb.w + hb.w) * mf;
        cc.x = (cc.x * sc.x + hc.x) * mf; cc.y = (cc.y * sc.y + hc.y) * mf;
        cc.z = (cc.z * sc.z + hc.z) * mf; cc.w = (cc.w * sc.w + hc.w) * mf;
        *(float4*)&s1[t] = a; *(float4*)&s2[t] = b; *(float4*)&s3[t] = cc;
    }
    __syncthreads();
    int h = tid >> 6, c0 = (tid & 63) * 2;
    float2 acc[8];
    #pragma unroll
    for (int i = 0; i < 8; ++i) acc[i] = make_float2(0.f, 0.f);
    for (int k4 = 0; k4 < 128; k4 += 4) {
        float2 w1[4], w2[4], w3[4];
        #pragma unroll
        for (int kk = 0; kk < 4; ++kk) {
            w1[kk] = *(const float2*)&Wl[(k4 + kk) * 128 + c0];
            w2[kk] = *(const float2*)&Wl[(128 + k4 + kk) * 128 + c0];
            w3[kk] = *(const float2*)&Wl[(256 + k4 + kk) * 128 + c0];
        }
        #pragma unroll
        for (int i = 0; i < 8; ++i) {
            int r = h * 8 + i;
            float4 a = *(const float4*)&s1[r * 128 + k4];
            float4 b = *(const float4*)&s2[r * 128 + k4];
            float4 c = *(const float4*)&s3[r * 128 + k4];
            acc[i].x += a.x * w1[0].x + a.y * w1[1].x + a.z * w1[2].x + a.w * w1[3].x
                      + b.x * w2[0].x + b.y * w2[1].x + b.z * w2[2].x + b.w * w2[3].x
                      + c.x * w3[0].x + c.y * w3[1].x + c.z * w3[2].x + c.w * w3[3].x;
            acc[i].y += a.x * w1[0].y + a.y * w1[1].y + a.z * w1[2].y + a.w * w1[3].y
                      + b.x * w2[0].y + b.y * w2[1].y + b.z * w2[2].y + b.w * w2[3].y
                      + c.x * w3[0].y + c.y * w3[1].y + c.z * w3[2].y + c.w * w3[3].y;
        }
    }
    float bx = bl[c0], by = bl[c0 + 1];
    #pragma unroll
    for (int i = 0; i < 8; ++i) {
        int r = h * 8 + i;
        float mf = (mask[row0 + r] != 0) ? 1.f : 0.f;
        *(float2*)&out[(row0 + r) * 128 + c0] =
            make_float2((acc[i].x + bx) * mf, (acc[i].y + by) * mf);
    }
}

// ---------------- launch ----------------
extern "C" void kernel_launch(void* const* d_in, const int* in_sizes, int n_in,
                              void* d_out, int out_size, void* d_ws, size_t ws_size,
                              hipStream_t stream) {
    (void)in_sizes; (void)n_in; (void)out_size; (void)ws_size;
    const float* x    = (const float*)d_in[0];
    const float* adj  = (const float*)d_in[1];
    const int*   mask = (const int*)d_in[2];
    const float* Wr1 = (const float*)d_in[3],  *Wx1 = (const float*)d_in[4];
    const float* b1  = (const float*)d_in[5],  *g1  = (const float*)d_in[6],  *be1 = (const float*)d_in[7];
    const float* Wr2 = (const float*)d_in[8],  *Wx2 = (const float*)d_in[9];
    const float* b2  = (const float*)d_in[10], *g2  = (const float*)d_in[11], *be2 = (const float*)d_in[12];
    const float* Wr3 = (const float*)d_in[13], *Wx3 = (const float*)d_in[14];
    const float* b3  = (const float*)d_in[15], *g3  = (const float*)d_in[16], *be3 = (const float*)d_in[17];
    const float* Wl  = (const float*)d_in[18], *bl  = (const float*)d_in[19];

    char* ws = (char*)d_ws;
    uint32_t* bitset = (uint32_t*)(ws + OFF_BITSET);
    float*    agg    = (float*)(ws + OFF_AGG);
    float*    h1     = (float*)(ws + OFF_H1);
    float*    h2     = (float*)(ws + OFF_H2);
    float*    h3     = (float*)(ws + OFF_H3);
    uint16_t* xb     = (uint16_t*)(ws + OFF_XB);
    uint16_t* h1b    = (uint16_t*)(ws + OFF_H1B);
    uint16_t* h2b    = (uint16_t*)(ws + OFF_H2B);
    uint16_t* cols   = (uint16_t*)(ws + OFF_COLS);
    uint32_t* packed = (uint32_t*)(ws + OFF_PACKED);
    uint32_t* rp     = (uint32_t*)(ws + OFF_RP);
    uint32_t* deg0   = (uint32_t*)(ws + OFF_DEG0);
    uint32_t* degf   = (uint32_t*)(ws + OFF_DEGF);
    uint32_t* rmaskg = (uint32_t*)(ws + OFF_RMASK);
    float*    bn     = (float*)(ws + OFF_BN);
    uint16_t* whi    = (uint16_t*)(ws + OFF_WHI);
    uint16_t* wlo    = (uint16_t*)(ws + OFF_WLO);
    uint16_t* pref   = (uint16_t*)(ws + OFF_PREF);
    float*    out    = (float*)d_out;

    kP_prep   <<<6272, 256, 0, stream>>>(Wr1, Wx1, Wr2, Wx2, Wr3, Wx3, Wl,
                                         whi, wlo, bn, x, xb, adj, bitset, deg0);
    k2_rowptr <<<8,    256, 0, stream>>>(deg0, rp);
    k3_cols   <<<4096, 256, 0, stream>>>(bitset, rp, cols, pref);
    k4_packed <<<4096, 256, 0, stream>>>(bitset, cols, rp, pref, packed);
    k5_dilate <<<8,    1024, 0, stream>>>(packed, rp, deg0, mask, rmaskg, degf);
    // layer 1 (fused compaction + gather bf16 x; identity affine)
    k7_l1     <<<4096, 256, 0, stream>>>(xb,  cols, rp, rmaskg, agg);
    k8_mfma   <<<512,  256, 0, stream>>>(agg, x,  whi,         wlo,         b1, mask,
                                         bn, g1, be1, 0, h1, h1b, bn + 0);
    // layer 2 (gather bf16 h1; BN1 affine on the fly)
    k7_spmm   <<<4096, 256, 0, stream>>>(h1b, cols, rp, degf, agg);
    k8_mfma   <<<512,  256, 0, stream>>>(agg, h1, whi + 32768, wlo + 32768, b2, mask,
                                         bn + 0, g1, be1, 1, h2, h2b, bn + 256);
    // layer 3 (gather bf16 h2; BN2 affine on the fly)
    k7_spmm   <<<4096, 256, 0, stream>>>(h2b, cols, rp, degf, agg);
    k8_mfma   <<<512,  256, 0, stream>>>(agg, h2, whi + 65536, wlo + 65536, b3, mask,
                                         bn + 256, g2, be2, 1, h3, nullptr, bn + 512);
    // final
    k11_final <<<512,  256, 0, stream>>>(h1, h2, h3, Wl, bl, mask, bn,
                                         g1, be1, g2, be2, g3, be3, out);
}

// Round 17
// 273.747 us; speedup vs baseline: 1.3127x; 1.0125x over previous
//
#include <hip/hip_runtime.h>
#include <cstdint>

// ---------------- problem constants ----------------
constexpr int B_ = 8, N_ = 2048, D_ = 128, NW = 64;   // NW = words per bitset row
constexpr int EMAX = 131072;                           // per-batch edge capacity
constexpr int RPS = 2064;                              // rowptr stride per batch
constexpr int TDIL = 10;

// ---------------- workspace layout (bytes) ----------------
constexpr size_t OFF_BITSET = 0;                  // 4MB (preproc), reused as agg (8MB)
constexpr size_t OFF_AGG    = 0;
constexpr size_t OFF_H1     = (size_t)8  << 20;
constexpr size_t OFF_H2     = (size_t)16 << 20;
constexpr size_t OFF_H3     = (size_t)24 << 20;   // h3 (8MB); earlier: xb/h1b/h2b bf16
constexpr size_t OFF_XB     = (size_t)24 << 20;   // bf16 x   (4MB), dead before k8-L2
constexpr size_t OFF_H1B    = (size_t)28 << 20;   // bf16 h1  (4MB), dead before k8-L3
constexpr size_t OFF_H2B    = (size_t)24 << 20;   // bf16 h2  (4MB, reuses XB), dead before k8-L3
constexpr size_t OFF_COLS   = (size_t)32 << 20;   // u16 [B][EMAX]  (2MB)
constexpr size_t OFF_PACKED = (size_t)34 << 20;   // u32 [B][EMAX]  (4MB)
constexpr size_t OFF_RP     = (size_t)38 << 20;   // u32 [B][RPS]
constexpr size_t OFF_DEG0   = OFF_RP   + ((size_t)128 << 10);
constexpr size_t OFF_DEGF   = OFF_DEG0 + ((size_t)64  << 10);
constexpr size_t OFF_RMASK  = OFF_DEGF + ((size_t)64  << 10);  // u32 [B][N][4] (256KB)
constexpr size_t OFF_BN     = OFF_RMASK + ((size_t)256 << 10); // 3*256 floats
constexpr size_t OFF_WHI    = OFF_BN  + ((size_t)4 << 10);     // 147456 u16
constexpr size_t OFF_WLO    = OFF_WHI + ((size_t)304 << 10);   // 147456 u16
constexpr size_t OFF_PREF   = OFF_WLO + ((size_t)304 << 10);   // u16 [B*N][64] (2MB)

typedef __attribute__((ext_vector_type(8))) short short8v;
typedef __attribute__((ext_vector_type(4))) float f32x4;

__device__ __forceinline__ uint16_t bf16rne(float f) {
    uint32_t u = __float_as_uint(f);
    return (uint16_t)((u + 0x7FFFu + ((u >> 16) & 1u)) >> 16);
}

// ---------------- KP: fused prep — weights split + x->bf16 + adj->bitset+pref
__global__ __launch_bounds__(256) void kP_prep(
        const float* __restrict__ Wr1, const float* __restrict__ Wx1,
        const float* __restrict__ Wr2, const float* __restrict__ Wx2,
        const float* __restrict__ Wr3, const float* __restrict__ Wx3,
        const float* __restrict__ Wl,
        uint16_t* __restrict__ whi, uint16_t* __restrict__ wlo,
        float* __restrict__ bn,
        const float* __restrict__ x, uint16_t* __restrict__ xb,
        const float* __restrict__ adj, uint32_t* __restrict__ bitset,
        uint32_t* __restrict__ deg0, uint16_t* __restrict__ pref) {
    if (blockIdx.x >= 2176) {
        int row  = (blockIdx.x - 2176) * 4 + (threadIdx.x >> 6);
        int lane = threadIdx.x & 63;
        const float* ar = adj + (size_t)row * N_;
        uint32_t myw = 0;
        #pragma unroll 4
        for (int it = 0; it < 32; ++it) {
            float v = ar[it * 64 + lane];
            unsigned long long m = __ballot(v != 0.0f);
            if (lane == 2 * it)          myw = (uint32_t)m;
            else if (lane == 2 * it + 1) myw = (uint32_t)(m >> 32);
        }
        bitset[(size_t)row * NW + lane] = myw;
        uint32_t pc = (uint32_t)__popc(myw);
        uint32_t inc = pc;
        #pragma unroll
        for (int off = 1; off < 64; off <<= 1) {
            uint32_t t = __shfl_up(inc, off);
            if (lane >= off) inc += t;
        }
        pref[(size_t)row * 64 + lane] = (uint16_t)(inc - pc);
        if (lane == 63) deg0[row] = inc;        // inclusive scan total
        return;
    }
    if (blockIdx.x >= 128) {
        size_t i = ((size_t)(blockIdx.x - 128) * 256 + threadIdx.x) * 4;
        float4 v = *(const float4*)&x[i];
        ushort4 o;
        o.x = bf16rne(v.x); o.y = bf16rne(v.y);
        o.z = bf16rne(v.z); o.w = bf16rne(v.w);
        *(ushort4*)&xb[i] = o;
        return;
    }
    if (blockIdx.x == 0) {
        for (int i = threadIdx.x; i < 768; i += 256) bn[i] = 0.f;
    }
    int g  = blockIdx.x >> 5;          // 0..3: L1,L2,L3,Wl
    int lb = blockIdx.x & 31;
    int K = (g == 3) ? 384 : 256;
    const float* A  = (g == 0) ? Wr1 : (g == 1) ? Wr2 : (g == 2) ? Wr3 : Wl;
    const float* Bw = (g == 0) ? Wx1 : (g == 1) ? Wx2 : (g == 2) ? Wx3 : nullptr;
    size_t base = (g == 3) ? (size_t)98304 : (size_t)g * 32768;
    int total = K * 128;
    for (int f = lb * 256 + threadIdx.x; f < total; f += 32 * 256) {
        int e = f & 7, lane = (f >> 3) & 63, ct = (f >> 9) & 7, ks = f >> 12;
        int k = ks * 32 + ((lane >> 4) << 3) + e;
        int col = (ct << 4) + (lane & 15);
        float v = (g == 3 || k < 128) ? A[(size_t)k * 128 + col]
                                      : Bw[(size_t)(k - 128) * 128 + col];
        uint32_t hi = bf16rne(v);
        float hf = __uint_as_float(hi << 16);
        whi[base + f] = (uint16_t)hi;
        wlo[base + f] = bf16rne(v - hf);
    }
}

// ---------------- K2: per-batch prefix sum of degrees -> rowptr ----------------
__global__ __launch_bounds__(256) void k2_rowptr(const uint32_t* __restrict__ deg0,
        uint32_t* __restrict__ rowptr) {
    int b = blockIdx.x, t = threadIdx.x;
    __shared__ uint32_t tsum[256];
    uint32_t v[8]; uint32_t s = 0;
    #pragma unroll
    for (int j = 0; j < 8; ++j) { v[j] = deg0[b * N_ + t * 8 + j]; s += v[j]; v[j] = s; }
    tsum[t] = s;
    __syncthreads();
    for (int off = 1; off < 256; off <<= 1) {
        uint32_t xv = (t >= off) ? tsum[t - off] : 0u;
        __syncthreads();
        tsum[t] += xv;
        __syncthreads();
    }
    uint32_t excl = tsum[t] - s;
    uint32_t* rp = rowptr + (size_t)b * RPS;
    if (t == 0) rp[0] = 0;
    #pragma unroll
    for (int j = 0; j < 8; ++j) {
        uint32_t val = excl + v[j];
        if (val > (uint32_t)EMAX) val = EMAX;
        rp[t * 8 + j + 1] = val;
    }
}

// ---------------- K34: fused cols fill + packed (col | mate_local<<16) ------
// k4 for row n needs only row n's own cols (just produced here, kept in LDS)
// plus NEIGHBOR pref/bitset words (from kP). Same-wave DS ordering makes the
// LDS write->read safe without a barrier. k5 consumes only the first 128
// edges/row, so packing e<128 preserves existing behavior.
__global__ __launch_bounds__(256) void k34_colpack(
        const uint32_t* __restrict__ bitset, const uint32_t* __restrict__ rowptr,
        const uint16_t* __restrict__ pref, uint16_t* __restrict__ cols,
        uint32_t* __restrict__ packed) {
    __shared__ uint16_t scols[4][128];
    int row  = blockIdx.x * 4 + (threadIdx.x >> 6);
    int wv   = (threadIdx.x >> 6) & 3;
    int lane = threadIdx.x & 63;
    int b = row >> 11, n = row & (N_ - 1);
    const uint32_t* rpb = rowptr + (size_t)b * RPS;
    uint32_t st = rpb[n], en = rpb[n + 1];
    int cnt = (int)(en - st);
    uint32_t w  = bitset[(size_t)row * NW + lane];
    uint32_t pr = pref[(size_t)row * 64 + lane];
    uint16_t* cb = cols + (size_t)b * EMAX;
    uint32_t gbase = st + pr;
    uint32_t loc = pr;
    while (w) {
        int bit = __builtin_ctz(w); w &= w - 1;
        uint16_t cv = (uint16_t)(lane * 32 + bit);
        if (gbase < (uint32_t)EMAX) cb[gbase] = cv;
        if (loc < 128u) scols[wv][loc] = cv;
        ++gbase; ++loc;
    }
    // pack first min(cnt,128) edges from the LDS copy
    uint32_t wi = (uint32_t)(n >> 5);
    uint32_t bmask = (n & 31) ? ((1u << (n & 31)) - 1u) : 0u;
    #pragma unroll
    for (int half = 0; half < 2; ++half) {
        int e = lane + half * 64;
        if (e < cnt && e < 128) {
            uint32_t j = scols[wv][e];
            size_t grow = (size_t)b * N_ + j;
            uint32_t ml = (uint32_t)pref[grow * 64 + wi]
                        + (uint32_t)__popc(bitset[grow * NW + wi] & bmask);
            packed[(size_t)b * EMAX + st + e] = j | (ml << 16);
        }
    }
}

// ---------------- K5: DAG-parallel dilation (16 waves per batch) ----------------
#define K5_ISSUE(PK0, PK1, CNT, ROW)                                        \
    do {                                                                    \
        int rr_ = (ROW);                                                    \
        if (rr_ < N_) {                                                     \
            uint32_t ldI_ = rps[rr_], enI_ = rps[rr_ + 1];                  \
            CNT = (int)(enI_ - ldI_);                                       \
            PK0 = (lane < CNT) ? pkg[ldI_ + lane] : 0xFFFFFFFFu;            \
            if (CNT > 64)                                                   \
                PK1 = (lane + 64 < CNT) ? pkg[ldI_ + 64 + lane] : 0xFFFFFFFFu; \
            else PK1 = 0xFFFFFFFFu;                                         \
        } else { CNT = 0; PK0 = 0xFFFFFFFFu; PK1 = 0xFFFFFFFFu; }           \
    } while (0)

#define K5_PROC(PK0, PK1, CNT, NROW)                                        \
    do {                                                                    \
        int nr_ = (NROW);                                                   \
        if (CNT <= 64) {                                                    \
            uint32_t c0_ = PK0 & 0xFFFFu;                                   \
            bool e0_ = (lane < CNT) && (c0_ < (uint32_t)nr_);               \
            while (true) {                                                  \
                uint32_t d0_ = e0_ ? __hip_atomic_load(&done[c0_ >> 5],     \
                        __ATOMIC_ACQUIRE, __HIP_MEMORY_SCOPE_WORKGROUP) : 0u; \
                bool ok0_ = !e0_ || ((d0_ >> (c0_ & 31)) & 1u);             \
                if (__all((int)ok0_)) break;                                \
            }                                                               \
            __builtin_amdgcn_s_setprio(1);                                  \
            uint2 mc_ = *(const uint2*)&rm4[(size_t)nr_ * 4];               \
            uint32_t w01_ = (lane < 32) ? mc_.x : mc_.y;                    \
            uint32_t a0_ = (w01_ >> (lane & 31)) & 1u;                      \
            unsigned long long bl0_ = __ballot(a0_ != 0);                   \
            uint32_t num_ = (uint32_t)__popcll(bl0_);                       \
            if (mk[nr_] && num_ > 1u) {                                     \
                bool allrm_ = num_ <= (uint32_t)TDIL;                       \
                uint32_t sf_ = (num_ + 1u) >> 1;                            \
                uint32_t r2_ = (num_ & 1u) ? 0xFFFFFFFFu : num_;            \
                uint32_t rank0_ = (uint32_t)__popcll(bl0_ & below) + 1u;    \
                bool rm0_ = a0_ && (allrm_ || rank0_ == sf_ || rank0_ == r2_); \
                unsigned long long rb0_ = __ballot(rm0_);                   \
                if (rm0_) {                                                 \
                    uint32_t ml_ = PK0 >> 16;                               \
                    if (ml_ < 128u) atomicAnd(&rm4[c0_ * 4 + (ml_ >> 5)], ~(1u << (ml_ & 31))); \
                }                                                           \
                if (lane == 0) {                                            \
                    uint2 nm_;                                              \
                    nm_.x = mc_.x & ~(uint32_t)rb0_;                        \
                    nm_.y = mc_.y & ~(uint32_t)(rb0_ >> 32);                \
                    *(uint2*)&rm4[(size_t)nr_ * 4] = nm_;                   \
                }                                                           \
            }                                                               \
            __asm__ __volatile__("" ::: "memory");                          \
            if (lane == 0)                                                  \
                __hip_atomic_fetch_or(&done[nr_ >> 5], 1u << (nr_ & 31),    \
                        __ATOMIC_RELAXED, __HIP_MEMORY_SCOPE_WORKGROUP);    \
            __builtin_amdgcn_s_setprio(0);                                  \
        } else {                                                            \
            uint32_t c0_ = PK0 & 0xFFFFu, c1_ = PK1 & 0xFFFFu;              \
            bool e0_ = (lane < CNT)      && (c0_ < (uint32_t)nr_);          \
            bool e1_ = (lane + 64 < CNT) && (c1_ < (uint32_t)nr_);          \
            while (true) {                                                  \
                uint32_t d0_ = e0_ ? __hip_atomic_load(&done[c0_ >> 5],     \
                        __ATOMIC_ACQUIRE, __HIP_MEMORY_SCOPE_WORKGROUP) : 0u; \
                uint32_t d1_ = e1_ ? __hip_atomic_load(&done[c1_ >> 5],     \
                        __ATOMIC_ACQUIRE, __HIP_MEMORY_SCOPE_WORKGROUP) : 0u; \
                bool ok0_ = !e0_ || ((d0_ >> (c0_ & 31)) & 1u);             \
                bool ok1_ = !e1_ || ((d1_ >> (c1_ & 31)) & 1u);             \
                if (__all((int)(ok0_ && ok1_))) break;                      \
            }                                                               \
            __builtin_amdgcn_s_setprio(1);                                  \
            uint4 mcur_ = *(const uint4*)&rm4[(size_t)nr_ * 4];             \
            uint32_t w01_ = (lane < 32) ? mcur_.x : mcur_.y;                \
            uint32_t w23_ = (lane < 32) ? mcur_.z : mcur_.w;                \
            uint32_t a0_ = (w01_ >> (lane & 31)) & 1u;                      \
            uint32_t a1_ = (w23_ >> (lane & 31)) & 1u;                      \
            unsigned long long bl0_ = __ballot(a0_ != 0), bl1_ = __ballot(a1_ != 0); \
            uint32_t num_ = (uint32_t)__popcll(bl0_) + (uint32_t)__popcll(bl1_); \
            if (mk[nr_] && num_ > 1u) {                                     \
                bool allrm_ = num_ <= (uint32_t)TDIL;                       \
                uint32_t sf_ = (num_ + 1u) >> 1;                            \
                uint32_t r2_ = (num_ & 1u) ? 0xFFFFFFFFu : num_;            \
                uint32_t rank0_ = (uint32_t)__popcll(bl0_ & below) + 1u;    \
                uint32_t rank1_ = (uint32_t)__popcll(bl0_) +                \
                                  (uint32_t)__popcll(bl1_ & below) + 1u;    \
                bool rm0_ = a0_ && (allrm_ || rank0_ == sf_ || rank0_ == r2_); \
                bool rm1_ = a1_ && (allrm_ || rank1_ == sf_ || rank1_ == r2_); \
                unsigned long long rb0_ = __ballot(rm0_), rb1_ = __ballot(rm1_); \
                if (rm0_) {                                                 \
                    uint32_t ml_ = PK0 >> 16;                               \
                    if (ml_ < 128u) atomicAnd(&rm4[c0_ * 4 + (ml_ >> 5)], ~(1u << (ml_ & 31))); \
                }                                                           \
                if (rm1_) {                                                 \
                    uint32_t ml_ = PK1 >> 16;                               \
                    if (ml_ < 128u) atomicAnd(&rm4[c1_ * 4 + (ml_ >> 5)], ~(1u << (ml_ & 31))); \
                }                                                           \
                if (lane == 0) {                                            \
                    uint4 nm_;                                              \
                    nm_.x = mcur_.x & ~(uint32_t)rb0_;                      \
                    nm_.y = mcur_.y & ~(uint32_t)(rb0_ >> 32);              \
                    nm_.z = mcur_.z & ~(uint32_t)rb1_;                      \
                    nm_.w = mcur_.w & ~(uint32_t)(rb1_ >> 32);              \
                    *(uint4*)&rm4[(size_t)nr_ * 4] = nm_;                   \
                }                                                           \
            }                                                               \
            __asm__ __volatile__("" ::: "memory");                          \
            if (lane == 0)                                                  \
                __hip_atomic_fetch_or(&done[nr_ >> 5], 1u << (nr_ & 31),    \
                        __ATOMIC_RELAXED, __HIP_MEMORY_SCOPE_WORKGROUP);    \
            __builtin_amdgcn_s_setprio(0);                                  \
        }                                                                   \
    } while (0)

__global__ __launch_bounds__(1024) void k5_dilate(
        const uint32_t* __restrict__ packed, const uint32_t* __restrict__ rowptr,
        const uint32_t* __restrict__ deg0, const int* __restrict__ mask,
        uint32_t* __restrict__ rmaskg, uint32_t* __restrict__ degf) {
    int b = blockIdx.x;
    int tid = threadIdx.x;
    int lane = tid & 63;
    int wv = tid >> 6;                                // 0..15
    __shared__ __align__(16) uint32_t rm4[N_ * 4];    // 32KB
    __shared__ uint32_t rps[N_ + 1];                  // 8.2KB
    __shared__ uint8_t  mk[N_];                       // 2KB
    __shared__ uint32_t done[64];                     // 2048 done-bits
    const uint32_t* pkg = packed + (size_t)b * EMAX;
    const uint32_t* rpg = rowptr + (size_t)b * RPS;

    for (int i = tid; i <= N_; i += 1024) rps[i] = rpg[i];
    if (tid < 64) done[tid] = 0u;
    for (int i = tid; i < N_; i += 1024) {
        int d = (int)deg0[b * N_ + i]; if (d > 128) d = 128;
        uint4 mm;
        mm.x = (d >= 32) ? ~0u : ((d > 0)  ? ((1u << d)        - 1u) : 0u);
        mm.y = (d >= 64) ? ~0u : ((d > 32) ? ((1u << (d - 32)) - 1u) : 0u);
        mm.z = (d >= 96) ? ~0u : ((d > 64) ? ((1u << (d - 64)) - 1u) : 0u);
        mm.w = (d >= 128)? ~0u : ((d > 96) ? ((1u << (d - 96)) - 1u) : 0u);
        *(uint4*)&rm4[(size_t)i * 4] = mm;
        mk[i] = (uint8_t)(mask[b * N_ + i] != 0);
    }
    __syncthreads();

    unsigned long long below = (1ULL << lane) - 1ULL;
    int cntA, cntB, cntC;
    uint32_t pkA0, pkA1, pkB0, pkB1, pkC0, pkC1;
    K5_ISSUE(pkA0, pkA1, cntA, wv);
    K5_ISSUE(pkB0, pkB1, cntB, wv + 16);
    K5_ISSUE(pkC0, pkC1, cntC, wv + 32);

    int n = wv;
    while (n < N_) {
        K5_PROC(pkA0, pkA1, cntA, n);
        K5_ISSUE(pkA0, pkA1, cntA, n + 48);
        n += 16; if (n >= N_) break;
        K5_PROC(pkB0, pkB1, cntB, n);
        K5_ISSUE(pkB0, pkB1, cntB, n + 48);
        n += 16; if (n >= N_) break;
        K5_PROC(pkC0, pkC1, cntC, n);
        K5_ISSUE(pkC0, pkC1, cntC, n + 48);
        n += 16;
    }
    __syncthreads();
    for (int i = tid; i < N_; i += 1024) {
        uint4 mm = *(const uint4*)&rm4[(size_t)i * 4];
        *(uint4*)&rmaskg[((size_t)b * N_ + i) * 4] = mm;
        degf[b * N_ + i] = (uint32_t)(__popc(mm.x) + __popc(mm.y) + __popc(mm.z) + __popc(mm.w));
    }
}

// ---------------- K7L1: fused per-row compaction + bf16 gather (layer 1) ----
__global__ __launch_bounds__(256) void k7_l1(const uint16_t* __restrict__ Xb16,
        uint16_t* __restrict__ cols, const uint32_t* __restrict__ rowptr,
        const uint32_t* __restrict__ rmaskg, float* __restrict__ agg) {
    __shared__ uint16_t wbuf[4][128];
    int wid  = blockIdx.x * 4 + (threadIdx.x >> 6);
    int wv   = (threadIdx.x >> 6) & 3;
    int lane = threadIdx.x & 63;
    int b = wid >> 11, n = wid & (N_ - 1);
    uint16_t* cb = cols + (size_t)b * EMAX;
    uint32_t st = rowptr[(size_t)b * RPS + n];
    uint32_t en = rowptr[(size_t)b * RPS + n + 1];
    int cnt0 = (int)(en - st);
    uint4 mm = *(const uint4*)&rmaskg[(size_t)wid * 4];
    uint32_t w01 = (lane < 32) ? mm.x : mm.y;
    uint32_t w23 = (lane < 32) ? mm.z : mm.w;
    uint32_t a0 = (lane < cnt0)      ? ((w01 >> (lane & 31)) & 1u) : 0u;
    uint32_t a1 = (lane + 64 < cnt0) ? ((w23 >> (lane & 31)) & 1u) : 0u;
    uint16_t c0v = 0, c1v = 0;
    if (a0) c0v = cb[st + lane];
    if (a1) c1v = cb[st + 64 + lane];
    unsigned long long b0 = __ballot(a0 != 0), b1 = __ballot(a1 != 0);
    unsigned long long below = (1ULL << lane) - 1ULL;
    uint32_t i0 = (uint32_t)__popcll(b0 & below);
    uint32_t i1 = (uint32_t)__popcll(b0) + (uint32_t)__popcll(b1 & below);
    if (a0) { wbuf[wv][i0] = c0v; cb[st + i0] = c0v; }
    if (a1) { wbuf[wv][i1] = c1v; cb[st + i1] = c1v; }
    int dcnt = (int)((uint32_t)__popcll(b0) + (uint32_t)__popcll(b1));

    const uint16_t* Xb = Xb16 + ((size_t)b * N_) * D_;
    float ax = 0.f, ay = 0.f;
    int k = 0;
    for (; k + 8 <= dcnt; k += 8) {
        uint32_t u0 = ((const uint32_t*)(Xb + (size_t)wbuf[wv][k]     * D_))[lane];
        uint32_t u1 = ((const uint32_t*)(Xb + (size_t)wbuf[wv][k + 1] * D_))[lane];
        uint32_t u2 = ((const uint32_t*)(Xb + (size_t)wbuf[wv][k + 2] * D_))[lane];
        uint32_t u3 = ((const uint32_t*)(Xb + (size_t)wbuf[wv][k + 3] * D_))[lane];
        uint32_t u4 = ((const uint32_t*)(Xb + (size_t)wbuf[wv][k + 4] * D_))[lane];
        uint32_t u5 = ((const uint32_t*)(Xb + (size_t)wbuf[wv][k + 5] * D_))[lane];
        uint32_t u6 = ((const uint32_t*)(Xb + (size_t)wbuf[wv][k + 6] * D_))[lane];
        uint32_t u7 = ((const uint32_t*)(Xb + (size_t)wbuf[wv][k + 7] * D_))[lane];
        ax += __uint_as_float(u0 << 16) + __uint_as_float(u1 << 16)
            + __uint_as_float(u2 << 16) + __uint_as_float(u3 << 16)
            + __uint_as_float(u4 << 16) + __uint_as_float(u5 << 16)
            + __uint_as_float(u6 << 16) + __uint_as_float(u7 << 16);
        ay += __uint_as_float(u0 & 0xFFFF0000u) + __uint_as_float(u1 & 0xFFFF0000u)
            + __uint_as_float(u2 & 0xFFFF0000u) + __uint_as_float(u3 & 0xFFFF0000u)
            + __uint_as_float(u4 & 0xFFFF0000u) + __uint_as_float(u5 & 0xFFFF0000u)
            + __uint_as_float(u6 & 0xFFFF0000u) + __uint_as_float(u7 & 0xFFFF0000u);
    }
    for (; k < dcnt; ++k) {
        uint32_t u = ((const uint32_t*)(Xb + (size_t)wbuf[wv][k] * D_))[lane];
        ax += __uint_as_float(u << 16);
        ay += __uint_as_float(u & 0xFFFF0000u);
    }
    float inv = 1.0f / (float)(dcnt ? dcnt : 1);
    ((float2*)(agg + (size_t)wid * D_))[lane] = make_float2(ax * inv, ay * inv);
}

// ---------------- K7: SpMM mean-aggregate over bf16 features (layers 2/3) ---
__global__ __launch_bounds__(256) void k7_spmm(const uint16_t* __restrict__ Xb16,
        const uint16_t* __restrict__ cols, const uint32_t* __restrict__ rowptr,
        const uint32_t* __restrict__ degf, float* __restrict__ agg) {
    int wid  = blockIdx.x * 4 + (threadIdx.x >> 6);
    int lane = threadIdx.x & 63;
    int b = wid >> 11, n = wid & (N_ - 1);
    const uint16_t* cb = cols + (size_t)b * EMAX;
    uint32_t start = rowptr[(size_t)b * RPS + n];
    uint32_t cnt = degf[wid];
    const uint16_t* Xb = Xb16 + ((size_t)b * N_) * D_;
    float ax = 0.f, ay = 0.f;
    for (uint32_t base = 0; base < cnt; base += 64) {
        int idx = (int)base + lane;
        int cl = (idx < (int)cnt) ? (int)cb[start + idx] : 0;
        int kmax = (int)cnt - (int)base; if (kmax > 64) kmax = 64;
        int k = 0;
        for (; k + 8 <= kmax; k += 8) {
            int c0 = __shfl(cl, k),     c1 = __shfl(cl, k + 1);
            int c2 = __shfl(cl, k + 2), c3 = __shfl(cl, k + 3);
            int c4 = __shfl(cl, k + 4), c5 = __shfl(cl, k + 5);
            int c6 = __shfl(cl, k + 6), c7 = __shfl(cl, k + 7);
            uint32_t u0 = ((const uint32_t*)(Xb + (size_t)c0 * D_))[lane];
            uint32_t u1 = ((const uint32_t*)(Xb + (size_t)c1 * D_))[lane];
            uint32_t u2 = ((const uint32_t*)(Xb + (size_t)c2 * D_))[lane];
            uint32_t u3 = ((const uint32_t*)(Xb + (size_t)c3 * D_))[lane];
            uint32_t u4 = ((const uint32_t*)(Xb + (size_t)c4 * D_))[lane];
            uint32_t u5 = ((const uint32_t*)(Xb + (size_t)c5 * D_))[lane];
            uint32_t u6 = ((const uint32_t*)(Xb + (size_t)c6 * D_))[lane];
            uint32_t u7 = ((const uint32_t*)(Xb + (size_t)c7 * D_))[lane];
            ax += __uint_as_float(u0 << 16) + __uint_as_float(u1 << 16)
                + __uint_as_float(u2 << 16) + __uint_as_float(u3 << 16)
                + __uint_as_float(u4 << 16) + __uint_as_float(u5 << 16)
                + __uint_as_float(u6 << 16) + __uint_as_float(u7 << 16);
            ay += __uint_as_float(u0 & 0xFFFF0000u) + __uint_as_float(u1 & 0xFFFF0000u)
                + __uint_as_float(u2 & 0xFFFF0000u) + __uint_as_float(u3 & 0xFFFF0000u)
                + __uint_as_float(u4 & 0xFFFF0000u) + __uint_as_float(u5 & 0xFFFF0000u)
                + __uint_as_float(u6 & 0xFFFF0000u) + __uint_as_float(u7 & 0xFFFF0000u);
        }
        for (; k < kmax; ++k) {
            int c = __shfl(cl, k);
            uint32_t u = ((const uint32_t*)(Xb + (size_t)c * D_))[lane];
            ax += __uint_as_float(u << 16);
            ay += __uint_as_float(u & 0xFFFF0000u);
        }
    }
    float inv = 1.0f / (float)(cnt ? cnt : 1u);
    ((float2*)(agg + (size_t)wid * D_))[lane] = make_float2(ax * inv, ay * inv);
}

// ---------------- bf16 split helper ----------------
__device__ __forceinline__ void cvt_store4(uint16_t* hiA, uint16_t* loA,
                                           int idx, float4 v) {
    float vv[4] = {v.x, v.y, v.z, v.w};
    ushort4 hs, ls;
    uint16_t* hp = (uint16_t*)&hs; uint16_t* lp = (uint16_t*)&ls;
    #pragma unroll
    for (int i = 0; i < 4; ++i) {
        uint32_t hi = bf16rne(vv[i]);
        float hf = __uint_as_float(hi << 16);
        hp[i] = (uint16_t)hi;
        lp[i] = bf16rne(vv[i] - hf);
    }
    *(ushort4*)&hiA[idx] = hs;
    *(ushort4*)&loA[idx] = ls;
}

// ---------------- K8: fused SAGE via bf16x3 MFMA ----------------
constexpr int ASTR = 264;   // shorts per row (256 + 8 pad)
__global__ __launch_bounds__(256) void k8_mfma(const float* __restrict__ agg,
        const float* __restrict__ Hin,
        const uint16_t* __restrict__ whi, const uint16_t* __restrict__ wlo,
        const float* __restrict__ bias, const int* __restrict__ mask,
        const float* __restrict__ bnp, const float* __restrict__ gp,
        const float* __restrict__ bep, int use_bn,
        float* __restrict__ P, uint16_t* __restrict__ Pb,
        float* __restrict__ bnstat) {
    __shared__ __align__(16) char buf[2 * 32 * ASTR * 2];   // 33792B
    __shared__ float scL[128], shL[128];
    uint16_t* aHi = (uint16_t*)buf;
    uint16_t* aLo = (uint16_t*)(buf + 32 * ASTR * 2);
    float* outP = (float*)buf;                              // overlay after MFMA
    int tid = threadIdx.x, lane = tid & 63, h = tid >> 6;
    size_t row0 = (size_t)blockIdx.x * 32;

    if (tid < 128) {
        float sc = 1.f, sh = 0.f;
        if (use_bn) {
            float mean = bnp[tid] * (1.f / 16384.f);
            float var  = bnp[128 + tid] * (1.f / 16384.f) - mean * mean;
            sc = gp[tid] * rsqrtf(var + 1e-5f);
            sh = bep[tid] - mean * sc;
        }
        scL[tid] = sc; shL[tid] = sh;
    }
    __syncthreads();

    for (int f = tid * 4; f < 4096; f += 1024) {
        int r = f >> 7, c = f & 127;
        float4 va = *(const float4*)&agg[(row0 + r) * 128 + c];
        float4 vx = *(const float4*)&Hin[(row0 + r) * 128 + c];
        float4 s4 = *(const float4*)&scL[c];
        float4 h4 = *(const float4*)&shL[c];
        va.x = va.x * s4.x + h4.x; va.y = va.y * s4.y + h4.y;
        va.z = va.z * s4.z + h4.z; va.w = va.w * s4.w + h4.w;
        vx.x = vx.x * s4.x + h4.x; vx.y = vx.y * s4.y + h4.y;
        vx.z = vx.z * s4.z + h4.z; vx.w = vx.w * s4.w + h4.w;
        cvt_store4(aHi, aLo, r * ASTR + c, va);
        cvt_store4(aHi, aLo, r * ASTR + 128 + c, vx);
    }
    __syncthreads();

    f32x4 acc00 = {0.f,0.f,0.f,0.f}, acc01 = acc00, acc10 = acc00, acc11 = acc00;
    int ct0 = h * 2, ct1 = h * 2 + 1;
    int arow = (lane & 15);
    int koff = (lane >> 4) * 8;
    #pragma unroll
    for (int ks = 0; ks < 8; ++ks) {
        int k0 = ks * 32 + koff;
        short8v a0h = *(short8v*)&aHi[arow * ASTR + k0];
        short8v a0l = *(short8v*)&aLo[arow * ASTR + k0];
        short8v a1h = *(short8v*)&aHi[(arow + 16) * ASTR + k0];
        short8v a1l = *(short8v*)&aLo[(arow + 16) * ASTR + k0];
        short8v b0h = *(const short8v*)&whi[(size_t)(((ks * 8 + ct0) << 6) + lane) * 8];
        short8v b0l = *(const short8v*)&wlo[(size_t)(((ks * 8 + ct0) << 6) + lane) * 8];
        short8v b1h = *(const short8v*)&whi[(size_t)(((ks * 8 + ct1) << 6) + lane) * 8];
        short8v b1l = *(const short8v*)&wlo[(size_t)(((ks * 8 + ct1) << 6) + lane) * 8];
        acc00 = __builtin_amdgcn_mfma_f32_16x16x32_bf16(a0h, b0h, acc00, 0, 0, 0);
        acc00 = __builtin_amdgcn_mfma_f32_16x16x32_bf16(a0h, b0l, acc00, 0, 0, 0);
        acc00 = __builtin_amdgcn_mfma_f32_16x16x32_bf16(a0l, b0h, acc00, 0, 0, 0);
        acc01 = __builtin_amdgcn_mfma_f32_16x16x32_bf16(a0h, b1h, acc01, 0, 0, 0);
        acc01 = __builtin_amdgcn_mfma_f32_16x16x32_bf16(a0h, b1l, acc01, 0, 0, 0);
        acc01 = __builtin_amdgcn_mfma_f32_16x16x32_bf16(a0l, b1h, acc01, 0, 0, 0);
        acc10 = __builtin_amdgcn_mfma_f32_16x16x32_bf16(a1h, b0h, acc10, 0, 0, 0);
        acc10 = __builtin_amdgcn_mfma_f32_16x16x32_bf16(a1h, b0l, acc10, 0, 0, 0);
        acc10 = __builtin_amdgcn_mfma_f32_16x16x32_bf16(a1l, b0h, acc10, 0, 0, 0);
        acc11 = __builtin_amdgcn_mfma_f32_16x16x32_bf16(a1h, b1h, acc11, 0, 0, 0);
        acc11 = __builtin_amdgcn_mfma_f32_16x16x32_bf16(a1h, b1l, acc11, 0, 0, 0);
        acc11 = __builtin_amdgcn_mfma_f32_16x16x32_bf16(a1l, b1h, acc11, 0, 0, 0);
    }
    __syncthreads();

    int orow = (lane >> 4) * 4;
    int oc0 = ct0 * 16 + (lane & 15);
    int oc1 = ct1 * 16 + (lane & 15);
    #pragma unroll
    for (int j = 0; j < 4; ++j) {
        outP[(orow + j) * 128 + oc0]      = acc00[j];
        outP[(orow + j) * 128 + oc1]      = acc01[j];
        outP[(16 + orow + j) * 128 + oc0] = acc10[j];
        outP[(16 + orow + j) * 128 + oc1] = acc11[j];
    }
    __syncthreads();

    float bs0 = bias[lane], bs1 = bias[lane + 64];
    #pragma unroll
    for (int i = 0; i < 8; ++i) {
        int r = h * 8 + i;
        float v0 = outP[r * 128 + lane] + bs0;
        float v1 = outP[r * 128 + lane + 64] + bs1;
        float s = v0 * v0 + v1 * v1;
        #pragma unroll
        for (int off = 32; off >= 1; off >>= 1) s += __shfl_xor(s, off);
        float nrm = fmaxf(sqrtf(s), 1e-12f);
        float mf = (mask[row0 + r] != 0) ? 1.f : 0.f;
        float inv = mf / nrm;
        float p0 = fmaxf(v0 * inv, 0.f), p1 = fmaxf(v1 * inv, 0.f);
        P[(row0 + r) * 128 + lane]      = p0;
        P[(row0 + r) * 128 + lane + 64] = p1;
        if (Pb) {
            Pb[(row0 + r) * 128 + lane]      = bf16rne(p0);
            Pb[(row0 + r) * 128 + lane + 64] = bf16rne(p1);
        }
        outP[r * 128 + lane] = p0; outP[r * 128 + lane + 64] = p1;
    }
    __syncthreads();
    if (tid < 128) {
        float s = 0.f, q = 0.f;
        #pragma unroll
        for (int r = 0; r < 32; ++r) { float v = outP[r * 128 + tid]; s += v; q += v * v; }
        atomicAdd(&bnstat[tid], s);
        atomicAdd(&bnstat[128 + tid], q);
    }
}

// ---------------- K11: final (concat BN(h_i) * mf) @ Wl + bl, * mf ----------
__global__ __launch_bounds__(256) void k11_final(const float* __restrict__ h1,
        const float* __restrict__ h2, const float* __restrict__ h3,
        const float* __restrict__ Wl, const float* __restrict__ bl,
        const int* __restrict__ mask, const float* __restrict__ bn,
        const float* __restrict__ g1, const float* __restrict__ be1,
        const float* __restrict__ g2, const float* __restrict__ be2,
        const float* __restrict__ g3, const float* __restrict__ be3,
        float* __restrict__ out) {
    __shared__ float s1[32 * 128], s2[32 * 128], s3[32 * 128];
    __shared__ float scA[128], shA[128], scB[128], shB[128], scC[128], shC[128];
    int tid = threadIdx.x;
    size_t row0 = (size_t)blockIdx.x * 32;
    if (tid < 128) {
        float m1 = bn[tid] * (1.f / 16384.f);
        float v1 = bn[128 + tid] * (1.f / 16384.f) - m1 * m1;
        scA[tid] = g1[tid] * rsqrtf(v1 + 1e-5f);
        shA[tid] = be1[tid] - m1 * scA[tid];
        float m2 = bn[256 + tid] * (1.f / 16384.f);
        float v2 = bn[384 + tid] * (1.f / 16384.f) - m2 * m2;
        scB[tid] = g2[tid] * rsqrtf(v2 + 1e-5f);
        shB[tid] = be2[tid] - m2 * scB[tid];
        float m3 = bn[512 + tid] * (1.f / 16384.f);
        float v3 = bn[640 + tid] * (1.f / 16384.f) - m3 * m3;
        scC[tid] = g3[tid] * rsqrtf(v3 + 1e-5f);
        shC[tid] = be3[tid] - m3 * scC[tid];
    }
    __syncthreads();
    for (int t = tid * 4; t < 32 * 128; t += 1024) {
        int r = t >> 7;
        float mf = (mask[row0 + r] != 0) ? 1.f : 0.f;
        int c = t & 127;
        float4 a = *(const float4*)&h1[row0 * 128 + t];
        float4 b = *(const float4*)&h2[row0 * 128 + t];
        float4 cc = *(const float4*)&h3[row0 * 128 + t];
        float4 sa = *(const float4*)&scA[c], ha = *(const float4*)&shA[c];
        float4 sb = *(const float4*)&scB[c], hb = *(const float4*)&shB[c];
        float4 sc = *(const float4*)&scC[c], hc = *(const float4*)&shC[c];
        a.x = (a.x * sa.x + ha.x) * mf; a.y = (a.y * sa.y + ha.y) * mf;
        a.z = (a.z * sa.z + ha.z) * mf; a.w = (a.w * sa.w + ha.w) * mf;
        b.x = (b.x * sb.x + hb.x) * mf; b.y = (b.y * sb.y + hb.y) * mf;
        b.z = (b.z * sb.z + hb.z) * mf; b.w = (b.w * sb.w + hb.w) * mf;
        cc.x = (cc.x * sc.x + hc.x) * mf; cc.y = (cc.y * sc.y + hc.y) * mf;
        cc.z = (cc.z * sc.z + hc.z) * mf; cc.w = (cc.w * sc.w + hc.w) * mf;
        *(float4*)&s1[t] = a; *(float4*)&s2[t] = b; *(float4*)&s3[t] = cc;
    }
    __syncthreads();
    int h = tid >> 6, c0 = (tid & 63) * 2;
    float2 acc[8];
    #pragma unroll
    for (int i = 0; i < 8; ++i) acc[i] = make_float2(0.f, 0.f);
    for (int k4 = 0; k4 < 128; k4 += 4) {
        float2 w1[4], w2[4], w3[4];
        #pragma unroll
        for (int kk = 0; kk < 4; ++kk) {
            w1[kk] = *(const float2*)&Wl[(k4 + kk) * 128 + c0];
            w2[kk] = *(const float2*)&Wl[(128 + k4 + kk) * 128 + c0];
            w3[kk] = *(const float2*)&Wl[(256 + k4 + kk) * 128 + c0];
        }
        #pragma unroll
        for (int i = 0; i < 8; ++i) {
            int r = h * 8 + i;
            float4 a = *(const float4*)&s1[r * 128 + k4];
            float4 b = *(const float4*)&s2[r * 128 + k4];
            float4 c = *(const float4*)&s3[r * 128 + k4];
            acc[i].x += a.x * w1[0].x + a.y * w1[1].x + a.z * w1[2].x + a.w * w1[3].x
                      + b.x * w2[0].x + b.y * w2[1].x + b.z * w2[2].x + b.w * w2[3].x
                      + c.x * w3[0].x + c.y * w3[1].x + c.z * w3[2].x + c.w * w3[3].x;
            acc[i].y += a.x * w1[0].y + a.y * w1[1].y + a.z * w1[2].y + a.w * w1[3].y
                      + b.x * w2[0].y + b.y * w2[1].y + b.z * w2[2].y + b.w * w2[3].y
                      + c.x * w3[0].y + c.y * w3[1].y + c.z * w3[2].y + c.w * w3[3].y;
        }
    }
    float bx = bl[c0], by = bl[c0 + 1];
    #pragma unroll
    for (int i = 0; i < 8; ++i) {
        int r = h * 8 + i;
        float mf = (mask[row0 + r] != 0) ? 1.f : 0.f;
        *(float2*)&out[(row0 + r) * 128 + c0] =
            make_float2((acc[i].x + bx) * mf, (acc[i].y + by) * mf);
    }
}

// ---------------- launch ----------------
extern "C" void kernel_launch(void* const* d_in, const int* in_sizes, int n_in,
                              void* d_out, int out_size, void* d_ws, size_t ws_size,
                              hipStream_t stream) {
    (void)in_sizes; (void)n_in; (void)out_size; (void)ws_size;
    const float* x    = (const float*)d_in[0];
    const float* adj  = (const float*)d_in[1];
    const int*   mask = (const int*)d_in[2];
    const float* Wr1 = (const float*)d_in[3],  *Wx1 = (const float*)d_in[4];
    const float* b1  = (const float*)d_in[5],  *g1  = (const float*)d_in[6],  *be1 = (const float*)d_in[7];
    const float* Wr2 = (const float*)d_in[8],  *Wx2 = (const float*)d_in[9];
    const float* b2  = (const float*)d_in[10], *g2  = (const float*)d_in[11], *be2 = (const float*)d_in[12];
    const float* Wr3 = (const float*)d_in[13], *Wx3 = (const float*)d_in[14];
    const float* b3  = (const float*)d_in[15], *g3  = (const float*)d_in[16], *be3 = (const float*)d_in[17];
    const float* Wl  = (const float*)d_in[18], *bl  = (const float*)d_in[19];

    char* ws = (char*)d_ws;
    uint32_t* bitset = (uint32_t*)(ws + OFF_BITSET);
    float*    agg    = (float*)(ws + OFF_AGG);
    float*    h1     = (float*)(ws + OFF_H1);
    float*    h2     = (float*)(ws + OFF_H2);
    float*    h3     = (float*)(ws + OFF_H3);
    uint16_t* xb     = (uint16_t*)(ws + OFF_XB);
    uint16_t* h1b    = (uint16_t*)(ws + OFF_H1B);
    uint16_t* h2b    = (uint16_t*)(ws + OFF_H2B);
    uint16_t* cols   = (uint16_t*)(ws + OFF_COLS);
    uint32_t* packed = (uint32_t*)(ws + OFF_PACKED);
    uint32_t* rp     = (uint32_t*)(ws + OFF_RP);
    uint32_t* deg0   = (uint32_t*)(ws + OFF_DEG0);
    uint32_t* degf   = (uint32_t*)(ws + OFF_DEGF);
    uint32_t* rmaskg = (uint32_t*)(ws + OFF_RMASK);
    float*    bn     = (float*)(ws + OFF_BN);
    uint16_t* whi    = (uint16_t*)(ws + OFF_WHI);
    uint16_t* wlo    = (uint16_t*)(ws + OFF_WLO);
    uint16_t* pref   = (uint16_t*)(ws + OFF_PREF);
    float*    out    = (float*)d_out;

    kP_prep   <<<6272, 256, 0, stream>>>(Wr1, Wx1, Wr2, Wx2, Wr3, Wx3, Wl,
                                         whi, wlo, bn, x, xb, adj, bitset, deg0, pref);
    k2_rowptr <<<8,    256, 0, stream>>>(deg0, rp);
    k34_colpack<<<4096,256, 0, stream>>>(bitset, rp, pref, cols, packed);
    k5_dilate <<<8,    1024, 0, stream>>>(packed, rp, deg0, mask, rmaskg, degf);
    // layer 1 (fused compaction + gather bf16 x; identity affine)
    k7_l1     <<<4096, 256, 0, stream>>>(xb,  cols, rp, rmaskg, agg);
    k8_mfma   <<<512,  256, 0, stream>>>(agg, x,  whi,         wlo,         b1, mask,
                                         bn, g1, be1, 0, h1, h1b, bn + 0);
    // layer 2 (gather bf16 h1; BN1 affine on the fly)
    k7_spmm   <<<4096, 256, 0, stream>>>(h1b, cols, rp, degf, agg);
    k8_mfma   <<<512,  256, 0, stream>>>(agg, h1, whi + 32768, wlo + 32768, b2, mask,
                                         bn + 0, g1, be1, 1, h2, h2b, bn + 256);
    // layer 3 (gather bf16 h2; BN2 affine on the fly)
    k7_spmm   <<<4096, 256, 0, stream>>>(h2b, cols, rp, degf, agg);
    k8_mfma   <<<512,  256, 0, stream>>>(agg, h2, whi + 65536, wlo + 65536, b3, mask,
                                         bn + 256, g2, be2, 1, h3, nullptr, bn + 512);
    // final
    k11_final <<<512,  256, 0, stream>>>(h1, h2, h3, Wl, bl, mask, bn,
                                         g1, be1, g2, be2, g3, be3, out);
}